// Round 10
// baseline (1752.831 us; speedup 1.0000x reference)
//
#include <hip/hip_runtime.h>
#include <math.h>
#include <float.h>
#include <limits.h>

#define B_ 8
#define C_ 32
#define N_ 4096
#define K_ 16
#define L_ 20   // per-lane candidate list length (margin 4 over 16)

typedef __attribute__((ext_vector_type(8))) short bf16x8;
typedef __attribute__((ext_vector_type(4))) float f32x4;
#define MFMA16(a, b, c) __builtin_amdgcn_mfma_f32_16x16x32_bf16(a, b, c, 0, 0, 0)

// ------------------------------------------------------------------
// ws layout (bytes):
//   yT  : [B][N][96] float    12,582,912
//   sqd : [B][N]     double      262,144
//   sq  : [B][N]     float       131,072
//   knn : [B][N][16] int       2,097,152
//   hBs : swizzled bf16 hi     6,291,456   (frag-major: [g16][sl][lane][8])
//   lBs : swizzled bf16 lo     6,291,456
//   Ek/Ev/Eq floats               20,480
// ------------------------------------------------------------------

__global__ __launch_bounds__(256) void kE_combine(
    const float* __restrict__ Wk, const float* __restrict__ Dk,
    const float* __restrict__ Wv, const float* __restrict__ Dv,
    const float* __restrict__ Wq, const float* __restrict__ Dq,
    float* __restrict__ Ek, float* __restrict__ Ev, float* __restrict__ Eq) {
  int t = threadIdx.x;
  for (int e = t; e < 2048; e += 256) {
    int o = e >> 6, c = e & 63;
    float a = 0.f, v = 0.f;
    for (int m = 0; m < 32; ++m) {
      a = fmaf(Dk[o * 32 + m], Wk[m * 64 + c], a);
      v = fmaf(Dv[o * 32 + m], Wv[m * 64 + c], v);
    }
    Ek[e] = a; Ev[e] = v;
  }
  for (int e = t; e < 1024; e += 256) {
    int o = e >> 5, c = e & 31;
    float a = 0.f;
    for (int m = 0; m < 32; ++m) a = fmaf(Dq[o * 32 + m], Wq[m * 32 + c], a);
    Eq[e] = a;
  }
}

// transpose y -> yT; sq fp32; sqd fp64; hBs/lBs = bf16 hi/lo split stored
// FRAGMENT-MAJOR: addr = ((g16*3 + sl)*64 + lane)*8 + e, lane=(fg<<4)|fm,
// point n = g16*16+fm, k-dim d = sl*32 + fg*8 + e.
__global__ __launch_bounds__(256) void kA_transpose(
    const float* __restrict__ y, float* __restrict__ yT,
    float* __restrict__ sq, double* __restrict__ sqd,
    ushort* __restrict__ hBs, ushort* __restrict__ lBs) {
  __shared__ float tile[96][65];
  int b = blockIdx.x >> 6;
  int n0 = (blockIdx.x & 63) * 64;
  int t = threadIdx.x;
  int g = t >> 6, ln = t & 63;
  #pragma unroll
  for (int r = 0; r < 24; ++r) {
    int d = g * 24 + r;
    tile[d][ln] = y[((size_t)b * 96 + d) * N_ + n0 + ln];
  }
  __syncthreads();
  if (t < 64) {
    float s = 0.f; double sd = 0.0;
    #pragma unroll
    for (int d = 0; d < 96; ++d) {
      float v = tile[d][t];
      s = fmaf(v, v, s);
      sd += (double)v * (double)v;
    }
    sq[b * N_ + n0 + t] = s;
    sqd[b * N_ + n0 + t] = sd;
  }
  for (int idx = t; idx < 64 * 96; idx += 256) {
    int nl = idx / 96, d = idx % 96;
    yT[((size_t)b * N_ + n0 + nl) * 96 + d] = tile[d][nl];
  }
  for (int idx = t; idx < 768; idx += 256) {
    int g16l = idx / 192;
    int rem = idx - g16l * 192;
    int sl = rem >> 6;
    int ln2 = rem & 63;
    int fg2 = ln2 >> 4, fm2 = ln2 & 15;
    int nl = g16l * 16 + fm2;
    uint hw[4], lw[4];
    #pragma unroll
    for (int e2 = 0; e2 < 4; ++e2) {
      float v0 = tile[sl * 32 + fg2 * 8 + 2 * e2][nl];
      float v1 = tile[sl * 32 + fg2 * 8 + 2 * e2 + 1][nl];
      uint x0 = __float_as_uint(v0), x1 = __float_as_uint(v1);
      uint h0 = x0 >> 16, h1 = x1 >> 16;
      float r0 = v0 - __uint_as_float(h0 << 16);
      float r1 = v1 - __uint_as_float(h1 << 16);
      uint l0 = __float_as_uint(r0) >> 16, l1 = __float_as_uint(r1) >> 16;
      hw[e2] = h0 | (h1 << 16);
      lw[e2] = l0 | (l1 << 16);
    }
    size_t off = (size_t)b * 393216 +
                 (((size_t)(n0 >> 4) + g16l) * 3 + sl) * 512 + (size_t)ln2 * 8;
    *(uint4*)(hBs + off) = make_uint4(hw[0], hw[1], hw[2], hw[3]);
    *(uint4*)(lBs + off) = make_uint4(lw[0], lw[1], lw[2], lw[3]);
  }
}

// Named-register top-20 (rule #20: arrays demote to scratch; this chain
// stays in VGPRs - proven 3.7x in round 9).
#define DECL20 \
  float v0=-FLT_MAX,v1=-FLT_MAX,v2=-FLT_MAX,v3=-FLT_MAX,v4=-FLT_MAX, \
        v5=-FLT_MAX,v6=-FLT_MAX,v7=-FLT_MAX,v8=-FLT_MAX,v9=-FLT_MAX, \
        v10=-FLT_MAX,v11=-FLT_MAX,v12=-FLT_MAX,v13=-FLT_MAX,v14=-FLT_MAX, \
        v15=-FLT_MAX,v16=-FLT_MAX,v17=-FLT_MAX,v18=-FLT_MAX,v19=-FLT_MAX; \
  int y0=0,y1=0,y2=0,y3=0,y4=0,y5=0,y6=0,y7=0,y8=0,y9=0, \
      y10=0,y11=0,y12=0,y13=0,y14=0,y15=0,y16=0,y17=0,y18=0,y19=0;

#define CX(i) { bool cc = cv > v##i; \
  float tf = cc ? v##i : cv; int ti = cc ? y##i : ci; \
  v##i = cc ? cv : v##i; y##i = cc ? ci : y##i; cv = tf; ci = ti; }

#define INSERT20 { CX(0) CX(1) CX(2) CX(3) CX(4) CX(5) CX(6) CX(7) CX(8) CX(9) \
  CX(10) CX(11) CX(12) CX(13) CX(14) CX(15) CX(16) CX(17) CX(18) CX(19) }

// kNN: block = 16 queries x 4 j-chunk waves (2048 blocks, 8192 waves).
// LDS shrunk to 36.6KB (ushort indices, dead mv removed) -> 4 blocks/CU
// = 16 waves/CU, double round-9's resident waves (latency-bound regime).
__global__ __launch_bounds__(256) void kB_knn(
    const float* __restrict__ yT, const ushort* __restrict__ hBs,
    const ushort* __restrict__ lBs, const float* __restrict__ sq,
    const double* __restrict__ sqd, int* __restrict__ knn) {
  __shared__ float  lv[4][4][16][L_ + 1];   // [w][fg][fm][slot]   21,504 B
  __shared__ ushort liu[4][4][16][L_ + 2];  //                     11,264 B
  __shared__ int    mid[16][L_];            //                      1,280 B
  __shared__ double rv[16][L_];             //                      2,560 B

  const int t = threadIdx.x;
  const int lane = t & 63;
  const int w = t >> 6;
  const int fg = lane >> 4, fm = lane & 15;
  const int b = blockIdx.x & 7;             // XCD-friendly batch pinning
  const int qg = blockIdx.x >> 3;           // 0..255
  const int q = qg * 16 + fm;
  const size_t bN = (size_t)b * N_;
  const ushort* hb = hBs + bN * 96;
  const ushort* lb = lBs + bN * 96;
  const float* sqb = sq + bN;
  const float sqi = sqb[q];

  // resident query frags (B operand): h and l, 3 k-segments each
  const ushort* hqb = hb + (size_t)qg * 1536 + (size_t)lane * 8;
  const ushort* lqb = lb + (size_t)qg * 1536 + (size_t)lane * 8;
  const bf16x8 qh0 = *(const bf16x8*)(hqb);
  const bf16x8 qh1 = *(const bf16x8*)(hqb + 512);
  const bf16x8 qh2 = *(const bf16x8*)(hqb + 1024);
  const bf16x8 ql0 = *(const bf16x8*)(lqb);
  const bf16x8 ql1 = *(const bf16x8*)(lqb + 512);
  const bf16x8 ql2 = *(const bf16x8*)(lqb + 1024);

  DECL20

  const int jchunk = w * 1024;
  #pragma unroll 1
  for (int jt = 0; jt < 16; ++jt) {
    const int g16 = (jchunk >> 4) + jt * 4;
    const ushort* hpb = hb + (size_t)g16 * 1536 + (size_t)lane * 8;
    const ushort* lpb = lb + (size_t)g16 * 1536 + (size_t)lane * 8;
    #pragma unroll
    for (int jb = 0; jb < 4; ++jb) {
      const ushort* ph = hpb + jb * 1536;
      const ushort* pl = lpb + jb * 1536;
      const bf16x8 a0 = *(const bf16x8*)(ph);
      const bf16x8 a1 = *(const bf16x8*)(ph + 512);
      const bf16x8 a2 = *(const bf16x8*)(ph + 1024);
      const bf16x8 b0 = *(const bf16x8*)(pl);
      const bf16x8 b1 = *(const bf16x8*)(pl + 512);
      const bf16x8 b2 = *(const bf16x8*)(pl + 1024);
      f32x4 c = {0.f, 0.f, 0.f, 0.f};
      c = MFMA16(a0, qh0, c);   // h_j . h_q
      c = MFMA16(a1, qh1, c);
      c = MFMA16(a2, qh2, c);
      c = MFMA16(a0, ql0, c);   // h_j . l_q
      c = MFMA16(a1, ql1, c);
      c = MFMA16(a2, ql2, c);
      c = MFMA16(b0, qh0, c);   // l_j . h_q
      c = MFMA16(b1, qh1, c);
      c = MFMA16(b2, qh2, c);
      const int jbase = jchunk + jt * 64 + jb * 16 + fg * 4;
      const float4 s4 = *(const float4*)(sqb + jbase);
      #pragma unroll
      for (int r = 0; r < 4; ++r) {
        const float sj = r == 0 ? s4.x : r == 1 ? s4.y : r == 2 ? s4.z : s4.w;
        const float neg = 2.f * c[r] - sqi - sj;
        if (neg > v19) {                 // strict >: earlier index wins ties
          float cv = neg; int ci = jbase + r;
          INSERT20
        }
      }
    }
  }

  // ---- per-lane sorted lists + sentinel ----
  {
    float* lvp = &lv[w][fg][fm][0];
    ushort* lip = &liu[w][fg][fm][0];
    lvp[0]=v0; lvp[1]=v1; lvp[2]=v2; lvp[3]=v3; lvp[4]=v4;
    lvp[5]=v5; lvp[6]=v6; lvp[7]=v7; lvp[8]=v8; lvp[9]=v9;
    lvp[10]=v10; lvp[11]=v11; lvp[12]=v12; lvp[13]=v13; lvp[14]=v14;
    lvp[15]=v15; lvp[16]=v16; lvp[17]=v17; lvp[18]=v18; lvp[19]=v19;
    lvp[20]=-FLT_MAX;
    lip[0]=(ushort)y0; lip[1]=(ushort)y1; lip[2]=(ushort)y2; lip[3]=(ushort)y3;
    lip[4]=(ushort)y4; lip[5]=(ushort)y5; lip[6]=(ushort)y6; lip[7]=(ushort)y7;
    lip[8]=(ushort)y8; lip[9]=(ushort)y9; lip[10]=(ushort)y10; lip[11]=(ushort)y11;
    lip[12]=(ushort)y12; lip[13]=(ushort)y13; lip[14]=(ushort)y14; lip[15]=(ushort)y15;
    lip[16]=(ushort)y16; lip[17]=(ushort)y17; lip[18]=(ushort)y18; lip[19]=(ushort)y19;
    lip[20]=0xFFFFu;
  }
  __syncthreads();

  // ---- 16-way exact merge (threads 0..15, one per query) ----
  if (t < 16) {
    int p[16];
    #pragma unroll
    for (int c2 = 0; c2 < 16; ++c2) p[c2] = 0;
    #pragma unroll 1
    for (int r = 0; r < L_; ++r) {
      float bv = -FLT_MAX; int bi2 = INT_MAX; int bc = 0;
      #pragma unroll
      for (int c2 = 0; c2 < 16; ++c2) {
        float v = lv[c2 >> 2][c2 & 3][t][p[c2]];
        int  id = (int)liu[c2 >> 2][c2 & 3][t][p[c2]];
        if (v > bv || (v == bv && id < bi2)) { bv = v; bi2 = id; bc = c2; }
      }
      mid[t][r] = bi2;
      #pragma unroll
      for (int c2 = 0; c2 < 16; ++c2) p[c2] += (bc == c2);
    }
  }
  __syncthreads();

  // ---- fp64 exact re-score: 320 tasks (16 q x 20 cand) ----
  {
    const double* sqdb = sqd + bN;
    const float* yTb = yT + bN * 96;
    #pragma unroll 1
    for (int task = t; task < 16 * L_; task += 256) {
      const int fq = task / L_, slot = task - fq * L_;
      const int qq = qg * 16 + fq;
      const int j = mid[fq][slot];
      const float4* q4p = (const float4*)(yTb + (size_t)qq * 96);
      const float4* p4p = (const float4*)(yTb + (size_t)j * 96);
      double a0 = 0.0, a1 = 0.0, a2 = 0.0, a3 = 0.0;
      #pragma unroll 4
      for (int m = 0; m < 24; ++m) {
        float4 qm = q4p[m], pm = p4p[m];
        a0 += (double)qm.x * (double)pm.x;
        a1 += (double)qm.y * (double)pm.y;
        a2 += (double)qm.z * (double)pm.z;
        a3 += (double)qm.w * (double)pm.w;
      }
      rv[fq][slot] = 2.0 * ((a0 + a1) + (a2 + a3)) - sqdb[qq] - sqdb[j];
    }
  }
  __syncthreads();

  // ---- final exact sorted top-16 (threads 0..15) ----
  if (t < 16) {
    double bd[16]; int bix[16];
    #pragma unroll
    for (int i = 0; i < 16; ++i) { bd[i] = -DBL_MAX; bix[i] = INT_MAX; }
    #pragma unroll 1
    for (int r = 0; r < L_; ++r) {
      double v = rv[t][r]; int id = mid[t][r];
      if (v > bd[15] || (v == bd[15] && id < bix[15])) {
        #pragma unroll
        for (int i = 0; i < 16; ++i) {
          if (v > bd[i] || (v == bd[i] && id < bix[i])) {
            double tv = bd[i]; bd[i] = v; v = tv;
            int ti = bix[i]; bix[i] = id; id = ti;
          }
        }
      }
    }
    int* outp = knn + (bN + (size_t)(qg * 16 + t)) * 16;
    #pragma unroll
    for (int r = 0; r < 16; ++r) outp[r] = bix[r];
  }
}

__device__ __forceinline__ float f4e(const float4& v, int i) {
  return i == 0 ? v.x : i == 1 ? v.y : i == 2 ? v.z : v.w;
}

// Fused main: single k-loop does K-score AND V-accumulate with online
// softmax (flash-style running m,l). Halves the neighbor loads (the two
// old passes loaded the same 24 float4 per k) -> 384 FMA per 25 loads.
__global__ __launch_bounds__(256) void kC_main(
    const float* __restrict__ x, const float* __restrict__ yT,
    const int* __restrict__ knn,
    const float* __restrict__ Wq, const float* __restrict__ Eq,
    const float* __restrict__ Wk, const float* __restrict__ Ek,
    const float* __restrict__ Wv, const float* __restrict__ Ev,
    float* __restrict__ out) {
  __shared__ float4 sWq[8 * 32], sEq[8 * 32];
  __shared__ float4 sWk[16 * 32], sEk[16 * 32], sWv[16 * 32], sEv[16 * 32];
  __shared__ float sOut[8][97];

  int t = threadIdx.x;
  {
    int e = t;
    int c4 = e >> 5, o = e & 31;
    sWq[e] = ((const float4*)(Wq + o * 32))[c4];
    sEq[e] = ((const float4*)(Eq + o * 32))[c4];
  }
  for (int e = t; e < 512; e += 256) {
    int c4 = e >> 5, o = e & 31;
    sWk[e] = ((const float4*)(Wk + o * 64))[c4];
    sEk[e] = ((const float4*)(Ek + o * 64))[c4];
    sWv[e] = ((const float4*)(Wv + o * 64))[c4];
    sEv[e] = ((const float4*)(Ev + o * 64))[c4];
  }
  __syncthreads();

  int q = t >> 5, o = t & 31;
  int bno = blockIdx.x;
  int b = bno >> 9;
  int n = ((bno & 511) << 3) + q;

  // ---- Qx ----
  const float* xb = x + (size_t)b * 96 * N_ + n;
  float pq[3] = {0, 0, 0}, dq[3] = {0, 0, 0};
  #pragma unroll
  for (int c4 = 0; c4 < 8; ++c4) {
    float4 wq = sWq[c4 * 32 + o], eq = sEq[c4 * 32 + o];
    #pragma unroll
    for (int i = 0; i < 4; ++i) {
      int c = c4 * 4 + i;
      float w = f4e(wq, i), e2 = f4e(eq, i);
      #pragma unroll
      for (int d = 0; d < 3; ++d) {
        float xv = xb[(size_t)(c * 3 + d) * N_];
        pq[d] = fmaf(w, xv, pq[d]);
        dq[d] = fmaf(e2, xv, dq[d]);
      }
    }
  }
  float Qx[3];
  {
    float dot = pq[0] * dq[0] + pq[1] * dq[1] + pq[2] * dq[2];
    float dsq = dq[0] * dq[0] + dq[1] * dq[1] + dq[2] * dq[2] + 1e-6f;
    float r = dot / dsq;
    float qv[3];
    #pragma unroll
    for (int d = 0; d < 3; ++d) {
      float pn = pq[d] - r * dq[d];
      qv[d] = 0.2f * pq[d] + 0.8f * (dot >= 0.f ? pq[d] : pn);
    }
    float nn = sqrtf(qv[0] * qv[0] + qv[1] * qv[1] + qv[2] * qv[2]);
    float nch2 = nn * nn;
    #pragma unroll
    for (int m = 1; m <= 16; m <<= 1) nch2 += __shfl_xor(nch2, m, 32);
    float s = (nn / fmaxf(sqrtf(nch2), 1e-12f)) / fmaxf(nn, 1e-12f);
    #pragma unroll
    for (int d = 0; d < 3; ++d) Qx[d] = qv[d] * s;
  }

  const float* ctr = yT + ((size_t)b * N_ + n) * 96;
  const int* kidx = knn + ((size_t)b * N_ + n) * 16;

  // ---- center-part hoists for K and V ----
  float pck[3] = {0, 0, 0}, dck[3] = {0, 0, 0};
  float pcv[3] = {0, 0, 0}, dcv[3] = {0, 0, 0};
  #pragma unroll
  for (int c4 = 0; c4 < 8; ++c4) {
    float4 wklo = sWk[c4 * 32 + o], wkhi = sWk[(c4 + 8) * 32 + o];
    float4 eklo = sEk[c4 * 32 + o], ekhi = sEk[(c4 + 8) * 32 + o];
    float4 wvlo = sWv[c4 * 32 + o], wvhi = sWv[(c4 + 8) * 32 + o];
    float4 evlo = sEv[c4 * 32 + o], evhi = sEv[(c4 + 8) * 32 + o];
    float4 c0 = ((const float4*)ctr)[c4 * 3 + 0];
    float4 c1 = ((const float4*)ctr)[c4 * 3 + 1];
    float4 c2 = ((const float4*)ctr)[c4 * 3 + 2];
    float cv[12] = {c0.x, c0.y, c0.z, c0.w, c1.x, c1.y, c1.z, c1.w, c2.x, c2.y, c2.z, c2.w};
    #pragma unroll
    for (int v = 0; v < 12; ++v) {
      int cl = v / 3, d = v % 3;
      pck[d] = fmaf(f4e(wkhi, cl) - f4e(wklo, cl), cv[v], pck[d]);
      dck[d] = fmaf(f4e(ekhi, cl) - f4e(eklo, cl), cv[v], dck[d]);
      pcv[d] = fmaf(f4e(wvhi, cl) - f4e(wvlo, cl), cv[v], pcv[d]);
      dcv[d] = fmaf(f4e(evhi, cl) - f4e(evlo, cl), cv[v], dcv[d]);
    }
  }

  // ---- fused K+V loop with online softmax ----
  float m_run = -FLT_MAX, l_run = 0.f;
  float acc0 = 0.f, acc1 = 0.f, acc2 = 0.f;
  #pragma unroll 1
  for (int k = 0; k < 16; ++k) {
    int jn = kidx[k];
    const float* nb = yT + ((size_t)b * N_ + jn) * 96;
    float p[3]  = {pck[0], pck[1], pck[2]}, dd[3] = {dck[0], dck[1], dck[2]};
    float pv[3] = {pcv[0], pcv[1], pcv[2]}, dv[3] = {dcv[0], dcv[1], dcv[2]};
    #pragma unroll
    for (int c4 = 0; c4 < 8; ++c4) {
      float4 wk = sWk[c4 * 32 + o], ek = sEk[c4 * 32 + o];
      float4 wv = sWv[c4 * 32 + o], ev = sEv[c4 * 32 + o];
      float4 n0 = ((const float4*)nb)[c4 * 3 + 0];
      float4 n1 = ((const float4*)nb)[c4 * 3 + 1];
      float4 n2 = ((const float4*)nb)[c4 * 3 + 2];
      float nv[12] = {n0.x, n0.y, n0.z, n0.w, n1.x, n1.y, n1.z, n1.w, n2.x, n2.y, n2.z, n2.w};
      #pragma unroll
      for (int v = 0; v < 12; ++v) {
        int cl = v / 3, d = v % 3;
        p[d]  = fmaf(f4e(wk, cl), nv[v], p[d]);
        dd[d] = fmaf(f4e(ek, cl), nv[v], dd[d]);
        pv[d] = fmaf(f4e(wv, cl), nv[v], pv[d]);
        dv[d] = fmaf(f4e(ev, cl), nv[v], dv[d]);
      }
    }
    // K leaky + channel-equi normalize + head score
    float dot = p[0] * dd[0] + p[1] * dd[1] + p[2] * dd[2];
    float dsq = dd[0] * dd[0] + dd[1] * dd[1] + dd[2] * dd[2] + 1e-6f;
    float r = dot / dsq;
    float ky[3];
    #pragma unroll
    for (int d = 0; d < 3; ++d) {
      float pn = p[d] - r * dd[d];
      ky[d] = 0.2f * p[d] + 0.8f * (dot >= 0.f ? p[d] : pn);
    }
    float nn = sqrtf(ky[0] * ky[0] + ky[1] * ky[1] + ky[2] * ky[2]);
    float nch2 = nn * nn;
    #pragma unroll
    for (int m = 1; m <= 16; m <<= 1) nch2 += __shfl_xor(nch2, m, 32);
    float s = (1.f / fmaxf(sqrtf(nch2), 1e-12f)) * (nn / fmaxf(nn, 1e-12f));
    float qk = (ky[0] * Qx[0] + ky[1] * Qx[1] + ky[2] * Qx[2]) * s;
    #pragma unroll
    for (int m = 1; m <= 8; m <<= 1) qk += __shfl_xor(qk, m, 32);
    float s_k = qk * 0.14433756729740643f;   // 1/sqrt(48)
    // V leaky
    float dotv = pv[0] * dv[0] + pv[1] * dv[1] + pv[2] * dv[2];
    float dsqv = dv[0] * dv[0] + dv[1] * dv[1] + dv[2] * dv[2] + 1e-6f;
    float rv2 = dotv / dsqv;
    float vy[3];
    #pragma unroll
    for (int d = 0; d < 3; ++d) {
      float pn = pv[d] - rv2 * dv[d];
      vy[d] = 0.2f * pv[d] + 0.8f * (dotv >= 0.f ? pv[d] : pn);
    }
    // online softmax update (uniform across the 16-lane head group)
    float m_new = fmaxf(m_run, s_k);
    float corr = expf(m_run - m_new);        // first iter: exp(-inf)=0
    float e = expf(s_k - m_new);
    l_run = l_run * corr + e;
    acc0 = fmaf(e, vy[0], acc0 * corr);
    acc1 = fmaf(e, vy[1], acc1 * corr);
    acc2 = fmaf(e, vy[2], acc2 * corr);
    m_run = m_new;
  }
  float inv_l = 1.f / l_run;

  // ---- output via LDS transpose for coalesced stores ----
  sOut[q][o * 3 + 0] = acc0 * inv_l;
  sOut[q][o * 3 + 1] = acc1 * inv_l;
  sOut[q][o * 3 + 2] = acc2 * inv_l;
  __syncthreads();
  int nl = t & 7;
  int n_out = ((bno & 511) << 3) + nl;
  #pragma unroll
  for (int it = 0; it < 3; ++it) {
    int od = it * 32 + (t >> 3);
    size_t a = (size_t)b * 96 * N_ + (size_t)od * N_ + n_out;
    out[a] = x[a] + sOut[nl][od];
  }
}

extern "C" void kernel_launch(void* const* d_in, const int* in_sizes, int n_in,
                              void* d_out, int out_size, void* d_ws, size_t ws_size,
                              hipStream_t stream) {
  const float* x  = (const float*)d_in[0];
  const float* y  = (const float*)d_in[1];
  const float* Wq = (const float*)d_in[2];
  const float* Dq = (const float*)d_in[3];
  const float* Wk = (const float*)d_in[4];
  const float* Dk = (const float*)d_in[5];
  const float* Wv = (const float*)d_in[6];
  const float* Dv = (const float*)d_in[7];
  float* out = (float*)d_out;

  char* wsb = (char*)d_ws;
  float*  yT  = (float*)wsb;                                   // 12,582,912 B
  double* sqd = (double*)(wsb + 12582912);                     //    262,144 B
  float*  sq  = (float*)(wsb + 12845056);                      //    131,072 B
  int*    knn = (int*)(wsb + 12976128);                        //  2,097,152 B
  ushort* hBs = (ushort*)(wsb + 15073280);                     //  6,291,456 B
  ushort* lBs = (ushort*)(wsb + 21364736);                     //  6,291,456 B
  float*  Ek  = (float*)(wsb + 27656192);                      //      8,192 B
  float*  Ev  = Ek + 2048;
  float*  Eq  = Ev + 2048;

  kE_combine<<<dim3(1), dim3(256), 0, stream>>>(Wk, Dk, Wv, Dv, Wq, Dq, Ek, Ev, Eq);
  kA_transpose<<<dim3(512), dim3(256), 0, stream>>>(y, yT, sq, sqd, hBs, lBs);
  kB_knn<<<dim3(2048), dim3(256), 0, stream>>>(yT, hBs, lBs, sq, sqd, knn);
  kC_main<<<dim3(4096), dim3(256), 0, stream>>>(x, yT, knn, Wq, Eq, Wk, Ek, Wv, Ev, out);
}

// Round 11
// 1558.839 us; speedup vs baseline: 1.1244x; 1.1244x over previous
//
#include <hip/hip_runtime.h>
#include <math.h>
#include <float.h>
#include <limits.h>

#define B_ 8
#define C_ 32
#define N_ 4096
#define K_ 16
#define L_ 20   // per-lane candidate list length (margin 4 over 16)

typedef __attribute__((ext_vector_type(8))) short bf16x8;
typedef __attribute__((ext_vector_type(4))) float f32x4;
#define MFMA16(a, b, c) __builtin_amdgcn_mfma_f32_16x16x32_bf16(a, b, c, 0, 0, 0)

// ------------------------------------------------------------------
// ws layout (bytes):
//   yT  : [B][N][96] float    12,582,912
//   sqd : [B][N]     double      262,144
//   sq  : [B][N]     float       131,072
//   knn : [B][N][16] int       2,097,152
//   hBs : swizzled bf16 hi     6,291,456   (frag-major: [g16][sl][lane][8])
//   lBs : swizzled bf16 lo     6,291,456
//   Ek/Ev/Eq floats               20,480
// ------------------------------------------------------------------

__global__ __launch_bounds__(256) void kE_combine(
    const float* __restrict__ Wk, const float* __restrict__ Dk,
    const float* __restrict__ Wv, const float* __restrict__ Dv,
    const float* __restrict__ Wq, const float* __restrict__ Dq,
    float* __restrict__ Ek, float* __restrict__ Ev, float* __restrict__ Eq) {
  int t = threadIdx.x;
  for (int e = t; e < 2048; e += 256) {
    int o = e >> 6, c = e & 63;
    float a = 0.f, v = 0.f;
    for (int m = 0; m < 32; ++m) {
      a = fmaf(Dk[o * 32 + m], Wk[m * 64 + c], a);
      v = fmaf(Dv[o * 32 + m], Wv[m * 64 + c], v);
    }
    Ek[e] = a; Ev[e] = v;
  }
  for (int e = t; e < 1024; e += 256) {
    int o = e >> 5, c = e & 31;
    float a = 0.f;
    for (int m = 0; m < 32; ++m) a = fmaf(Dq[o * 32 + m], Wq[m * 32 + c], a);
    Eq[e] = a;
  }
}

// transpose y -> yT; sq fp32; sqd fp64; hBs/lBs = bf16 hi/lo split stored
// FRAGMENT-MAJOR: addr = ((g16*3 + sl)*64 + lane)*8 + e, lane=(fg<<4)|fm,
// point n = g16*16+fm, k-dim d = sl*32 + fg*8 + e.
__global__ __launch_bounds__(256) void kA_transpose(
    const float* __restrict__ y, float* __restrict__ yT,
    float* __restrict__ sq, double* __restrict__ sqd,
    ushort* __restrict__ hBs, ushort* __restrict__ lBs) {
  __shared__ float tile[96][65];
  int b = blockIdx.x >> 6;
  int n0 = (blockIdx.x & 63) * 64;
  int t = threadIdx.x;
  int g = t >> 6, ln = t & 63;
  #pragma unroll
  for (int r = 0; r < 24; ++r) {
    int d = g * 24 + r;
    tile[d][ln] = y[((size_t)b * 96 + d) * N_ + n0 + ln];
  }
  __syncthreads();
  if (t < 64) {
    float s = 0.f; double sd = 0.0;
    #pragma unroll
    for (int d = 0; d < 96; ++d) {
      float v = tile[d][t];
      s = fmaf(v, v, s);
      sd += (double)v * (double)v;
    }
    sq[b * N_ + n0 + t] = s;
    sqd[b * N_ + n0 + t] = sd;
  }
  for (int idx = t; idx < 64 * 96; idx += 256) {
    int nl = idx / 96, d = idx % 96;
    yT[((size_t)b * N_ + n0 + nl) * 96 + d] = tile[d][nl];
  }
  for (int idx = t; idx < 768; idx += 256) {
    int g16l = idx / 192;
    int rem = idx - g16l * 192;
    int sl = rem >> 6;
    int ln2 = rem & 63;
    int fg2 = ln2 >> 4, fm2 = ln2 & 15;
    int nl = g16l * 16 + fm2;
    uint hw[4], lw[4];
    #pragma unroll
    for (int e2 = 0; e2 < 4; ++e2) {
      float v0 = tile[sl * 32 + fg2 * 8 + 2 * e2][nl];
      float v1 = tile[sl * 32 + fg2 * 8 + 2 * e2 + 1][nl];
      uint x0 = __float_as_uint(v0), x1 = __float_as_uint(v1);
      uint h0 = x0 >> 16, h1 = x1 >> 16;
      float r0 = v0 - __uint_as_float(h0 << 16);
      float r1 = v1 - __uint_as_float(h1 << 16);
      uint l0 = __float_as_uint(r0) >> 16, l1 = __float_as_uint(r1) >> 16;
      hw[e2] = h0 | (h1 << 16);
      lw[e2] = l0 | (l1 << 16);
    }
    size_t off = (size_t)b * 393216 +
                 (((size_t)(n0 >> 4) + g16l) * 3 + sl) * 512 + (size_t)ln2 * 8;
    *(uint4*)(hBs + off) = make_uint4(hw[0], hw[1], hw[2], hw[3]);
    *(uint4*)(lBs + off) = make_uint4(lw[0], lw[1], lw[2], lw[3]);
  }
}

// Named-register top-20 (rule #20: arrays demote to scratch; this chain
// stays in VGPRs - proven 3.7x in round 9).
#define DECL20 \
  float v0=-FLT_MAX,v1=-FLT_MAX,v2=-FLT_MAX,v3=-FLT_MAX,v4=-FLT_MAX, \
        v5=-FLT_MAX,v6=-FLT_MAX,v7=-FLT_MAX,v8=-FLT_MAX,v9=-FLT_MAX, \
        v10=-FLT_MAX,v11=-FLT_MAX,v12=-FLT_MAX,v13=-FLT_MAX,v14=-FLT_MAX, \
        v15=-FLT_MAX,v16=-FLT_MAX,v17=-FLT_MAX,v18=-FLT_MAX,v19=-FLT_MAX; \
  int y0=0,y1=0,y2=0,y3=0,y4=0,y5=0,y6=0,y7=0,y8=0,y9=0, \
      y10=0,y11=0,y12=0,y13=0,y14=0,y15=0,y16=0,y17=0,y18=0,y19=0;

#define CX(i) { bool cc = cv > v##i; \
  float tf = cc ? v##i : cv; int ti = cc ? y##i : ci; \
  v##i = cc ? cv : v##i; y##i = cc ? ci : y##i; cv = tf; ci = ti; }

#define INSERT20 { CX(0) CX(1) CX(2) CX(3) CX(4) CX(5) CX(6) CX(7) CX(8) CX(9) \
  CX(10) CX(11) CX(12) CX(13) CX(14) CX(15) CX(16) CX(17) CX(18) CX(19) }

// kNN: block = 16 queries x 4 j-chunk waves (2048 blocks, 8192 waves).
// LDS 36.6KB -> 4 blocks/CU = 16 waves/CU.
__global__ __launch_bounds__(256) void kB_knn(
    const float* __restrict__ yT, const ushort* __restrict__ hBs,
    const ushort* __restrict__ lBs, const float* __restrict__ sq,
    const double* __restrict__ sqd, int* __restrict__ knn) {
  __shared__ float  lv[4][4][16][L_ + 1];   // [w][fg][fm][slot]   21,504 B
  __shared__ ushort liu[4][4][16][L_ + 2];  //                     11,264 B
  __shared__ int    mid[16][L_];            //                      1,280 B
  __shared__ double rv[16][L_];             //                      2,560 B

  const int t = threadIdx.x;
  const int lane = t & 63;
  const int w = t >> 6;
  const int fg = lane >> 4, fm = lane & 15;
  const int b = blockIdx.x & 7;             // XCD-friendly batch pinning
  const int qg = blockIdx.x >> 3;           // 0..255
  const int q = qg * 16 + fm;
  const size_t bN = (size_t)b * N_;
  const ushort* hb = hBs + bN * 96;
  const ushort* lb = lBs + bN * 96;
  const float* sqb = sq + bN;
  const float sqi = sqb[q];

  // resident query frags (B operand): h and l, 3 k-segments each
  const ushort* hqb = hb + (size_t)qg * 1536 + (size_t)lane * 8;
  const ushort* lqb = lb + (size_t)qg * 1536 + (size_t)lane * 8;
  const bf16x8 qh0 = *(const bf16x8*)(hqb);
  const bf16x8 qh1 = *(const bf16x8*)(hqb + 512);
  const bf16x8 qh2 = *(const bf16x8*)(hqb + 1024);
  const bf16x8 ql0 = *(const bf16x8*)(lqb);
  const bf16x8 ql1 = *(const bf16x8*)(lqb + 512);
  const bf16x8 ql2 = *(const bf16x8*)(lqb + 1024);

  DECL20

  const int jchunk = w * 1024;
  #pragma unroll 1
  for (int jt = 0; jt < 16; ++jt) {
    const int g16 = (jchunk >> 4) + jt * 4;
    const ushort* hpb = hb + (size_t)g16 * 1536 + (size_t)lane * 8;
    const ushort* lpb = lb + (size_t)g16 * 1536 + (size_t)lane * 8;
    #pragma unroll
    for (int jb = 0; jb < 4; ++jb) {
      const ushort* ph = hpb + jb * 1536;
      const ushort* pl = lpb + jb * 1536;
      const bf16x8 a0 = *(const bf16x8*)(ph);
      const bf16x8 a1 = *(const bf16x8*)(ph + 512);
      const bf16x8 a2 = *(const bf16x8*)(ph + 1024);
      const bf16x8 b0 = *(const bf16x8*)(pl);
      const bf16x8 b1 = *(const bf16x8*)(pl + 512);
      const bf16x8 b2 = *(const bf16x8*)(pl + 1024);
      f32x4 c = {0.f, 0.f, 0.f, 0.f};
      c = MFMA16(a0, qh0, c);   // h_j . h_q
      c = MFMA16(a1, qh1, c);
      c = MFMA16(a2, qh2, c);
      c = MFMA16(a0, ql0, c);   // h_j . l_q
      c = MFMA16(a1, ql1, c);
      c = MFMA16(a2, ql2, c);
      c = MFMA16(b0, qh0, c);   // l_j . h_q
      c = MFMA16(b1, qh1, c);
      c = MFMA16(b2, qh2, c);
      const int jbase = jchunk + jt * 64 + jb * 16 + fg * 4;
      const float4 s4 = *(const float4*)(sqb + jbase);
      #pragma unroll
      for (int r = 0; r < 4; ++r) {
        const float sj = r == 0 ? s4.x : r == 1 ? s4.y : r == 2 ? s4.z : s4.w;
        const float neg = 2.f * c[r] - sqi - sj;
        if (neg > v19) {                 // strict >: earlier index wins ties
          float cv = neg; int ci = jbase + r;
          INSERT20
        }
      }
    }
  }

  // ---- per-lane sorted lists + sentinel ----
  {
    float* lvp = &lv[w][fg][fm][0];
    ushort* lip = &liu[w][fg][fm][0];
    lvp[0]=v0; lvp[1]=v1; lvp[2]=v2; lvp[3]=v3; lvp[4]=v4;
    lvp[5]=v5; lvp[6]=v6; lvp[7]=v7; lvp[8]=v8; lvp[9]=v9;
    lvp[10]=v10; lvp[11]=v11; lvp[12]=v12; lvp[13]=v13; lvp[14]=v14;
    lvp[15]=v15; lvp[16]=v16; lvp[17]=v17; lvp[18]=v18; lvp[19]=v19;
    lvp[20]=-FLT_MAX;
    lip[0]=(ushort)y0; lip[1]=(ushort)y1; lip[2]=(ushort)y2; lip[3]=(ushort)y3;
    lip[4]=(ushort)y4; lip[5]=(ushort)y5; lip[6]=(ushort)y6; lip[7]=(ushort)y7;
    lip[8]=(ushort)y8; lip[9]=(ushort)y9; lip[10]=(ushort)y10; lip[11]=(ushort)y11;
    lip[12]=(ushort)y12; lip[13]=(ushort)y13; lip[14]=(ushort)y14; lip[15]=(ushort)y15;
    lip[16]=(ushort)y16; lip[17]=(ushort)y17; lip[18]=(ushort)y18; lip[19]=(ushort)y19;
    lip[20]=0xFFFFu;
  }
  __syncthreads();

  // ---- 16-way exact merge (threads 0..15, one per query) ----
  if (t < 16) {
    int p[16];
    #pragma unroll
    for (int c2 = 0; c2 < 16; ++c2) p[c2] = 0;
    #pragma unroll 1
    for (int r = 0; r < L_; ++r) {
      float bv = -FLT_MAX; int bi2 = INT_MAX; int bc = 0;
      #pragma unroll
      for (int c2 = 0; c2 < 16; ++c2) {
        float v = lv[c2 >> 2][c2 & 3][t][p[c2]];
        int  id = (int)liu[c2 >> 2][c2 & 3][t][p[c2]];
        if (v > bv || (v == bv && id < bi2)) { bv = v; bi2 = id; bc = c2; }
      }
      mid[t][r] = bi2;
      #pragma unroll
      for (int c2 = 0; c2 < 16; ++c2) p[c2] += (bc == c2);
    }
  }
  __syncthreads();

  // ---- fp64 exact re-score: 320 tasks (16 q x 20 cand) ----
  {
    const double* sqdb = sqd + bN;
    const float* yTb = yT + bN * 96;
    #pragma unroll 1
    for (int task = t; task < 16 * L_; task += 256) {
      const int fq = task / L_, slot = task - fq * L_;
      const int qq = qg * 16 + fq;
      const int j = mid[fq][slot];
      const float4* q4p = (const float4*)(yTb + (size_t)qq * 96);
      const float4* p4p = (const float4*)(yTb + (size_t)j * 96);
      double a0 = 0.0, a1 = 0.0, a2 = 0.0, a3 = 0.0;
      #pragma unroll 4
      for (int m = 0; m < 24; ++m) {
        float4 qm = q4p[m], pm = p4p[m];
        a0 += (double)qm.x * (double)pm.x;
        a1 += (double)qm.y * (double)pm.y;
        a2 += (double)qm.z * (double)pm.z;
        a3 += (double)qm.w * (double)pm.w;
      }
      rv[fq][slot] = 2.0 * ((a0 + a1) + (a2 + a3)) - sqdb[qq] - sqdb[j];
    }
  }
  __syncthreads();

  // ---- final exact sorted top-16 (threads 0..15) ----
  if (t < 16) {
    double bd[16]; int bix[16];
    #pragma unroll
    for (int i = 0; i < 16; ++i) { bd[i] = -DBL_MAX; bix[i] = INT_MAX; }
    #pragma unroll 1
    for (int r = 0; r < L_; ++r) {
      double v = rv[t][r]; int id = mid[t][r];
      if (v > bd[15] || (v == bd[15] && id < bix[15])) {
        #pragma unroll
        for (int i = 0; i < 16; ++i) {
          if (v > bd[i] || (v == bd[i] && id < bix[i])) {
            double tv = bd[i]; bd[i] = v; v = tv;
            int ti = bix[i]; bix[i] = id; id = ti;
          }
        }
      }
    }
    int* outp = knn + (bN + (size_t)(qg * 16 + t)) * 16;
    #pragma unroll
    for (int r = 0; r < 16; ++r) outp[r] = bix[r];
  }
}

__device__ __forceinline__ float f4e(const float4& v, int i) {
  return i == 0 ? v.x : i == 1 ? v.y : i == 2 ? v.z : v.w;
}

// Fused main, two-pass (round-9 arithmetic, VGPR ~128) with PHASE-REUSED
// weight LDS: one sW/sE[512] buffer serves Wq/Eq -> Wk/Ek -> Wv/Ev in
// disjoint phases. LDS 44.5KB -> 19.5KB => 4 blocks/CU (was 3).
__global__ __launch_bounds__(256) void kC_main(
    const float* __restrict__ x, const float* __restrict__ yT,
    const int* __restrict__ knn,
    const float* __restrict__ Wq, const float* __restrict__ Eq,
    const float* __restrict__ Wk, const float* __restrict__ Ek,
    const float* __restrict__ Wv, const float* __restrict__ Ev,
    float* __restrict__ out) {
  __shared__ float4 sW[512], sE[512];       // 16,384 B (phase-reused)
  __shared__ float sOut[8][97];             //  3,104 B

  int t = threadIdx.x;
  int q = t >> 5, o = t & 31;
  int bno = blockIdx.x;
  int b = bno >> 9;
  int n = ((bno & 511) << 3) + q;
  int h = o >> 4, kk_mine = o & 15;

  // ---- phase 0: Wq/Eq ----
  {
    int c4 = t >> 5, oo = t & 31;
    sW[t] = ((const float4*)(Wq + oo * 32))[c4];
    sE[t] = ((const float4*)(Eq + oo * 32))[c4];
  }
  __syncthreads();

  const float* xb = x + (size_t)b * 96 * N_ + n;
  float pq[3] = {0, 0, 0}, dq[3] = {0, 0, 0};
  #pragma unroll
  for (int c4 = 0; c4 < 8; ++c4) {
    float4 wq = sW[c4 * 32 + o], eq = sE[c4 * 32 + o];
    #pragma unroll
    for (int i = 0; i < 4; ++i) {
      int c = c4 * 4 + i;
      float w = f4e(wq, i), e2 = f4e(eq, i);
      #pragma unroll
      for (int d = 0; d < 3; ++d) {
        float xv = xb[(size_t)(c * 3 + d) * N_];
        pq[d] = fmaf(w, xv, pq[d]);
        dq[d] = fmaf(e2, xv, dq[d]);
      }
    }
  }
  float Qx[3];
  {
    float dot = pq[0] * dq[0] + pq[1] * dq[1] + pq[2] * dq[2];
    float dsq = dq[0] * dq[0] + dq[1] * dq[1] + dq[2] * dq[2] + 1e-6f;
    float r = dot / dsq;
    float qv[3];
    #pragma unroll
    for (int d = 0; d < 3; ++d) {
      float pn = pq[d] - r * dq[d];
      qv[d] = 0.2f * pq[d] + 0.8f * (dot >= 0.f ? pq[d] : pn);
    }
    float nn = sqrtf(qv[0] * qv[0] + qv[1] * qv[1] + qv[2] * qv[2]);
    float nch2 = nn * nn;
    #pragma unroll
    for (int m = 1; m <= 16; m <<= 1) nch2 += __shfl_xor(nch2, m, 32);
    float s = (nn / fmaxf(sqrtf(nch2), 1e-12f)) / fmaxf(nn, 1e-12f);
    #pragma unroll
    for (int d = 0; d < 3; ++d) Qx[d] = qv[d] * s;
  }
  __syncthreads();   // done reading Wq/Eq

  // ---- phase 1: Wk/Ek ----
  for (int e = t; e < 512; e += 256) {
    int c4 = e >> 5, oo = e & 31;
    sW[e] = ((const float4*)(Wk + oo * 64))[c4];
    sE[e] = ((const float4*)(Ek + oo * 64))[c4];
  }
  __syncthreads();

  const float* ctr = yT + ((size_t)b * N_ + n) * 96;
  const int* kidx = knn + ((size_t)b * N_ + n) * 16;

  float pck[3] = {0, 0, 0}, dck[3] = {0, 0, 0};
  #pragma unroll
  for (int c4 = 0; c4 < 8; ++c4) {
    float4 wlo = sW[c4 * 32 + o], whi = sW[(c4 + 8) * 32 + o];
    float4 elo = sE[c4 * 32 + o], ehi = sE[(c4 + 8) * 32 + o];
    float4 c0 = ((const float4*)ctr)[c4 * 3 + 0];
    float4 c1 = ((const float4*)ctr)[c4 * 3 + 1];
    float4 c2 = ((const float4*)ctr)[c4 * 3 + 2];
    float cv[12] = {c0.x, c0.y, c0.z, c0.w, c1.x, c1.y, c1.z, c1.w, c2.x, c2.y, c2.z, c2.w};
    #pragma unroll
    for (int v = 0; v < 12; ++v) {
      int cl = v / 3, d = v % 3;
      pck[d] = fmaf(f4e(whi, cl) - f4e(wlo, cl), cv[v], pck[d]);
      dck[d] = fmaf(f4e(ehi, cl) - f4e(elo, cl), cv[v], dck[d]);
    }
  }

  float myscore = 0.f;
  #pragma unroll 1
  for (int k = 0; k < 16; ++k) {
    int jn = kidx[k];
    const float* nb = yT + ((size_t)b * N_ + jn) * 96;
    float p[3] = {pck[0], pck[1], pck[2]}, dd[3] = {dck[0], dck[1], dck[2]};
    #pragma unroll
    for (int c4 = 0; c4 < 8; ++c4) {
      float4 w = sW[c4 * 32 + o], e = sE[c4 * 32 + o];
      float4 n0 = ((const float4*)nb)[c4 * 3 + 0];
      float4 n1 = ((const float4*)nb)[c4 * 3 + 1];
      float4 n2 = ((const float4*)nb)[c4 * 3 + 2];
      float nv[12] = {n0.x, n0.y, n0.z, n0.w, n1.x, n1.y, n1.z, n1.w, n2.x, n2.y, n2.z, n2.w};
      #pragma unroll
      for (int v = 0; v < 12; ++v) {
        int cl = v / 3, d = v % 3;
        p[d]  = fmaf(f4e(w, cl), nv[v], p[d]);
        dd[d] = fmaf(f4e(e, cl), nv[v], dd[d]);
      }
    }
    float dot = p[0] * dd[0] + p[1] * dd[1] + p[2] * dd[2];
    float dsq = dd[0] * dd[0] + dd[1] * dd[1] + dd[2] * dd[2] + 1e-6f;
    float r = dot / dsq;
    float ky[3];
    #pragma unroll
    for (int d = 0; d < 3; ++d) {
      float pn = p[d] - r * dd[d];
      ky[d] = 0.2f * p[d] + 0.8f * (dot >= 0.f ? p[d] : pn);
    }
    float nn = sqrtf(ky[0] * ky[0] + ky[1] * ky[1] + ky[2] * ky[2]);
    float nch2 = nn * nn;
    #pragma unroll
    for (int m = 1; m <= 16; m <<= 1) nch2 += __shfl_xor(nch2, m, 32);
    float s = (1.f / fmaxf(sqrtf(nch2), 1e-12f)) * (nn / fmaxf(nn, 1e-12f));
    float qk = (ky[0] * Qx[0] + ky[1] * Qx[1] + ky[2] * Qx[2]) * s;
    #pragma unroll
    for (int m = 1; m <= 8; m <<= 1) qk += __shfl_xor(qk, m, 32);
    float score = qk * 0.14433756729740643f;   // 1/sqrt(48)
    if (kk_mine == k) myscore = score;
  }

  // ---- softmax (registers survive the phase barriers) ----
  float att_mine;
  {
    float mx = myscore;
    #pragma unroll
    for (int m = 1; m <= 8; m <<= 1) mx = fmaxf(mx, __shfl_xor(mx, m, 32));
    float ex = expf(myscore - mx);
    float ss = ex;
    #pragma unroll
    for (int m = 1; m <= 8; m <<= 1) ss += __shfl_xor(ss, m, 32);
    att_mine = ex / ss;
  }
  __syncthreads();   // done reading Wk/Ek

  // ---- phase 2: Wv/Ev ----
  for (int e = t; e < 512; e += 256) {
    int c4 = e >> 5, oo = e & 31;
    sW[e] = ((const float4*)(Wv + oo * 64))[c4];
    sE[e] = ((const float4*)(Ev + oo * 64))[c4];
  }
  __syncthreads();

  float pcv[3] = {0, 0, 0}, dcv[3] = {0, 0, 0};
  #pragma unroll
  for (int c4 = 0; c4 < 8; ++c4) {
    float4 wlo = sW[c4 * 32 + o], whi = sW[(c4 + 8) * 32 + o];
    float4 elo = sE[c4 * 32 + o], ehi = sE[(c4 + 8) * 32 + o];
    float4 c0 = ((const float4*)ctr)[c4 * 3 + 0];
    float4 c1 = ((const float4*)ctr)[c4 * 3 + 1];
    float4 c2 = ((const float4*)ctr)[c4 * 3 + 2];
    float cv[12] = {c0.x, c0.y, c0.z, c0.w, c1.x, c1.y, c1.z, c1.w, c2.x, c2.y, c2.z, c2.w};
    #pragma unroll
    for (int v = 0; v < 12; ++v) {
      int cl = v / 3, d = v % 3;
      pcv[d] = fmaf(f4e(whi, cl) - f4e(wlo, cl), cv[v], pcv[d]);
      dcv[d] = fmaf(f4e(ehi, cl) - f4e(elo, cl), cv[v], dcv[d]);
    }
  }
  float acc[3] = {0, 0, 0};
  #pragma unroll 1
  for (int k = 0; k < 16; ++k) {
    int jn = kidx[k];
    const float* nb = yT + ((size_t)b * N_ + jn) * 96;
    float p[3] = {pcv[0], pcv[1], pcv[2]}, dd[3] = {dcv[0], dcv[1], dcv[2]};
    #pragma unroll
    for (int c4 = 0; c4 < 8; ++c4) {
      float4 w = sW[c4 * 32 + o], e = sE[c4 * 32 + o];
      float4 n0 = ((const float4*)nb)[c4 * 3 + 0];
      float4 n1 = ((const float4*)nb)[c4 * 3 + 1];
      float4 n2 = ((const float4*)nb)[c4 * 3 + 2];
      float nv[12] = {n0.x, n0.y, n0.z, n0.w, n1.x, n1.y, n1.z, n1.w, n2.x, n2.y, n2.z, n2.w};
      #pragma unroll
      for (int v = 0; v < 12; ++v) {
        int cl = v / 3, d = v % 3;
        p[d]  = fmaf(f4e(w, cl), nv[v], p[d]);
        dd[d] = fmaf(f4e(e, cl), nv[v], dd[d]);
      }
    }
    float dot = p[0] * dd[0] + p[1] * dd[1] + p[2] * dd[2];
    float dsq = dd[0] * dd[0] + dd[1] * dd[1] + dd[2] * dd[2] + 1e-6f;
    float r = dot / dsq;
    float attk = __shfl(att_mine, h * 16 + k, 32);
    #pragma unroll
    for (int d = 0; d < 3; ++d) {
      float pn = p[d] - r * dd[d];
      float vy = 0.2f * p[d] + 0.8f * (dot >= 0.f ? p[d] : pn);
      acc[d] = fmaf(attk, vy, acc[d]);
    }
  }

  // ---- output via LDS transpose for coalesced stores ----
  #pragma unroll
  for (int d = 0; d < 3; ++d) sOut[q][o * 3 + d] = acc[d];
  __syncthreads();
  int nl = t & 7;
  int n_out = ((bno & 511) << 3) + nl;
  #pragma unroll
  for (int it = 0; it < 3; ++it) {
    int od = it * 32 + (t >> 3);
    size_t a = (size_t)b * 96 * N_ + (size_t)od * N_ + n_out;
    out[a] = x[a] + sOut[nl][od];
  }
}

extern "C" void kernel_launch(void* const* d_in, const int* in_sizes, int n_in,
                              void* d_out, int out_size, void* d_ws, size_t ws_size,
                              hipStream_t stream) {
  const float* x  = (const float*)d_in[0];
  const float* y  = (const float*)d_in[1];
  const float* Wq = (const float*)d_in[2];
  const float* Dq = (const float*)d_in[3];
  const float* Wk = (const float*)d_in[4];
  const float* Dk = (const float*)d_in[5];
  const float* Wv = (const float*)d_in[6];
  const float* Dv = (const float*)d_in[7];
  float* out = (float*)d_out;

  char* wsb = (char*)d_ws;
  float*  yT  = (float*)wsb;                                   // 12,582,912 B
  double* sqd = (double*)(wsb + 12582912);                     //    262,144 B
  float*  sq  = (float*)(wsb + 12845056);                      //    131,072 B
  int*    knn = (int*)(wsb + 12976128);                        //  2,097,152 B
  ushort* hBs = (ushort*)(wsb + 15073280);                     //  6,291,456 B
  ushort* lBs = (ushort*)(wsb + 21364736);                     //  6,291,456 B
  float*  Ek  = (float*)(wsb + 27656192);                      //      8,192 B
  float*  Ev  = Ek + 2048;
  float*  Eq  = Ev + 2048;

  kE_combine<<<dim3(1), dim3(256), 0, stream>>>(Wk, Dk, Wv, Dv, Wq, Dq, Ek, Ev, Eq);
  kA_transpose<<<dim3(512), dim3(256), 0, stream>>>(y, yT, sq, sqd, hBs, lBs);
  kB_knn<<<dim3(2048), dim3(256), 0, stream>>>(yT, hBs, lBs, sq, sqd, knn);
  kC_main<<<dim3(4096), dim3(256), 0, stream>>>(x, yT, knn, Wq, Eq, Wk, Ek, Wv, Ev, out);
}

// Round 12
// 1288.049 us; speedup vs baseline: 1.3608x; 1.2102x over previous
//
#include <hip/hip_runtime.h>
#include <math.h>
#include <float.h>
#include <limits.h>

#define B_ 8
#define C_ 32
#define N_ 4096
#define K_ 16
#define L_ 20   // per-lane candidate list length (margin 4 over 16)

typedef __attribute__((ext_vector_type(8))) short bf16x8;
typedef __attribute__((ext_vector_type(4))) float f32x4;
#define MFMA16(a, b, c) __builtin_amdgcn_mfma_f32_16x16x32_bf16(a, b, c, 0, 0, 0)

// ------------------------------------------------------------------
// ws layout (bytes):
//   yT  : [B][N][96] float    12,582,912
//   sqd : [B][N]     double      262,144
//   sq  : [B][N]     float       131,072
//   knn : [B][N][16] int       2,097,152
//   hBs : swizzled bf16 hi     6,291,456   (frag-major: [g16][sl][lane][8])
//   lBs : swizzled bf16 lo     6,291,456
//   Ek/Ev/Eq floats               20,480
// ------------------------------------------------------------------

__global__ __launch_bounds__(256) void kE_combine(
    const float* __restrict__ Wk, const float* __restrict__ Dk,
    const float* __restrict__ Wv, const float* __restrict__ Dv,
    const float* __restrict__ Wq, const float* __restrict__ Dq,
    float* __restrict__ Ek, float* __restrict__ Ev, float* __restrict__ Eq) {
  int t = threadIdx.x;
  for (int e = t; e < 2048; e += 256) {
    int o = e >> 6, c = e & 63;
    float a = 0.f, v = 0.f;
    for (int m = 0; m < 32; ++m) {
      a = fmaf(Dk[o * 32 + m], Wk[m * 64 + c], a);
      v = fmaf(Dv[o * 32 + m], Wv[m * 64 + c], v);
    }
    Ek[e] = a; Ev[e] = v;
  }
  for (int e = t; e < 1024; e += 256) {
    int o = e >> 5, c = e & 31;
    float a = 0.f;
    for (int m = 0; m < 32; ++m) a = fmaf(Dq[o * 32 + m], Wq[m * 32 + c], a);
    Eq[e] = a;
  }
}

// transpose y -> yT; sq fp32; sqd fp64; hBs/lBs = bf16 hi/lo split stored
// FRAGMENT-MAJOR: addr = ((g16*3 + sl)*64 + lane)*8 + e, lane=(fg<<4)|fm,
// point n = g16*16+fm, k-dim d = sl*32 + fg*8 + e.
__global__ __launch_bounds__(256) void kA_transpose(
    const float* __restrict__ y, float* __restrict__ yT,
    float* __restrict__ sq, double* __restrict__ sqd,
    ushort* __restrict__ hBs, ushort* __restrict__ lBs) {
  __shared__ float tile[96][65];
  int b = blockIdx.x >> 6;
  int n0 = (blockIdx.x & 63) * 64;
  int t = threadIdx.x;
  int g = t >> 6, ln = t & 63;
  #pragma unroll
  for (int r = 0; r < 24; ++r) {
    int d = g * 24 + r;
    tile[d][ln] = y[((size_t)b * 96 + d) * N_ + n0 + ln];
  }
  __syncthreads();
  if (t < 64) {
    float s = 0.f; double sd = 0.0;
    #pragma unroll
    for (int d = 0; d < 96; ++d) {
      float v = tile[d][t];
      s = fmaf(v, v, s);
      sd += (double)v * (double)v;
    }
    sq[b * N_ + n0 + t] = s;
    sqd[b * N_ + n0 + t] = sd;
  }
  for (int idx = t; idx < 64 * 96; idx += 256) {
    int nl = idx / 96, d = idx % 96;
    yT[((size_t)b * N_ + n0 + nl) * 96 + d] = tile[d][nl];
  }
  for (int idx = t; idx < 768; idx += 256) {
    int g16l = idx / 192;
    int rem = idx - g16l * 192;
    int sl = rem >> 6;
    int ln2 = rem & 63;
    int fg2 = ln2 >> 4, fm2 = ln2 & 15;
    int nl = g16l * 16 + fm2;
    uint hw[4], lw[4];
    #pragma unroll
    for (int e2 = 0; e2 < 4; ++e2) {
      float v0 = tile[sl * 32 + fg2 * 8 + 2 * e2][nl];
      float v1 = tile[sl * 32 + fg2 * 8 + 2 * e2 + 1][nl];
      uint x0 = __float_as_uint(v0), x1 = __float_as_uint(v1);
      uint h0 = x0 >> 16, h1 = x1 >> 16;
      float r0 = v0 - __uint_as_float(h0 << 16);
      float r1 = v1 - __uint_as_float(h1 << 16);
      uint l0 = __float_as_uint(r0) >> 16, l1 = __float_as_uint(r1) >> 16;
      hw[e2] = h0 | (h1 << 16);
      lw[e2] = l0 | (l1 << 16);
    }
    size_t off = (size_t)b * 393216 +
                 (((size_t)(n0 >> 4) + g16l) * 3 + sl) * 512 + (size_t)ln2 * 8;
    *(uint4*)(hBs + off) = make_uint4(hw[0], hw[1], hw[2], hw[3]);
    *(uint4*)(lBs + off) = make_uint4(lw[0], lw[1], lw[2], lw[3]);
  }
}

// Named-register top-20 (rule #20: arrays demote to scratch; this chain
// stays in VGPRs - proven 3.7x in round 9).
#define DECL20 \
  float v0=-FLT_MAX,v1=-FLT_MAX,v2=-FLT_MAX,v3=-FLT_MAX,v4=-FLT_MAX, \
        v5=-FLT_MAX,v6=-FLT_MAX,v7=-FLT_MAX,v8=-FLT_MAX,v9=-FLT_MAX, \
        v10=-FLT_MAX,v11=-FLT_MAX,v12=-FLT_MAX,v13=-FLT_MAX,v14=-FLT_MAX, \
        v15=-FLT_MAX,v16=-FLT_MAX,v17=-FLT_MAX,v18=-FLT_MAX,v19=-FLT_MAX; \
  int y0=0,y1=0,y2=0,y3=0,y4=0,y5=0,y6=0,y7=0,y8=0,y9=0, \
      y10=0,y11=0,y12=0,y13=0,y14=0,y15=0,y16=0,y17=0,y18=0,y19=0;

#define CX(i) { bool cc = cv > v##i; \
  float tf = cc ? v##i : cv; int ti = cc ? y##i : ci; \
  v##i = cc ? cv : v##i; y##i = cc ? ci : y##i; cv = tf; ci = ti; }

#define INSERT20 { CX(0) CX(1) CX(2) CX(3) CX(4) CX(5) CX(6) CX(7) CX(8) CX(9) \
  CX(10) CX(11) CX(12) CX(13) CX(14) CX(15) CX(16) CX(17) CX(18) CX(19) }

// kNN: block = 16 queries x 4 j-chunk waves (2048 blocks, 8192 waves).
// LDS 36.6KB -> 4 blocks/CU = 16 waves/CU.
__global__ __launch_bounds__(256) void kB_knn(
    const float* __restrict__ yT, const ushort* __restrict__ hBs,
    const ushort* __restrict__ lBs, const float* __restrict__ sq,
    const double* __restrict__ sqd, int* __restrict__ knn) {
  __shared__ float  lv[4][4][16][L_ + 1];   // [w][fg][fm][slot]   21,504 B
  __shared__ ushort liu[4][4][16][L_ + 2];  //                     11,264 B
  __shared__ int    mid[16][L_];            //                      1,280 B
  __shared__ double rv[16][L_];             //                      2,560 B

  const int t = threadIdx.x;
  const int lane = t & 63;
  const int w = t >> 6;
  const int fg = lane >> 4, fm = lane & 15;
  const int b = blockIdx.x & 7;             // XCD-friendly batch pinning
  const int qg = blockIdx.x >> 3;           // 0..255
  const int q = qg * 16 + fm;
  const size_t bN = (size_t)b * N_;
  const ushort* hb = hBs + bN * 96;
  const ushort* lb = lBs + bN * 96;
  const float* sqb = sq + bN;
  const float sqi = sqb[q];

  // resident query frags (B operand): h and l, 3 k-segments each
  const ushort* hqb = hb + (size_t)qg * 1536 + (size_t)lane * 8;
  const ushort* lqb = lb + (size_t)qg * 1536 + (size_t)lane * 8;
  const bf16x8 qh0 = *(const bf16x8*)(hqb);
  const bf16x8 qh1 = *(const bf16x8*)(hqb + 512);
  const bf16x8 qh2 = *(const bf16x8*)(hqb + 1024);
  const bf16x8 ql0 = *(const bf16x8*)(lqb);
  const bf16x8 ql1 = *(const bf16x8*)(lqb + 512);
  const bf16x8 ql2 = *(const bf16x8*)(lqb + 1024);

  DECL20

  const int jchunk = w * 1024;
  #pragma unroll 1
  for (int jt = 0; jt < 16; ++jt) {
    const int g16 = (jchunk >> 4) + jt * 4;
    const ushort* hpb = hb + (size_t)g16 * 1536 + (size_t)lane * 8;
    const ushort* lpb = lb + (size_t)g16 * 1536 + (size_t)lane * 8;
    #pragma unroll
    for (int jb = 0; jb < 4; ++jb) {
      const ushort* ph = hpb + jb * 1536;
      const ushort* pl = lpb + jb * 1536;
      const bf16x8 a0 = *(const bf16x8*)(ph);
      const bf16x8 a1 = *(const bf16x8*)(ph + 512);
      const bf16x8 a2 = *(const bf16x8*)(ph + 1024);
      const bf16x8 b0 = *(const bf16x8*)(pl);
      const bf16x8 b1 = *(const bf16x8*)(pl + 512);
      const bf16x8 b2 = *(const bf16x8*)(pl + 1024);
      f32x4 c = {0.f, 0.f, 0.f, 0.f};
      c = MFMA16(a0, qh0, c);   // h_j . h_q
      c = MFMA16(a1, qh1, c);
      c = MFMA16(a2, qh2, c);
      c = MFMA16(a0, ql0, c);   // h_j . l_q
      c = MFMA16(a1, ql1, c);
      c = MFMA16(a2, ql2, c);
      c = MFMA16(b0, qh0, c);   // l_j . h_q
      c = MFMA16(b1, qh1, c);
      c = MFMA16(b2, qh2, c);
      const int jbase = jchunk + jt * 64 + jb * 16 + fg * 4;
      const float4 s4 = *(const float4*)(sqb + jbase);
      #pragma unroll
      for (int r = 0; r < 4; ++r) {
        const float sj = r == 0 ? s4.x : r == 1 ? s4.y : r == 2 ? s4.z : s4.w;
        const float neg = 2.f * c[r] - sqi - sj;
        if (neg > v19) {                 // strict >: earlier index wins ties
          float cv = neg; int ci = jbase + r;
          INSERT20
        }
      }
    }
  }

  // ---- per-lane sorted lists + sentinel ----
  {
    float* lvp = &lv[w][fg][fm][0];
    ushort* lip = &liu[w][fg][fm][0];
    lvp[0]=v0; lvp[1]=v1; lvp[2]=v2; lvp[3]=v3; lvp[4]=v4;
    lvp[5]=v5; lvp[6]=v6; lvp[7]=v7; lvp[8]=v8; lvp[9]=v9;
    lvp[10]=v10; lvp[11]=v11; lvp[12]=v12; lvp[13]=v13; lvp[14]=v14;
    lvp[15]=v15; lvp[16]=v16; lvp[17]=v17; lvp[18]=v18; lvp[19]=v19;
    lvp[20]=-FLT_MAX;
    lip[0]=(ushort)y0; lip[1]=(ushort)y1; lip[2]=(ushort)y2; lip[3]=(ushort)y3;
    lip[4]=(ushort)y4; lip[5]=(ushort)y5; lip[6]=(ushort)y6; lip[7]=(ushort)y7;
    lip[8]=(ushort)y8; lip[9]=(ushort)y9; lip[10]=(ushort)y10; lip[11]=(ushort)y11;
    lip[12]=(ushort)y12; lip[13]=(ushort)y13; lip[14]=(ushort)y14; lip[15]=(ushort)y15;
    lip[16]=(ushort)y16; lip[17]=(ushort)y17; lip[18]=(ushort)y18; lip[19]=(ushort)y19;
    lip[20]=0xFFFFu;
  }
  __syncthreads();

  // ---- 16-way exact merge (threads 0..15, one per query) ----
  if (t < 16) {
    int p[16];
    #pragma unroll
    for (int c2 = 0; c2 < 16; ++c2) p[c2] = 0;
    #pragma unroll 1
    for (int r = 0; r < L_; ++r) {
      float bv = -FLT_MAX; int bi2 = INT_MAX; int bc = 0;
      #pragma unroll
      for (int c2 = 0; c2 < 16; ++c2) {
        float v = lv[c2 >> 2][c2 & 3][t][p[c2]];
        int  id = (int)liu[c2 >> 2][c2 & 3][t][p[c2]];
        if (v > bv || (v == bv && id < bi2)) { bv = v; bi2 = id; bc = c2; }
      }
      mid[t][r] = bi2;
      #pragma unroll
      for (int c2 = 0; c2 < 16; ++c2) p[c2] += (bc == c2);
    }
  }
  __syncthreads();

  // ---- fp64 exact re-score: 320 tasks (16 q x 20 cand) ----
  {
    const double* sqdb = sqd + bN;
    const float* yTb = yT + bN * 96;
    #pragma unroll 1
    for (int task = t; task < 16 * L_; task += 256) {
      const int fq = task / L_, slot = task - fq * L_;
      const int qq = qg * 16 + fq;
      const int j = mid[fq][slot];
      const float4* q4p = (const float4*)(yTb + (size_t)qq * 96);
      const float4* p4p = (const float4*)(yTb + (size_t)j * 96);
      double a0 = 0.0, a1 = 0.0, a2 = 0.0, a3 = 0.0;
      #pragma unroll 4
      for (int m = 0; m < 24; ++m) {
        float4 qm = q4p[m], pm = p4p[m];
        a0 += (double)qm.x * (double)pm.x;
        a1 += (double)qm.y * (double)pm.y;
        a2 += (double)qm.z * (double)pm.z;
        a3 += (double)qm.w * (double)pm.w;
      }
      rv[fq][slot] = 2.0 * ((a0 + a1) + (a2 + a3)) - sqdb[qq] - sqdb[j];
    }
  }
  __syncthreads();

  // ---- final exact sorted top-16 (threads 0..15) ----
  if (t < 16) {
    double bd[16]; int bix[16];
    #pragma unroll
    for (int i = 0; i < 16; ++i) { bd[i] = -DBL_MAX; bix[i] = INT_MAX; }
    #pragma unroll 1
    for (int r = 0; r < L_; ++r) {
      double v = rv[t][r]; int id = mid[t][r];
      if (v > bd[15] || (v == bd[15] && id < bix[15])) {
        #pragma unroll
        for (int i = 0; i < 16; ++i) {
          if (v > bd[i] || (v == bd[i] && id < bix[i])) {
            double tv = bd[i]; bd[i] = v; v = tv;
            int ti = bix[i]; bix[i] = id; id = ti;
          }
        }
      }
    }
    int* outp = knn + (bN + (size_t)(qg * 16 + t)) * 16;
    #pragma unroll
    for (int r = 0; r < 16; ++r) outp[r] = bix[r];
  }
}

__device__ __forceinline__ float f4e(const float4& v, int i) {
  return i == 0 ? v.x : i == 1 ? v.y : i == 2 ? v.z : v.w;
}

// Fused main: round-9 version (separate weight buffers loaded once, no
// phase barriers, two-pass) — measured ~430us across rounds 6-9.
// r10 fusion (VGPR 240) and r11 phase-reuse (barrier serialization,
// VGPR 132 > 128 boundary) were both slower.
__global__ __launch_bounds__(256) void kC_main(
    const float* __restrict__ x, const float* __restrict__ yT,
    const int* __restrict__ knn,
    const float* __restrict__ Wq, const float* __restrict__ Eq,
    const float* __restrict__ Wk, const float* __restrict__ Ek,
    const float* __restrict__ Wv, const float* __restrict__ Ev,
    float* __restrict__ out) {
  __shared__ float4 sWq[8 * 32], sEq[8 * 32];
  __shared__ float4 sWk[16 * 32], sEk[16 * 32], sWv[16 * 32], sEv[16 * 32];
  __shared__ float sOut[8][97];

  int t = threadIdx.x;
  {
    int e = t;
    int c4 = e >> 5, o = e & 31;
    sWq[e] = ((const float4*)(Wq + o * 32))[c4];
    sEq[e] = ((const float4*)(Eq + o * 32))[c4];
  }
  for (int e = t; e < 512; e += 256) {
    int c4 = e >> 5, o = e & 31;
    sWk[e] = ((const float4*)(Wk + o * 64))[c4];
    sEk[e] = ((const float4*)(Ek + o * 64))[c4];
    sWv[e] = ((const float4*)(Wv + o * 64))[c4];
    sEv[e] = ((const float4*)(Ev + o * 64))[c4];
  }
  __syncthreads();

  int q = t >> 5, o = t & 31;
  int bno = blockIdx.x;
  int b = bno >> 9;
  int n = ((bno & 511) << 3) + q;
  int h = o >> 4, kk_mine = o & 15;

  const float* xb = x + (size_t)b * 96 * N_ + n;
  float pq[3] = {0, 0, 0}, dq[3] = {0, 0, 0};
  #pragma unroll
  for (int c4 = 0; c4 < 8; ++c4) {
    float4 wq = sWq[c4 * 32 + o], eq = sEq[c4 * 32 + o];
    #pragma unroll
    for (int i = 0; i < 4; ++i) {
      int c = c4 * 4 + i;
      float w = f4e(wq, i), e2 = f4e(eq, i);
      #pragma unroll
      for (int d = 0; d < 3; ++d) {
        float xv = xb[(size_t)(c * 3 + d) * N_];
        pq[d] = fmaf(w, xv, pq[d]);
        dq[d] = fmaf(e2, xv, dq[d]);
      }
    }
  }
  float Qx[3];
  {
    float dot = pq[0] * dq[0] + pq[1] * dq[1] + pq[2] * dq[2];
    float dsq = dq[0] * dq[0] + dq[1] * dq[1] + dq[2] * dq[2] + 1e-6f;
    float r = dot / dsq;
    float qv[3];
    #pragma unroll
    for (int d = 0; d < 3; ++d) {
      float pn = pq[d] - r * dq[d];
      qv[d] = 0.2f * pq[d] + 0.8f * (dot >= 0.f ? pq[d] : pn);
    }
    float nn = sqrtf(qv[0] * qv[0] + qv[1] * qv[1] + qv[2] * qv[2]);
    float nch2 = nn * nn;
    #pragma unroll
    for (int m = 1; m <= 16; m <<= 1) nch2 += __shfl_xor(nch2, m, 32);
    float s = (nn / fmaxf(sqrtf(nch2), 1e-12f)) / fmaxf(nn, 1e-12f);
    #pragma unroll
    for (int d = 0; d < 3; ++d) Qx[d] = qv[d] * s;
  }

  const float* ctr = yT + ((size_t)b * N_ + n) * 96;
  const int* kidx = knn + ((size_t)b * N_ + n) * 16;

  float pck[3] = {0, 0, 0}, dck[3] = {0, 0, 0};
  #pragma unroll
  for (int c4 = 0; c4 < 8; ++c4) {
    float4 wlo = sWk[c4 * 32 + o], whi = sWk[(c4 + 8) * 32 + o];
    float4 elo = sEk[c4 * 32 + o], ehi = sEk[(c4 + 8) * 32 + o];
    float4 c0 = ((const float4*)ctr)[c4 * 3 + 0];
    float4 c1 = ((const float4*)ctr)[c4 * 3 + 1];
    float4 c2 = ((const float4*)ctr)[c4 * 3 + 2];
    float cv[12] = {c0.x, c0.y, c0.z, c0.w, c1.x, c1.y, c1.z, c1.w, c2.x, c2.y, c2.z, c2.w};
    #pragma unroll
    for (int v = 0; v < 12; ++v) {
      int cl = v / 3, d = v % 3;
      pck[d] = fmaf(f4e(whi, cl) - f4e(wlo, cl), cv[v], pck[d]);
      dck[d] = fmaf(f4e(ehi, cl) - f4e(elo, cl), cv[v], dck[d]);
    }
  }

  float myscore = 0.f;
  #pragma unroll 1
  for (int k = 0; k < 16; ++k) {
    int jn = kidx[k];
    const float* nb = yT + ((size_t)b * N_ + jn) * 96;
    float p[3] = {pck[0], pck[1], pck[2]}, dd[3] = {dck[0], dck[1], dck[2]};
    #pragma unroll
    for (int c4 = 0; c4 < 8; ++c4) {
      float4 w = sWk[c4 * 32 + o], e = sEk[c4 * 32 + o];
      float4 n0 = ((const float4*)nb)[c4 * 3 + 0];
      float4 n1 = ((const float4*)nb)[c4 * 3 + 1];
      float4 n2 = ((const float4*)nb)[c4 * 3 + 2];
      float nv[12] = {n0.x, n0.y, n0.z, n0.w, n1.x, n1.y, n1.z, n1.w, n2.x, n2.y, n2.z, n2.w};
      #pragma unroll
      for (int v = 0; v < 12; ++v) {
        int cl = v / 3, d = v % 3;
        p[d]  = fmaf(f4e(w, cl), nv[v], p[d]);
        dd[d] = fmaf(f4e(e, cl), nv[v], dd[d]);
      }
    }
    float dot = p[0] * dd[0] + p[1] * dd[1] + p[2] * dd[2];
    float dsq = dd[0] * dd[0] + dd[1] * dd[1] + dd[2] * dd[2] + 1e-6f;
    float r = dot / dsq;
    float ky[3];
    #pragma unroll
    for (int d = 0; d < 3; ++d) {
      float pn = p[d] - r * dd[d];
      ky[d] = 0.2f * p[d] + 0.8f * (dot >= 0.f ? p[d] : pn);
    }
    float nn = sqrtf(ky[0] * ky[0] + ky[1] * ky[1] + ky[2] * ky[2]);
    float nch2 = nn * nn;
    #pragma unroll
    for (int m = 1; m <= 16; m <<= 1) nch2 += __shfl_xor(nch2, m, 32);
    float s = (1.f / fmaxf(sqrtf(nch2), 1e-12f)) * (nn / fmaxf(nn, 1e-12f));
    float qk = (ky[0] * Qx[0] + ky[1] * Qx[1] + ky[2] * Qx[2]) * s;
    #pragma unroll
    for (int m = 1; m <= 8; m <<= 1) qk += __shfl_xor(qk, m, 32);
    float score = qk * 0.14433756729740643f;   // 1/sqrt(48)
    if (kk_mine == k) myscore = score;
  }

  float att_mine;
  {
    float mx = myscore;
    #pragma unroll
    for (int m = 1; m <= 8; m <<= 1) mx = fmaxf(mx, __shfl_xor(mx, m, 32));
    float ex = expf(myscore - mx);
    float ss = ex;
    #pragma unroll
    for (int m = 1; m <= 8; m <<= 1) ss += __shfl_xor(ss, m, 32);
    att_mine = ex / ss;
  }

  float pcv[3] = {0, 0, 0}, dcv[3] = {0, 0, 0};
  #pragma unroll
  for (int c4 = 0; c4 < 8; ++c4) {
    float4 wlo = sWv[c4 * 32 + o], whi = sWv[(c4 + 8) * 32 + o];
    float4 elo = sEv[c4 * 32 + o], ehi = sEv[(c4 + 8) * 32 + o];
    float4 c0 = ((const float4*)ctr)[c4 * 3 + 0];
    float4 c1 = ((const float4*)ctr)[c4 * 3 + 1];
    float4 c2 = ((const float4*)ctr)[c4 * 3 + 2];
    float cv[12] = {c0.x, c0.y, c0.z, c0.w, c1.x, c1.y, c1.z, c1.w, c2.x, c2.y, c2.z, c2.w};
    #pragma unroll
    for (int v = 0; v < 12; ++v) {
      int cl = v / 3, d = v % 3;
      pcv[d] = fmaf(f4e(whi, cl) - f4e(wlo, cl), cv[v], pcv[d]);
      dcv[d] = fmaf(f4e(ehi, cl) - f4e(elo, cl), cv[v], dcv[d]);
    }
  }
  float acc[3] = {0, 0, 0};
  #pragma unroll 1
  for (int k = 0; k < 16; ++k) {
    int jn = kidx[k];
    const float* nb = yT + ((size_t)b * N_ + jn) * 96;
    float p[3] = {pcv[0], pcv[1], pcv[2]}, dd[3] = {dcv[0], dcv[1], dcv[2]};
    #pragma unroll
    for (int c4 = 0; c4 < 8; ++c4) {
      float4 w = sWv[c4 * 32 + o], e = sEv[c4 * 32 + o];
      float4 n0 = ((const float4*)nb)[c4 * 3 + 0];
      float4 n1 = ((const float4*)nb)[c4 * 3 + 1];
      float4 n2 = ((const float4*)nb)[c4 * 3 + 2];
      float nv[12] = {n0.x, n0.y, n0.z, n0.w, n1.x, n1.y, n1.z, n1.w, n2.x, n2.y, n2.z, n2.w};
      #pragma unroll
      for (int v = 0; v < 12; ++v) {
        int cl = v / 3, d = v % 3;
        p[d]  = fmaf(f4e(w, cl), nv[v], p[d]);
        dd[d] = fmaf(f4e(e, cl), nv[v], dd[d]);
      }
    }
    float dot = p[0] * dd[0] + p[1] * dd[1] + p[2] * dd[2];
    float dsq = dd[0] * dd[0] + dd[1] * dd[1] + dd[2] * dd[2] + 1e-6f;
    float r = dot / dsq;
    float attk = __shfl(att_mine, h * 16 + k, 32);
    #pragma unroll
    for (int d = 0; d < 3; ++d) {
      float pn = p[d] - r * dd[d];
      float vy = 0.2f * p[d] + 0.8f * (dot >= 0.f ? p[d] : pn);
      acc[d] = fmaf(attk, vy, acc[d]);
    }
  }

  #pragma unroll
  for (int d = 0; d < 3; ++d) sOut[q][o * 3 + d] = acc[d];
  __syncthreads();
  int nl = t & 7;
  int n_out = ((bno & 511) << 3) + nl;
  #pragma unroll
  for (int it = 0; it < 3; ++it) {
    int od = it * 32 + (t >> 3);
    size_t a = (size_t)b * 96 * N_ + (size_t)od * N_ + n_out;
    out[a] = x[a] + sOut[nl][od];
  }
}

extern "C" void kernel_launch(void* const* d_in, const int* in_sizes, int n_in,
                              void* d_out, int out_size, void* d_ws, size_t ws_size,
                              hipStream_t stream) {
  const float* x  = (const float*)d_in[0];
  const float* y  = (const float*)d_in[1];
  const float* Wq = (const float*)d_in[2];
  const float* Dq = (const float*)d_in[3];
  const float* Wk = (const float*)d_in[4];
  const float* Dk = (const float*)d_in[5];
  const float* Wv = (const float*)d_in[6];
  const float* Dv = (const float*)d_in[7];
  float* out = (float*)d_out;

  char* wsb = (char*)d_ws;
  float*  yT  = (float*)wsb;                                   // 12,582,912 B
  double* sqd = (double*)(wsb + 12582912);                     //    262,144 B
  float*  sq  = (float*)(wsb + 12845056);                      //    131,072 B
  int*    knn = (int*)(wsb + 12976128);                        //  2,097,152 B
  ushort* hBs = (ushort*)(wsb + 15073280);                     //  6,291,456 B
  ushort* lBs = (ushort*)(wsb + 21364736);                     //  6,291,456 B
  float*  Ek  = (float*)(wsb + 27656192);                      //      8,192 B
  float*  Ev  = Ek + 2048;
  float*  Eq  = Ev + 2048;

  kE_combine<<<dim3(1), dim3(256), 0, stream>>>(Wk, Dk, Wv, Dv, Wq, Dq, Ek, Ev, Eq);
  kA_transpose<<<dim3(512), dim3(256), 0, stream>>>(y, yT, sq, sqd, hBs, lBs);
  kB_knn<<<dim3(2048), dim3(256), 0, stream>>>(yT, hBs, lBs, sq, sqd, knn);
  kC_main<<<dim3(4096), dim3(256), 0, stream>>>(x, yT, knn, Wq, Eq, Wk, Ek, Wv, Ev, out);
}

// Round 13
// 888.102 us; speedup vs baseline: 1.9737x; 1.4503x over previous
//
#include <hip/hip_runtime.h>
#include <math.h>
#include <float.h>
#include <limits.h>

#define B_ 8
#define C_ 32
#define N_ 4096
#define K_ 16
#define L_ 20   // merged candidate depth (fp32-inversion margin 4, proven)
#define LL 12   // per-lane register list depth (lane-capacity margin, see note)

typedef __attribute__((ext_vector_type(8))) short bf16x8;
typedef __attribute__((ext_vector_type(4))) float f32x4;
#define MFMA16(a, b, c) __builtin_amdgcn_mfma_f32_16x16x32_bf16(a, b, c, 0, 0, 0)

// ------------------------------------------------------------------
// ws layout (bytes):
//   yT  : [B][N][96] float    12,582,912
//   sqd : [B][N]     double      262,144
//   sq  : [B][N]     float       131,072
//   knn : [B][N][16] int       2,097,152
//   hBs : swizzled bf16 hi     6,291,456   (frag-major: [g16][sl][lane][8])
//   lBs : swizzled bf16 lo     6,291,456
//   Ek/Ev/Eq floats               20,480
// ------------------------------------------------------------------

__global__ __launch_bounds__(256) void kE_combine(
    const float* __restrict__ Wk, const float* __restrict__ Dk,
    const float* __restrict__ Wv, const float* __restrict__ Dv,
    const float* __restrict__ Wq, const float* __restrict__ Dq,
    float* __restrict__ Ek, float* __restrict__ Ev, float* __restrict__ Eq) {
  int t = threadIdx.x;
  for (int e = t; e < 2048; e += 256) {
    int o = e >> 6, c = e & 63;
    float a = 0.f, v = 0.f;
    for (int m = 0; m < 32; ++m) {
      a = fmaf(Dk[o * 32 + m], Wk[m * 64 + c], a);
      v = fmaf(Dv[o * 32 + m], Wv[m * 64 + c], v);
    }
    Ek[e] = a; Ev[e] = v;
  }
  for (int e = t; e < 1024; e += 256) {
    int o = e >> 5, c = e & 31;
    float a = 0.f;
    for (int m = 0; m < 32; ++m) a = fmaf(Dq[o * 32 + m], Wq[m * 32 + c], a);
    Eq[e] = a;
  }
}

// transpose y -> yT; sq fp32; sqd fp64; hBs/lBs = bf16 hi/lo split stored
// FRAGMENT-MAJOR: addr = ((g16*3 + sl)*64 + lane)*8 + e, lane=(fg<<4)|fm,
// point n = g16*16+fm, k-dim d = sl*32 + fg*8 + e.
__global__ __launch_bounds__(256) void kA_transpose(
    const float* __restrict__ y, float* __restrict__ yT,
    float* __restrict__ sq, double* __restrict__ sqd,
    ushort* __restrict__ hBs, ushort* __restrict__ lBs) {
  __shared__ float tile[96][65];
  int b = blockIdx.x >> 6;
  int n0 = (blockIdx.x & 63) * 64;
  int t = threadIdx.x;
  int g = t >> 6, ln = t & 63;
  #pragma unroll
  for (int r = 0; r < 24; ++r) {
    int d = g * 24 + r;
    tile[d][ln] = y[((size_t)b * 96 + d) * N_ + n0 + ln];
  }
  __syncthreads();
  if (t < 64) {
    float s = 0.f; double sd = 0.0;
    #pragma unroll
    for (int d = 0; d < 96; ++d) {
      float v = tile[d][t];
      s = fmaf(v, v, s);
      sd += (double)v * (double)v;
    }
    sq[b * N_ + n0 + t] = s;
    sqd[b * N_ + n0 + t] = sd;
  }
  for (int idx = t; idx < 64 * 96; idx += 256) {
    int nl = idx / 96, d = idx % 96;
    yT[((size_t)b * N_ + n0 + nl) * 96 + d] = tile[d][nl];
  }
  for (int idx = t; idx < 768; idx += 256) {
    int g16l = idx / 192;
    int rem = idx - g16l * 192;
    int sl = rem >> 6;
    int ln2 = rem & 63;
    int fg2 = ln2 >> 4, fm2 = ln2 & 15;
    int nl = g16l * 16 + fm2;
    uint hw[4], lw[4];
    #pragma unroll
    for (int e2 = 0; e2 < 4; ++e2) {
      float v0 = tile[sl * 32 + fg2 * 8 + 2 * e2][nl];
      float v1 = tile[sl * 32 + fg2 * 8 + 2 * e2 + 1][nl];
      uint x0 = __float_as_uint(v0), x1 = __float_as_uint(v1);
      uint h0 = x0 >> 16, h1 = x1 >> 16;
      float r0 = v0 - __uint_as_float(h0 << 16);
      float r1 = v1 - __uint_as_float(h1 << 16);
      uint l0 = __float_as_uint(r0) >> 16, l1 = __float_as_uint(r1) >> 16;
      hw[e2] = h0 | (h1 << 16);
      lw[e2] = l0 | (l1 << 16);
    }
    size_t off = (size_t)b * 393216 +
                 (((size_t)(n0 >> 4) + g16l) * 3 + sl) * 512 + (size_t)ln2 * 8;
    *(uint4*)(hBs + off) = make_uint4(hw[0], hw[1], hw[2], hw[3]);
    *(uint4*)(lBs + off) = make_uint4(lw[0], lw[1], lw[2], lw[3]);
  }
}

// Named-register top-12. Round-12 evidence: VGPR=52 << live set (~105 with
// top-20 lists) => lists still partially spilled. LL=12 shrinks the list to
// 24 regs so the whole live set (~90) fits the 128-VGPR tier.
// Exactness: per-lane top-12 contains the lane's share of the global
// fp32-top-20 unless >=13 of 20 land in one of 16 lanes (P ~ 1.7e-11/query).
// Merge still extracts top-20 (proven fp32 margin); fp64 backend unchanged.
#define DECL12 \
  float v0=-FLT_MAX,v1=-FLT_MAX,v2=-FLT_MAX,v3=-FLT_MAX,v4=-FLT_MAX, \
        v5=-FLT_MAX,v6=-FLT_MAX,v7=-FLT_MAX,v8=-FLT_MAX,v9=-FLT_MAX, \
        v10=-FLT_MAX,v11=-FLT_MAX; \
  int y0=0,y1=0,y2=0,y3=0,y4=0,y5=0,y6=0,y7=0,y8=0,y9=0,y10=0,y11=0;

#define CX(i) { bool cc = cv > v##i; \
  float tf = cc ? v##i : cv; int ti = cc ? y##i : ci; \
  v##i = cc ? cv : v##i; y##i = cc ? ci : y##i; cv = tf; ci = ti; }

#define INSERT12 { CX(0) CX(1) CX(2) CX(3) CX(4) CX(5) CX(6) CX(7) CX(8) CX(9) \
  CX(10) CX(11) }

// kNN: block = 16 queries x 4 j-chunk waves (2048 blocks, 8192 waves).
__global__ __launch_bounds__(256) void kB_knn(
    const float* __restrict__ yT, const ushort* __restrict__ hBs,
    const ushort* __restrict__ lBs, const float* __restrict__ sq,
    const double* __restrict__ sqd, int* __restrict__ knn) {
  __shared__ float  lv[4][4][16][LL + 1];   // [w][fg][fm][slot]   13,312 B
  __shared__ ushort liu[4][4][16][LL + 2];  //                      7,168 B
  __shared__ int    mid[16][L_];            //                      1,280 B
  __shared__ double rv[16][L_];             //                      2,560 B

  const int t = threadIdx.x;
  const int lane = t & 63;
  const int w = t >> 6;
  const int fg = lane >> 4, fm = lane & 15;
  const int b = blockIdx.x & 7;             // XCD-friendly batch pinning
  const int qg = blockIdx.x >> 3;           // 0..255
  const int q = qg * 16 + fm;
  const size_t bN = (size_t)b * N_;
  const ushort* hb = hBs + bN * 96;
  const ushort* lb = lBs + bN * 96;
  const float* sqb = sq + bN;
  const float sqi = sqb[q];

  // resident query frags (B operand): h and l, 3 k-segments each
  const ushort* hqb = hb + (size_t)qg * 1536 + (size_t)lane * 8;
  const ushort* lqb = lb + (size_t)qg * 1536 + (size_t)lane * 8;
  const bf16x8 qh0 = *(const bf16x8*)(hqb);
  const bf16x8 qh1 = *(const bf16x8*)(hqb + 512);
  const bf16x8 qh2 = *(const bf16x8*)(hqb + 1024);
  const bf16x8 ql0 = *(const bf16x8*)(lqb);
  const bf16x8 ql1 = *(const bf16x8*)(lqb + 512);
  const bf16x8 ql2 = *(const bf16x8*)(lqb + 1024);

  DECL12

  const int jchunk = w * 1024;
  #pragma unroll 1
  for (int jt = 0; jt < 16; ++jt) {
    const int g16 = (jchunk >> 4) + jt * 4;
    const ushort* hpb = hb + (size_t)g16 * 1536 + (size_t)lane * 8;
    const ushort* lpb = lb + (size_t)g16 * 1536 + (size_t)lane * 8;
    #pragma unroll
    for (int jb = 0; jb < 4; ++jb) {
      const ushort* ph = hpb + jb * 1536;
      const ushort* pl = lpb + jb * 1536;
      const bf16x8 a0 = *(const bf16x8*)(ph);
      const bf16x8 a1 = *(const bf16x8*)(ph + 512);
      const bf16x8 a2 = *(const bf16x8*)(ph + 1024);
      const bf16x8 b0 = *(const bf16x8*)(pl);
      const bf16x8 b1 = *(const bf16x8*)(pl + 512);
      const bf16x8 b2 = *(const bf16x8*)(pl + 1024);
      f32x4 c = {0.f, 0.f, 0.f, 0.f};
      c = MFMA16(a0, qh0, c);   // h_j . h_q
      c = MFMA16(a1, qh1, c);
      c = MFMA16(a2, qh2, c);
      c = MFMA16(a0, ql0, c);   // h_j . l_q
      c = MFMA16(a1, ql1, c);
      c = MFMA16(a2, ql2, c);
      c = MFMA16(b0, qh0, c);   // l_j . h_q
      c = MFMA16(b1, qh1, c);
      c = MFMA16(b2, qh2, c);
      const int jbase = jchunk + jt * 64 + jb * 16 + fg * 4;
      const float4 s4 = *(const float4*)(sqb + jbase);
      #pragma unroll
      for (int r = 0; r < 4; ++r) {
        const float sj = r == 0 ? s4.x : r == 1 ? s4.y : r == 2 ? s4.z : s4.w;
        const float neg = 2.f * c[r] - sqi - sj;
        if (neg > v11) {                 // strict >: earlier index wins ties
          float cv = neg; int ci = jbase + r;
          INSERT12
        }
      }
    }
  }

  // ---- per-lane sorted lists + sentinel ----
  {
    float* lvp = &lv[w][fg][fm][0];
    ushort* lip = &liu[w][fg][fm][0];
    lvp[0]=v0; lvp[1]=v1; lvp[2]=v2; lvp[3]=v3; lvp[4]=v4;
    lvp[5]=v5; lvp[6]=v6; lvp[7]=v7; lvp[8]=v8; lvp[9]=v9;
    lvp[10]=v10; lvp[11]=v11;
    lvp[12]=-FLT_MAX;
    lip[0]=(ushort)y0; lip[1]=(ushort)y1; lip[2]=(ushort)y2; lip[3]=(ushort)y3;
    lip[4]=(ushort)y4; lip[5]=(ushort)y5; lip[6]=(ushort)y6; lip[7]=(ushort)y7;
    lip[8]=(ushort)y8; lip[9]=(ushort)y9; lip[10]=(ushort)y10; lip[11]=(ushort)y11;
    lip[12]=0xFFFFu;
  }
  __syncthreads();

  // ---- 16-way exact merge (threads 0..15, one per query): top-20 ----
  if (t < 16) {
    int p[16];
    #pragma unroll
    for (int c2 = 0; c2 < 16; ++c2) p[c2] = 0;
    #pragma unroll 1
    for (int r = 0; r < L_; ++r) {
      float bv = -FLT_MAX; int bi2 = INT_MAX; int bc = 0;
      #pragma unroll
      for (int c2 = 0; c2 < 16; ++c2) {
        float v = lv[c2 >> 2][c2 & 3][t][p[c2]];
        int  id = (int)liu[c2 >> 2][c2 & 3][t][p[c2]];
        if (v > bv || (v == bv && id < bi2)) { bv = v; bi2 = id; bc = c2; }
      }
      mid[t][r] = bi2;
      #pragma unroll
      for (int c2 = 0; c2 < 16; ++c2) p[c2] += (bc == c2);
    }
  }
  __syncthreads();

  // ---- fp64 exact re-score: 320 tasks (16 q x 20 cand) ----
  {
    const double* sqdb = sqd + bN;
    const float* yTb = yT + bN * 96;
    #pragma unroll 1
    for (int task = t; task < 16 * L_; task += 256) {
      const int fq = task / L_, slot = task - fq * L_;
      const int qq = qg * 16 + fq;
      const int j = mid[fq][slot];
      const float4* q4p = (const float4*)(yTb + (size_t)qq * 96);
      const float4* p4p = (const float4*)(yTb + (size_t)j * 96);
      double a0 = 0.0, a1 = 0.0, a2 = 0.0, a3 = 0.0;
      #pragma unroll 4
      for (int m = 0; m < 24; ++m) {
        float4 qm = q4p[m], pm = p4p[m];
        a0 += (double)qm.x * (double)pm.x;
        a1 += (double)qm.y * (double)pm.y;
        a2 += (double)qm.z * (double)pm.z;
        a3 += (double)qm.w * (double)pm.w;
      }
      rv[fq][slot] = 2.0 * ((a0 + a1) + (a2 + a3)) - sqdb[qq] - sqdb[j];
    }
  }
  __syncthreads();

  // ---- final exact sorted top-16 (threads 0..15) ----
  if (t < 16) {
    double bd[16]; int bix[16];
    #pragma unroll
    for (int i = 0; i < 16; ++i) { bd[i] = -DBL_MAX; bix[i] = INT_MAX; }
    #pragma unroll 1
    for (int r = 0; r < L_; ++r) {
      double v = rv[t][r]; int id = mid[t][r];
      if (v > bd[15] || (v == bd[15] && id < bix[15])) {
        #pragma unroll
        for (int i = 0; i < 16; ++i) {
          if (v > bd[i] || (v == bd[i] && id < bix[i])) {
            double tv = bd[i]; bd[i] = v; v = tv;
            int ti = bix[i]; bix[i] = id; id = ti;
          }
        }
      }
    }
    int* outp = knn + (bN + (size_t)(qg * 16 + t)) * 16;
    #pragma unroll
    for (int r = 0; r < 16; ++r) outp[r] = bix[r];
  }
}

__device__ __forceinline__ float f4e(const float4& v, int i) {
  return i == 0 ? v.x : i == 1 ? v.y : i == 2 ? v.z : v.w;
}

// Fused main: round-9 version (separate weight buffers loaded once, no
// phase barriers, two-pass) — measured ~430us; r10 fusion and r11
// phase-reuse were both slower.
__global__ __launch_bounds__(256) void kC_main(
    const float* __restrict__ x, const float* __restrict__ yT,
    const int* __restrict__ knn,
    const float* __restrict__ Wq, const float* __restrict__ Eq,
    const float* __restrict__ Wk, const float* __restrict__ Ek,
    const float* __restrict__ Wv, const float* __restrict__ Ev,
    float* __restrict__ out) {
  __shared__ float4 sWq[8 * 32], sEq[8 * 32];
  __shared__ float4 sWk[16 * 32], sEk[16 * 32], sWv[16 * 32], sEv[16 * 32];
  __shared__ float sOut[8][97];

  int t = threadIdx.x;
  {
    int e = t;
    int c4 = e >> 5, o = e & 31;
    sWq[e] = ((const float4*)(Wq + o * 32))[c4];
    sEq[e] = ((const float4*)(Eq + o * 32))[c4];
  }
  for (int e = t; e < 512; e += 256) {
    int c4 = e >> 5, o = e & 31;
    sWk[e] = ((const float4*)(Wk + o * 64))[c4];
    sEk[e] = ((const float4*)(Ek + o * 64))[c4];
    sWv[e] = ((const float4*)(Wv + o * 64))[c4];
    sEv[e] = ((const float4*)(Ev + o * 64))[c4];
  }
  __syncthreads();

  int q = t >> 5, o = t & 31;
  int bno = blockIdx.x;
  int b = bno >> 9;
  int n = ((bno & 511) << 3) + q;
  int h = o >> 4, kk_mine = o & 15;

  const float* xb = x + (size_t)b * 96 * N_ + n;
  float pq[3] = {0, 0, 0}, dq[3] = {0, 0, 0};
  #pragma unroll
  for (int c4 = 0; c4 < 8; ++c4) {
    float4 wq = sWq[c4 * 32 + o], eq = sEq[c4 * 32 + o];
    #pragma unroll
    for (int i = 0; i < 4; ++i) {
      int c = c4 * 4 + i;
      float w = f4e(wq, i), e2 = f4e(eq, i);
      #pragma unroll
      for (int d = 0; d < 3; ++d) {
        float xv = xb[(size_t)(c * 3 + d) * N_];
        pq[d] = fmaf(w, xv, pq[d]);
        dq[d] = fmaf(e2, xv, dq[d]);
      }
    }
  }
  float Qx[3];
  {
    float dot = pq[0] * dq[0] + pq[1] * dq[1] + pq[2] * dq[2];
    float dsq = dq[0] * dq[0] + dq[1] * dq[1] + dq[2] * dq[2] + 1e-6f;
    float r = dot / dsq;
    float qv[3];
    #pragma unroll
    for (int d = 0; d < 3; ++d) {
      float pn = pq[d] - r * dq[d];
      qv[d] = 0.2f * pq[d] + 0.8f * (dot >= 0.f ? pq[d] : pn);
    }
    float nn = sqrtf(qv[0] * qv[0] + qv[1] * qv[1] + qv[2] * qv[2]);
    float nch2 = nn * nn;
    #pragma unroll
    for (int m = 1; m <= 16; m <<= 1) nch2 += __shfl_xor(nch2, m, 32);
    float s = (nn / fmaxf(sqrtf(nch2), 1e-12f)) / fmaxf(nn, 1e-12f);
    #pragma unroll
    for (int d = 0; d < 3; ++d) Qx[d] = qv[d] * s;
  }

  const float* ctr = yT + ((size_t)b * N_ + n) * 96;
  const int* kidx = knn + ((size_t)b * N_ + n) * 16;

  float pck[3] = {0, 0, 0}, dck[3] = {0, 0, 0};
  #pragma unroll
  for (int c4 = 0; c4 < 8; ++c4) {
    float4 wlo = sWk[c4 * 32 + o], whi = sWk[(c4 + 8) * 32 + o];
    float4 elo = sEk[c4 * 32 + o], ehi = sEk[(c4 + 8) * 32 + o];
    float4 c0 = ((const float4*)ctr)[c4 * 3 + 0];
    float4 c1 = ((const float4*)ctr)[c4 * 3 + 1];
    float4 c2 = ((const float4*)ctr)[c4 * 3 + 2];
    float cv[12] = {c0.x, c0.y, c0.z, c0.w, c1.x, c1.y, c1.z, c1.w, c2.x, c2.y, c2.z, c2.w};
    #pragma unroll
    for (int v = 0; v < 12; ++v) {
      int cl = v / 3, d = v % 3;
      pck[d] = fmaf(f4e(whi, cl) - f4e(wlo, cl), cv[v], pck[d]);
      dck[d] = fmaf(f4e(ehi, cl) - f4e(elo, cl), cv[v], dck[d]);
    }
  }

  float myscore = 0.f;
  #pragma unroll 1
  for (int k = 0; k < 16; ++k) {
    int jn = kidx[k];
    const float* nb = yT + ((size_t)b * N_ + jn) * 96;
    float p[3] = {pck[0], pck[1], pck[2]}, dd[3] = {dck[0], dck[1], dck[2]};
    #pragma unroll
    for (int c4 = 0; c4 < 8; ++c4) {
      float4 w = sWk[c4 * 32 + o], e = sEk[c4 * 32 + o];
      float4 n0 = ((const float4*)nb)[c4 * 3 + 0];
      float4 n1 = ((const float4*)nb)[c4 * 3 + 1];
      float4 n2 = ((const float4*)nb)[c4 * 3 + 2];
      float nv[12] = {n0.x, n0.y, n0.z, n0.w, n1.x, n1.y, n1.z, n1.w, n2.x, n2.y, n2.z, n2.w};
      #pragma unroll
      for (int v = 0; v < 12; ++v) {
        int cl = v / 3, d = v % 3;
        p[d]  = fmaf(f4e(w, cl), nv[v], p[d]);
        dd[d] = fmaf(f4e(e, cl), nv[v], dd[d]);
      }
    }
    float dot = p[0] * dd[0] + p[1] * dd[1] + p[2] * dd[2];
    float dsq = dd[0] * dd[0] + dd[1] * dd[1] + dd[2] * dd[2] + 1e-6f;
    float r = dot / dsq;
    float ky[3];
    #pragma unroll
    for (int d = 0; d < 3; ++d) {
      float pn = p[d] - r * dd[d];
      ky[d] = 0.2f * p[d] + 0.8f * (dot >= 0.f ? p[d] : pn);
    }
    float nn = sqrtf(ky[0] * ky[0] + ky[1] * ky[1] + ky[2] * ky[2]);
    float nch2 = nn * nn;
    #pragma unroll
    for (int m = 1; m <= 16; m <<= 1) nch2 += __shfl_xor(nch2, m, 32);
    float s = (1.f / fmaxf(sqrtf(nch2), 1e-12f)) * (nn / fmaxf(nn, 1e-12f));
    float qk = (ky[0] * Qx[0] + ky[1] * Qx[1] + ky[2] * Qx[2]) * s;
    #pragma unroll
    for (int m = 1; m <= 8; m <<= 1) qk += __shfl_xor(qk, m, 32);
    float score = qk * 0.14433756729740643f;   // 1/sqrt(48)
    if (kk_mine == k) myscore = score;
  }

  float att_mine;
  {
    float mx = myscore;
    #pragma unroll
    for (int m = 1; m <= 8; m <<= 1) mx = fmaxf(mx, __shfl_xor(mx, m, 32));
    float ex = expf(myscore - mx);
    float ss = ex;
    #pragma unroll
    for (int m = 1; m <= 8; m <<= 1) ss += __shfl_xor(ss, m, 32);
    att_mine = ex / ss;
  }

  float pcv[3] = {0, 0, 0}, dcv[3] = {0, 0, 0};
  #pragma unroll
  for (int c4 = 0; c4 < 8; ++c4) {
    float4 wlo = sWv[c4 * 32 + o], whi = sWv[(c4 + 8) * 32 + o];
    float4 elo = sEv[c4 * 32 + o], ehi = sEv[(c4 + 8) * 32 + o];
    float4 c0 = ((const float4*)ctr)[c4 * 3 + 0];
    float4 c1 = ((const float4*)ctr)[c4 * 3 + 1];
    float4 c2 = ((const float4*)ctr)[c4 * 3 + 2];
    float cv[12] = {c0.x, c0.y, c0.z, c0.w, c1.x, c1.y, c1.z, c1.w, c2.x, c2.y, c2.z, c2.w};
    #pragma unroll
    for (int v = 0; v < 12; ++v) {
      int cl = v / 3, d = v % 3;
      pcv[d] = fmaf(f4e(whi, cl) - f4e(wlo, cl), cv[v], pcv[d]);
      dcv[d] = fmaf(f4e(ehi, cl) - f4e(elo, cl), cv[v], dcv[d]);
    }
  }
  float acc[3] = {0, 0, 0};
  #pragma unroll 1
  for (int k = 0; k < 16; ++k) {
    int jn = kidx[k];
    const float* nb = yT + ((size_t)b * N_ + jn) * 96;
    float p[3] = {pcv[0], pcv[1], pcv[2]}, dd[3] = {dcv[0], dcv[1], dcv[2]};
    #pragma unroll
    for (int c4 = 0; c4 < 8; ++c4) {
      float4 w = sWv[c4 * 32 + o], e = sEv[c4 * 32 + o];
      float4 n0 = ((const float4*)nb)[c4 * 3 + 0];
      float4 n1 = ((const float4*)nb)[c4 * 3 + 1];
      float4 n2 = ((const float4*)nb)[c4 * 3 + 2];
      float nv[12] = {n0.x, n0.y, n0.z, n0.w, n1.x, n1.y, n1.z, n1.w, n2.x, n2.y, n2.z, n2.w};
      #pragma unroll
      for (int v = 0; v < 12; ++v) {
        int cl = v / 3, d = v % 3;
        p[d]  = fmaf(f4e(w, cl), nv[v], p[d]);
        dd[d] = fmaf(f4e(e, cl), nv[v], dd[d]);
      }
    }
    float dot = p[0] * dd[0] + p[1] * dd[1] + p[2] * dd[2];
    float dsq = dd[0] * dd[0] + dd[1] * dd[1] + dd[2] * dd[2] + 1e-6f;
    float r = dot / dsq;
    float attk = __shfl(att_mine, h * 16 + k, 32);
    #pragma unroll
    for (int d = 0; d < 3; ++d) {
      float pn = p[d] - r * dd[d];
      float vy = 0.2f * p[d] + 0.8f * (dot >= 0.f ? p[d] : pn);
      acc[d] = fmaf(attk, vy, acc[d]);
    }
  }

  #pragma unroll
  for (int d = 0; d < 3; ++d) sOut[q][o * 3 + d] = acc[d];
  __syncthreads();
  int nl = t & 7;
  int n_out = ((bno & 511) << 3) + nl;
  #pragma unroll
  for (int it = 0; it < 3; ++it) {
    int od = it * 32 + (t >> 3);
    size_t a = (size_t)b * 96 * N_ + (size_t)od * N_ + n_out;
    out[a] = x[a] + sOut[nl][od];
  }
}

extern "C" void kernel_launch(void* const* d_in, const int* in_sizes, int n_in,
                              void* d_out, int out_size, void* d_ws, size_t ws_size,
                              hipStream_t stream) {
  const float* x  = (const float*)d_in[0];
  const float* y  = (const float*)d_in[1];
  const float* Wq = (const float*)d_in[2];
  const float* Dq = (const float*)d_in[3];
  const float* Wk = (const float*)d_in[4];
  const float* Dk = (const float*)d_in[5];
  const float* Wv = (const float*)d_in[6];
  const float* Dv = (const float*)d_in[7];
  float* out = (float*)d_out;

  char* wsb = (char*)d_ws;
  float*  yT  = (float*)wsb;                                   // 12,582,912 B
  double* sqd = (double*)(wsb + 12582912);                     //    262,144 B
  float*  sq  = (float*)(wsb + 12845056);                      //    131,072 B
  int*    knn = (int*)(wsb + 12976128);                        //  2,097,152 B
  ushort* hBs = (ushort*)(wsb + 15073280);                     //  6,291,456 B
  ushort* lBs = (ushort*)(wsb + 21364736);                     //  6,291,456 B
  float*  Ek  = (float*)(wsb + 27656192);                      //      8,192 B
  float*  Ev  = Ek + 2048;
  float*  Eq  = Ev + 2048;

  kE_combine<<<dim3(1), dim3(256), 0, stream>>>(Wk, Dk, Wv, Dv, Wq, Dq, Ek, Ev, Eq);
  kA_transpose<<<dim3(512), dim3(256), 0, stream>>>(y, yT, sq, sqd, hBs, lBs);
  kB_knn<<<dim3(2048), dim3(256), 0, stream>>>(yT, hBs, lBs, sq, sqd, knn);
  kC_main<<<dim3(4096), dim3(256), 0, stream>>>(x, yT, knn, Wq, Eq, Wk, Ek, Wv, Ev, out);
}

// Round 14
// 647.908 us; speedup vs baseline: 2.7054x; 1.3707x over previous
//
#include <hip/hip_runtime.h>
#include <math.h>
#include <float.h>
#include <limits.h>

#define B_ 8
#define C_ 32
#define N_ 4096
#define K_ 16
#define L_ 20   // merged candidate depth (fp32-inversion margin 4, proven)
#define LL 12   // per-lane register list depth (lane-capacity margin)

typedef __attribute__((ext_vector_type(8))) short bf16x8;
typedef __attribute__((ext_vector_type(4))) float f32x4;
#define MFMA16(a, b, c) __builtin_amdgcn_mfma_f32_16x16x32_bf16(a, b, c, 0, 0, 0)

// ------------------------------------------------------------------
// ws layout (bytes):
//   yT  : [B][N][96] float    12,582,912
//   sqd : [B][N]     double      262,144
//   sq  : [B][N]     float       131,072
//   knn : [B][N][16] int       2,097,152
//   hBs : swizzled bf16 hi     6,291,456
//   lBs : swizzled bf16 lo     6,291,456
//   Ek/Ev/Eq floats               20,480
// ------------------------------------------------------------------

__global__ __launch_bounds__(256) void kE_combine(
    const float* __restrict__ Wk, const float* __restrict__ Dk,
    const float* __restrict__ Wv, const float* __restrict__ Dv,
    const float* __restrict__ Wq, const float* __restrict__ Dq,
    float* __restrict__ Ek, float* __restrict__ Ev, float* __restrict__ Eq) {
  int t = threadIdx.x;
  for (int e = t; e < 2048; e += 256) {
    int o = e >> 6, c = e & 63;
    float a = 0.f, v = 0.f;
    for (int m = 0; m < 32; ++m) {
      a = fmaf(Dk[o * 32 + m], Wk[m * 64 + c], a);
      v = fmaf(Dv[o * 32 + m], Wv[m * 64 + c], v);
    }
    Ek[e] = a; Ev[e] = v;
  }
  for (int e = t; e < 1024; e += 256) {
    int o = e >> 5, c = e & 31;
    float a = 0.f;
    for (int m = 0; m < 32; ++m) a = fmaf(Dq[o * 32 + m], Wq[m * 32 + c], a);
    Eq[e] = a;
  }
}

__global__ __launch_bounds__(256) void kA_transpose(
    const float* __restrict__ y, float* __restrict__ yT,
    float* __restrict__ sq, double* __restrict__ sqd,
    ushort* __restrict__ hBs, ushort* __restrict__ lBs) {
  __shared__ float tile[96][65];
  int b = blockIdx.x >> 6;
  int n0 = (blockIdx.x & 63) * 64;
  int t = threadIdx.x;
  int g = t >> 6, ln = t & 63;
  #pragma unroll
  for (int r = 0; r < 24; ++r) {
    int d = g * 24 + r;
    tile[d][ln] = y[((size_t)b * 96 + d) * N_ + n0 + ln];
  }
  __syncthreads();
  if (t < 64) {
    float s = 0.f; double sd = 0.0;
    #pragma unroll
    for (int d = 0; d < 96; ++d) {
      float v = tile[d][t];
      s = fmaf(v, v, s);
      sd += (double)v * (double)v;
    }
    sq[b * N_ + n0 + t] = s;
    sqd[b * N_ + n0 + t] = sd;
  }
  for (int idx = t; idx < 64 * 96; idx += 256) {
    int nl = idx / 96, d = idx % 96;
    yT[((size_t)b * N_ + n0 + nl) * 96 + d] = tile[d][nl];
  }
  for (int idx = t; idx < 768; idx += 256) {
    int g16l = idx / 192;
    int rem = idx - g16l * 192;
    int sl = rem >> 6;
    int ln2 = rem & 63;
    int fg2 = ln2 >> 4, fm2 = ln2 & 15;
    int nl = g16l * 16 + fm2;
    uint hw[4], lw[4];
    #pragma unroll
    for (int e2 = 0; e2 < 4; ++e2) {
      float v0 = tile[sl * 32 + fg2 * 8 + 2 * e2][nl];
      float v1 = tile[sl * 32 + fg2 * 8 + 2 * e2 + 1][nl];
      uint x0 = __float_as_uint(v0), x1 = __float_as_uint(v1);
      uint h0 = x0 >> 16, h1 = x1 >> 16;
      float r0 = v0 - __uint_as_float(h0 << 16);
      float r1 = v1 - __uint_as_float(h1 << 16);
      uint l0 = __float_as_uint(r0) >> 16, l1 = __float_as_uint(r1) >> 16;
      hw[e2] = h0 | (h1 << 16);
      lw[e2] = l0 | (l1 << 16);
    }
    size_t off = (size_t)b * 393216 +
                 (((size_t)(n0 >> 4) + g16l) * 3 + sl) * 512 + (size_t)ln2 * 8;
    *(uint4*)(hBs + off) = make_uint4(hw[0], hw[1], hw[2], hw[3]);
    *(uint4*)(lBs + off) = make_uint4(lw[0], lw[1], lw[2], lw[3]);
  }
}

// Named-register top-12 (LL=12: live set fits VGPR tier; proven r13).
#define DECL12 \
  float v0=-FLT_MAX,v1=-FLT_MAX,v2=-FLT_MAX,v3=-FLT_MAX,v4=-FLT_MAX, \
        v5=-FLT_MAX,v6=-FLT_MAX,v7=-FLT_MAX,v8=-FLT_MAX,v9=-FLT_MAX, \
        v10=-FLT_MAX,v11=-FLT_MAX; \
  int y0=0,y1=0,y2=0,y3=0,y4=0,y5=0,y6=0,y7=0,y8=0,y9=0,y10=0,y11=0;

#define CX(i) { bool cc = cv > v##i; \
  float tf = cc ? v##i : cv; int ti = cc ? y##i : ci; \
  v##i = cc ? cv : v##i; y##i = cc ? ci : y##i; cv = tf; ci = ti; }

#define INSERT12 { CX(0) CX(1) CX(2) CX(3) CX(4) CX(5) CX(6) CX(7) CX(8) CX(9) \
  CX(10) CX(11) }

__global__ __launch_bounds__(256) void kB_knn(
    const float* __restrict__ yT, const ushort* __restrict__ hBs,
    const ushort* __restrict__ lBs, const float* __restrict__ sq,
    const double* __restrict__ sqd, int* __restrict__ knn) {
  __shared__ float  lv[4][4][16][LL + 1];
  __shared__ ushort liu[4][4][16][LL + 2];
  __shared__ int    mid[16][L_];
  __shared__ double rv[16][L_];

  const int t = threadIdx.x;
  const int lane = t & 63;
  const int w = t >> 6;
  const int fg = lane >> 4, fm = lane & 15;
  const int b = blockIdx.x & 7;
  const int qg = blockIdx.x >> 3;
  const int q = qg * 16 + fm;
  const size_t bN = (size_t)b * N_;
  const ushort* hb = hBs + bN * 96;
  const ushort* lb = lBs + bN * 96;
  const float* sqb = sq + bN;
  const float sqi = sqb[q];

  const ushort* hqb = hb + (size_t)qg * 1536 + (size_t)lane * 8;
  const ushort* lqb = lb + (size_t)qg * 1536 + (size_t)lane * 8;
  const bf16x8 qh0 = *(const bf16x8*)(hqb);
  const bf16x8 qh1 = *(const bf16x8*)(hqb + 512);
  const bf16x8 qh2 = *(const bf16x8*)(hqb + 1024);
  const bf16x8 ql0 = *(const bf16x8*)(lqb);
  const bf16x8 ql1 = *(const bf16x8*)(lqb + 512);
  const bf16x8 ql2 = *(const bf16x8*)(lqb + 1024);

  DECL12

  const int jchunk = w * 1024;
  #pragma unroll 1
  for (int jt = 0; jt < 16; ++jt) {
    const int g16 = (jchunk >> 4) + jt * 4;
    const ushort* hpb = hb + (size_t)g16 * 1536 + (size_t)lane * 8;
    const ushort* lpb = lb + (size_t)g16 * 1536 + (size_t)lane * 8;
    #pragma unroll
    for (int jb = 0; jb < 4; ++jb) {
      const ushort* ph = hpb + jb * 1536;
      const ushort* pl = lpb + jb * 1536;
      const bf16x8 a0 = *(const bf16x8*)(ph);
      const bf16x8 a1 = *(const bf16x8*)(ph + 512);
      const bf16x8 a2 = *(const bf16x8*)(ph + 1024);
      const bf16x8 b0 = *(const bf16x8*)(pl);
      const bf16x8 b1 = *(const bf16x8*)(pl + 512);
      const bf16x8 b2 = *(const bf16x8*)(pl + 1024);
      f32x4 c = {0.f, 0.f, 0.f, 0.f};
      c = MFMA16(a0, qh0, c);
      c = MFMA16(a1, qh1, c);
      c = MFMA16(a2, qh2, c);
      c = MFMA16(a0, ql0, c);
      c = MFMA16(a1, ql1, c);
      c = MFMA16(a2, ql2, c);
      c = MFMA16(b0, qh0, c);
      c = MFMA16(b1, qh1, c);
      c = MFMA16(b2, qh2, c);
      const int jbase = jchunk + jt * 64 + jb * 16 + fg * 4;
      const float4 s4 = *(const float4*)(sqb + jbase);
      #pragma unroll
      for (int r = 0; r < 4; ++r) {
        const float sj = r == 0 ? s4.x : r == 1 ? s4.y : r == 2 ? s4.z : s4.w;
        const float neg = 2.f * c[r] - sqi - sj;
        if (neg > v11) {
          float cv = neg; int ci = jbase + r;
          INSERT12
        }
      }
    }
  }

  {
    float* lvp = &lv[w][fg][fm][0];
    ushort* lip = &liu[w][fg][fm][0];
    lvp[0]=v0; lvp[1]=v1; lvp[2]=v2; lvp[3]=v3; lvp[4]=v4;
    lvp[5]=v5; lvp[6]=v6; lvp[7]=v7; lvp[8]=v8; lvp[9]=v9;
    lvp[10]=v10; lvp[11]=v11;
    lvp[12]=-FLT_MAX;
    lip[0]=(ushort)y0; lip[1]=(ushort)y1; lip[2]=(ushort)y2; lip[3]=(ushort)y3;
    lip[4]=(ushort)y4; lip[5]=(ushort)y5; lip[6]=(ushort)y6; lip[7]=(ushort)y7;
    lip[8]=(ushort)y8; lip[9]=(ushort)y9; lip[10]=(ushort)y10; lip[11]=(ushort)y11;
    lip[12]=0xFFFFu;
  }
  __syncthreads();

  if (t < 16) {
    int p[16];
    #pragma unroll
    for (int c2 = 0; c2 < 16; ++c2) p[c2] = 0;
    #pragma unroll 1
    for (int r = 0; r < L_; ++r) {
      float bv = -FLT_MAX; int bi2 = INT_MAX; int bc = 0;
      #pragma unroll
      for (int c2 = 0; c2 < 16; ++c2) {
        float v = lv[c2 >> 2][c2 & 3][t][p[c2]];
        int  id = (int)liu[c2 >> 2][c2 & 3][t][p[c2]];
        if (v > bv || (v == bv && id < bi2)) { bv = v; bi2 = id; bc = c2; }
      }
      mid[t][r] = bi2;
      #pragma unroll
      for (int c2 = 0; c2 < 16; ++c2) p[c2] += (bc == c2);
    }
  }
  __syncthreads();

  {
    const double* sqdb = sqd + bN;
    const float* yTb = yT + bN * 96;
    #pragma unroll 1
    for (int task = t; task < 16 * L_; task += 256) {
      const int fq = task / L_, slot = task - fq * L_;
      const int qq = qg * 16 + fq;
      const int j = mid[fq][slot];
      const float4* q4p = (const float4*)(yTb + (size_t)qq * 96);
      const float4* p4p = (const float4*)(yTb + (size_t)j * 96);
      double a0 = 0.0, a1 = 0.0, a2 = 0.0, a3 = 0.0;
      #pragma unroll 4
      for (int m = 0; m < 24; ++m) {
        float4 qm = q4p[m], pm = p4p[m];
        a0 += (double)qm.x * (double)pm.x;
        a1 += (double)qm.y * (double)pm.y;
        a2 += (double)qm.z * (double)pm.z;
        a3 += (double)qm.w * (double)pm.w;
      }
      rv[fq][slot] = 2.0 * ((a0 + a1) + (a2 + a3)) - sqdb[qq] - sqdb[j];
    }
  }
  __syncthreads();

  if (t < 16) {
    double bd[16]; int bix[16];
    #pragma unroll
    for (int i = 0; i < 16; ++i) { bd[i] = -DBL_MAX; bix[i] = INT_MAX; }
    #pragma unroll 1
    for (int r = 0; r < L_; ++r) {
      double v = rv[t][r]; int id = mid[t][r];
      if (v > bd[15] || (v == bd[15] && id < bix[15])) {
        #pragma unroll
        for (int i = 0; i < 16; ++i) {
          if (v > bd[i] || (v == bd[i] && id < bix[i])) {
            double tv = bd[i]; bd[i] = v; v = tv;
            int ti = bix[i]; bix[i] = id; id = ti;
          }
        }
      }
    }
    int* outp = knn + (bN + (size_t)(qg * 16 + t)) * 16;
    #pragma unroll
    for (int r = 0; r < 16; ++r) outp[r] = bix[r];
  }
}

__device__ __forceinline__ float f4e(const float4& v, int i) {
  return i == 0 ? v.x : i == 1 ? v.y : i == 2 ? v.z : v.w;
}

// kC v2: 1 wave = 1 query; lane = k*4+g (k = neighbor slot, g = oc-octet).
// Removes the serial 16-iteration k-loop: all 16 neighbors in parallel,
// ONE set of shuffle reductions per pass instead of 16. Weights staged
// transposed [ic][oc] in LDS (lo + delta halves). Centers + Qx computed
// in phase 0 (lanes 0-31, oc=lane) and handed over via per-query LDS.
__global__ __launch_bounds__(256) void kC_main(
    const float* __restrict__ x, const float* __restrict__ yT,
    const int* __restrict__ knn,
    const float* __restrict__ Wq, const float* __restrict__ Eq,
    const float* __restrict__ Wk, const float* __restrict__ Ek,
    const float* __restrict__ Wv, const float* __restrict__ Ev,
    float* __restrict__ out) {
  __shared__ float sWkL[32][32], sEkL[32][32], sWvL[32][32], sEvL[32][32];
  __shared__ float sWkD[32][32], sEkD[32][32], sWvD[32][32], sEvD[32][32];
  __shared__ float sQxOut[4][96];   // Qx; reused as output buffer at the end
  __shared__ float sCK[4][32][6];   // K center: pc[3], dc[3] per oc
  __shared__ float sCV[4][32][6];   // V center

  const int t = threadIdx.x;
  const int w = t >> 6, lane = t & 63;
  const int kk = lane >> 2, g = lane & 3;
  const int blk = blockIdx.x;
  const int b = blk & 7;                    // XCD-friendly batch pinning
  const int n = ((blk >> 3) << 2) + w;      // this wave's query
  const size_t bN = (size_t)b * N_;

  // ---- stage transposed weights: lo half + delta(hi-lo) ----
  {
    int oc = t >> 3, icq = (t & 7) * 4;
    const float4 klo = *(const float4*)(Wk + oc * 64 + icq);
    const float4 khi = *(const float4*)(Wk + oc * 64 + 32 + icq);
    const float4 elo = *(const float4*)(Ek + oc * 64 + icq);
    const float4 ehi = *(const float4*)(Ek + oc * 64 + 32 + icq);
    const float4 vlo = *(const float4*)(Wv + oc * 64 + icq);
    const float4 vhi = *(const float4*)(Wv + oc * 64 + 32 + icq);
    const float4 flo = *(const float4*)(Ev + oc * 64 + icq);
    const float4 fhi = *(const float4*)(Ev + oc * 64 + 32 + icq);
    #pragma unroll
    for (int i = 0; i < 4; ++i) {
      sWkL[icq + i][oc] = f4e(klo, i); sWkD[icq + i][oc] = f4e(khi, i) - f4e(klo, i);
      sEkL[icq + i][oc] = f4e(elo, i); sEkD[icq + i][oc] = f4e(ehi, i) - f4e(elo, i);
      sWvL[icq + i][oc] = f4e(vlo, i); sWvD[icq + i][oc] = f4e(vhi, i) - f4e(vlo, i);
      sEvL[icq + i][oc] = f4e(flo, i); sEvD[icq + i][oc] = f4e(fhi, i) - f4e(flo, i);
    }
  }
  __syncthreads();

  const float* ctr = yT + (bN + n) * 96;

  // ---- phase 0 (lanes 0-31, oc = lane): Qx + K/V center hoists ----
  if (lane < 32) {
    const int oc = lane;
    const float* xb = x + (size_t)b * 96 * N_ + n;
    float pq[3] = {0,0,0}, dq[3] = {0,0,0};
    float pk[3] = {0,0,0}, dk[3] = {0,0,0};
    float pv[3] = {0,0,0}, dv[3] = {0,0,0};
    #pragma unroll 4
    for (int ic = 0; ic < 32; ++ic) {
      float wq = Wq[oc * 32 + ic], eq = Eq[oc * 32 + ic];
      float wkd = sWkD[ic][oc], ekd = sEkD[ic][oc];
      float wvd = sWvD[ic][oc], evd = sEvD[ic][oc];
      #pragma unroll
      for (int d = 0; d < 3; ++d) {
        float xv = xb[(size_t)(ic * 3 + d) * N_];
        float cv = ctr[ic * 3 + d];
        pq[d] = fmaf(wq, xv, pq[d]);  dq[d] = fmaf(eq, xv, dq[d]);
        pk[d] = fmaf(wkd, cv, pk[d]); dk[d] = fmaf(ekd, cv, dk[d]);
        pv[d] = fmaf(wvd, cv, pv[d]); dv[d] = fmaf(evd, cv, dv[d]);
      }
    }
    float dot = pq[0]*dq[0] + pq[1]*dq[1] + pq[2]*dq[2];
    float dsq = dq[0]*dq[0] + dq[1]*dq[1] + dq[2]*dq[2] + 1e-6f;
    float r = dot / dsq;
    float qv[3];
    #pragma unroll
    for (int d = 0; d < 3; ++d) {
      float pn = pq[d] - r * dq[d];
      qv[d] = 0.2f * pq[d] + 0.8f * (dot >= 0.f ? pq[d] : pn);
    }
    float nn = sqrtf(qv[0]*qv[0] + qv[1]*qv[1] + qv[2]*qv[2]);
    float nch2 = nn * nn;
    #pragma unroll
    for (int m = 1; m <= 16; m <<= 1) nch2 += __shfl_xor(nch2, m, 32);
    float s = (nn / fmaxf(sqrtf(nch2), 1e-12f)) / fmaxf(nn, 1e-12f);
    #pragma unroll
    for (int d = 0; d < 3; ++d) {
      sQxOut[w][oc * 3 + d] = qv[d] * s;
      sCK[w][oc][d] = pk[d]; sCK[w][oc][3 + d] = dk[d];
      sCV[w][oc][d] = pv[d]; sCV[w][oc][3 + d] = dv[d];
    }
  }
  __syncthreads();

  const int jn = knn[(bN + n) * 16 + kk];
  const float4* nb4 = (const float4*)(yT + (bN + (size_t)jn) * 96);
  const int oc0 = g * 8;

  float aP[8][3], aD[8][3];

  // ===== K pass =====
  {
    const float4* ck = (const float4*)&sCK[w][oc0][0];
    #pragma unroll
    for (int m = 0; m < 12; ++m) {
      float4 v = ck[m];
      #pragma unroll
      for (int e = 0; e < 4; ++e) {
        int f = m * 4 + e, oi = f / 6, r2 = f % 6;
        if (r2 < 3) aP[oi][r2] = f4e(v, e); else aD[oi][r2 - 3] = f4e(v, e);
      }
    }
  }
  #pragma unroll 2
  for (int ch = 0; ch < 8; ++ch) {
    float4 r0 = nb4[ch * 3], r1 = nb4[ch * 3 + 1], r2 = nb4[ch * 3 + 2];
    #pragma unroll
    for (int icl = 0; icl < 4; ++icl) {
      int ic = ch * 4 + icl;
      float4 wA = *(const float4*)&sWkL[ic][oc0];
      float4 wB = *(const float4*)&sWkL[ic][oc0 + 4];
      float4 eA = *(const float4*)&sEkL[ic][oc0];
      float4 eB = *(const float4*)&sEkL[ic][oc0 + 4];
      #pragma unroll
      for (int d = 0; d < 3; ++d) {
        int f = icl * 3 + d;
        float v = f < 4 ? f4e(r0, f) : f < 8 ? f4e(r1, f - 4) : f4e(r2, f - 8);
        #pragma unroll
        for (int oi = 0; oi < 4; ++oi) {
          aP[oi][d]     = fmaf(f4e(wA, oi), v, aP[oi][d]);
          aD[oi][d]     = fmaf(f4e(eA, oi), v, aD[oi][d]);
          aP[oi + 4][d] = fmaf(f4e(wB, oi), v, aP[oi + 4][d]);
          aD[oi + 4][d] = fmaf(f4e(eB, oi), v, aD[oi + 4][d]);
        }
      }
    }
  }
  float att;
  {
    float part = 0.f, nchp = 0.f;
    #pragma unroll
    for (int oi = 0; oi < 8; ++oi) {
      float dot = aP[oi][0]*aD[oi][0] + aP[oi][1]*aD[oi][1] + aP[oi][2]*aD[oi][2];
      float dsq = aD[oi][0]*aD[oi][0] + aD[oi][1]*aD[oi][1] + aD[oi][2]*aD[oi][2] + 1e-6f;
      float r = dot / dsq;
      float nn2 = 0.f, qdot = 0.f;
      const float* qx = &sQxOut[w][(oc0 + oi) * 3];
      #pragma unroll
      for (int d = 0; d < 3; ++d) {
        float pn = aP[oi][d] - r * aD[oi][d];
        float ky = 0.2f * aP[oi][d] + 0.8f * (dot >= 0.f ? aP[oi][d] : pn);
        nn2 = fmaf(ky, ky, nn2);
        qdot = fmaf(ky, qx[d], qdot);
      }
      float nn = sqrtf(nn2);
      part = fmaf(nn / fmaxf(nn, 1e-12f), qdot, part);
      nchp += nn2;
    }
    float nch2 = nchp + __shfl_xor(nchp, 1);
    nch2 += __shfl_xor(nch2, 2);
    float qk = part + __shfl_xor(part, 1);    // head sum over g-pair
    float score = qk / fmaxf(sqrtf(nch2), 1e-12f) * 0.14433756729740643f;
    float mx = score;
    #pragma unroll
    for (int m = 4; m <= 32; m <<= 1) mx = fmaxf(mx, __shfl_xor(mx, m));
    float ex = expf(score - mx);
    float sm = ex;
    #pragma unroll
    for (int m = 4; m <= 32; m <<= 1) sm += __shfl_xor(sm, m);
    att = ex / sm;
  }

  // ===== V pass =====
  {
    const float4* cv4 = (const float4*)&sCV[w][oc0][0];
    #pragma unroll
    for (int m = 0; m < 12; ++m) {
      float4 v = cv4[m];
      #pragma unroll
      for (int e = 0; e < 4; ++e) {
        int f = m * 4 + e, oi = f / 6, r2 = f % 6;
        if (r2 < 3) aP[oi][r2] = f4e(v, e); else aD[oi][r2 - 3] = f4e(v, e);
      }
    }
  }
  #pragma unroll 2
  for (int ch = 0; ch < 8; ++ch) {
    float4 r0 = nb4[ch * 3], r1 = nb4[ch * 3 + 1], r2 = nb4[ch * 3 + 2];
    #pragma unroll
    for (int icl = 0; icl < 4; ++icl) {
      int ic = ch * 4 + icl;
      float4 wA = *(const float4*)&sWvL[ic][oc0];
      float4 wB = *(const float4*)&sWvL[ic][oc0 + 4];
      float4 eA = *(const float4*)&sEvL[ic][oc0];
      float4 eB = *(const float4*)&sEvL[ic][oc0 + 4];
      #pragma unroll
      for (int d = 0; d < 3; ++d) {
        int f = icl * 3 + d;
        float v = f < 4 ? f4e(r0, f) : f < 8 ? f4e(r1, f - 4) : f4e(r2, f - 8);
        #pragma unroll
        for (int oi = 0; oi < 4; ++oi) {
          aP[oi][d]     = fmaf(f4e(wA, oi), v, aP[oi][d]);
          aD[oi][d]     = fmaf(f4e(eA, oi), v, aD[oi][d]);
          aP[oi + 4][d] = fmaf(f4e(wB, oi), v, aP[oi + 4][d]);
          aD[oi + 4][d] = fmaf(f4e(eB, oi), v, aD[oi + 4][d]);
        }
      }
    }
  }
  #pragma unroll
  for (int oi = 0; oi < 8; ++oi) {
    float dot = aP[oi][0]*aD[oi][0] + aP[oi][1]*aD[oi][1] + aP[oi][2]*aD[oi][2];
    float dsq = aD[oi][0]*aD[oi][0] + aD[oi][1]*aD[oi][1] + aD[oi][2]*aD[oi][2] + 1e-6f;
    float r = dot / dsq;
    #pragma unroll
    for (int d = 0; d < 3; ++d) {
      float pn = aP[oi][d] - r * aD[oi][d];
      float vy = 0.2f * aP[oi][d] + 0.8f * (dot >= 0.f ? aP[oi][d] : pn);
      aP[oi][d] = att * vy;
    }
  }
  // butterfly sum over the 16 k-lanes (stride-4 xor masks)
  #pragma unroll
  for (int m = 4; m <= 32; m <<= 1) {
    #pragma unroll
    for (int oi = 0; oi < 8; ++oi) {
      #pragma unroll
      for (int d = 0; d < 3; ++d) aP[oi][d] += __shfl_xor(aP[oi][d], m);
    }
  }
  if (kk == 0) {
    #pragma unroll
    for (int oi = 0; oi < 8; ++oi)
      #pragma unroll
      for (int d = 0; d < 3; ++d)
        sQxOut[w][(oc0 + oi) * 3 + d] = aP[oi][d];
  }
  __syncthreads();

  // ---- output: 4 queries x 96 channels, 16B-chunk coalesced + x add ----
  const int nb0 = (blk >> 3) << 2;
  for (int idx = t; idx < 384; idx += 256) {
    int qq = idx & 3, od = idx >> 2;
    size_t a = ((size_t)b * 96 + od) * N_ + nb0 + qq;
    out[a] = x[a] + sQxOut[qq][od];
  }
}

extern "C" void kernel_launch(void* const* d_in, const int* in_sizes, int n_in,
                              void* d_out, int out_size, void* d_ws, size_t ws_size,
                              hipStream_t stream) {
  const float* x  = (const float*)d_in[0];
  const float* y  = (const float*)d_in[1];
  const float* Wq = (const float*)d_in[2];
  const float* Dq = (const float*)d_in[3];
  const float* Wk = (const float*)d_in[4];
  const float* Dk = (const float*)d_in[5];
  const float* Wv = (const float*)d_in[6];
  const float* Dv = (const float*)d_in[7];
  float* out = (float*)d_out;

  char* wsb = (char*)d_ws;
  float*  yT  = (float*)wsb;                                   // 12,582,912 B
  double* sqd = (double*)(wsb + 12582912);                     //    262,144 B
  float*  sq  = (float*)(wsb + 12845056);                      //    131,072 B
  int*    knn = (int*)(wsb + 12976128);                        //  2,097,152 B
  ushort* hBs = (ushort*)(wsb + 15073280);                     //  6,291,456 B
  ushort* lBs = (ushort*)(wsb + 21364736);                     //  6,291,456 B
  float*  Ek  = (float*)(wsb + 27656192);                      //      8,192 B
  float*  Ev  = Ek + 2048;
  float*  Eq  = Ev + 2048;

  kE_combine<<<dim3(1), dim3(256), 0, stream>>>(Wk, Dk, Wv, Dv, Wq, Dq, Ek, Ev, Eq);
  kA_transpose<<<dim3(512), dim3(256), 0, stream>>>(y, yT, sq, sqd, hBs, lBs);
  kB_knn<<<dim3(2048), dim3(256), 0, stream>>>(yT, hBs, lBs, sq, sqd, knn);
  kC_main<<<dim3(8192), dim3(256), 0, stream>>>(x, yT, knn, Wq, Eq, Wk, Ek, Wv, Ev, out);
}

// Round 15
// 589.212 us; speedup vs baseline: 2.9749x; 1.0996x over previous
//
#include <hip/hip_runtime.h>
#include <math.h>
#include <float.h>
#include <limits.h>

#define B_ 8
#define C_ 32
#define N_ 4096
#define K_ 16
#define L_ 20   // merged candidate depth (fp32-inversion margin 4, proven)
#define LL 12   // per-lane register list depth (lane-capacity margin)

typedef __attribute__((ext_vector_type(8))) short bf16x8;
typedef __attribute__((ext_vector_type(4))) float f32x4;
#define MFMA16(a, b, c) __builtin_amdgcn_mfma_f32_16x16x32_bf16(a, b, c, 0, 0, 0)

// ------------------------------------------------------------------
// ws layout (bytes):
//   yT  : [B][N][96] float    12,582,912
//   sqd : [B][N]     double      262,144
//   sq  : [B][N]     float       131,072
//   knn : [B][N][16] int       2,097,152
//   hBs : swizzled bf16 hi     6,291,456
//   lBs : swizzled bf16 lo     6,291,456
//   Ek/Ev/Eq floats               20,480
// ------------------------------------------------------------------

__global__ __launch_bounds__(256) void kE_combine(
    const float* __restrict__ Wk, const float* __restrict__ Dk,
    const float* __restrict__ Wv, const float* __restrict__ Dv,
    const float* __restrict__ Wq, const float* __restrict__ Dq,
    float* __restrict__ Ek, float* __restrict__ Ev, float* __restrict__ Eq) {
  int t = threadIdx.x;
  for (int e = t; e < 2048; e += 256) {
    int o = e >> 6, c = e & 63;
    float a = 0.f, v = 0.f;
    for (int m = 0; m < 32; ++m) {
      a = fmaf(Dk[o * 32 + m], Wk[m * 64 + c], a);
      v = fmaf(Dv[o * 32 + m], Wv[m * 64 + c], v);
    }
    Ek[e] = a; Ev[e] = v;
  }
  for (int e = t; e < 1024; e += 256) {
    int o = e >> 5, c = e & 31;
    float a = 0.f;
    for (int m = 0; m < 32; ++m) a = fmaf(Dq[o * 32 + m], Wq[m * 32 + c], a);
    Eq[e] = a;
  }
}

__global__ __launch_bounds__(256) void kA_transpose(
    const float* __restrict__ y, float* __restrict__ yT,
    float* __restrict__ sq, double* __restrict__ sqd,
    ushort* __restrict__ hBs, ushort* __restrict__ lBs) {
  __shared__ float tile[96][65];
  int b = blockIdx.x >> 6;
  int n0 = (blockIdx.x & 63) * 64;
  int t = threadIdx.x;
  int g = t >> 6, ln = t & 63;
  #pragma unroll
  for (int r = 0; r < 24; ++r) {
    int d = g * 24 + r;
    tile[d][ln] = y[((size_t)b * 96 + d) * N_ + n0 + ln];
  }
  __syncthreads();
  if (t < 64) {
    float s = 0.f; double sd = 0.0;
    #pragma unroll
    for (int d = 0; d < 96; ++d) {
      float v = tile[d][t];
      s = fmaf(v, v, s);
      sd += (double)v * (double)v;
    }
    sq[b * N_ + n0 + t] = s;
    sqd[b * N_ + n0 + t] = sd;
  }
  for (int idx = t; idx < 64 * 96; idx += 256) {
    int nl = idx / 96, d = idx % 96;
    yT[((size_t)b * N_ + n0 + nl) * 96 + d] = tile[d][nl];
  }
  for (int idx = t; idx < 768; idx += 256) {
    int g16l = idx / 192;
    int rem = idx - g16l * 192;
    int sl = rem >> 6;
    int ln2 = rem & 63;
    int fg2 = ln2 >> 4, fm2 = ln2 & 15;
    int nl = g16l * 16 + fm2;
    uint hw[4], lw[4];
    #pragma unroll
    for (int e2 = 0; e2 < 4; ++e2) {
      float v0 = tile[sl * 32 + fg2 * 8 + 2 * e2][nl];
      float v1 = tile[sl * 32 + fg2 * 8 + 2 * e2 + 1][nl];
      uint x0 = __float_as_uint(v0), x1 = __float_as_uint(v1);
      uint h0 = x0 >> 16, h1 = x1 >> 16;
      float r0 = v0 - __uint_as_float(h0 << 16);
      float r1 = v1 - __uint_as_float(h1 << 16);
      uint l0 = __float_as_uint(r0) >> 16, l1 = __float_as_uint(r1) >> 16;
      hw[e2] = h0 | (h1 << 16);
      lw[e2] = l0 | (l1 << 16);
    }
    size_t off = (size_t)b * 393216 +
                 (((size_t)(n0 >> 4) + g16l) * 3 + sl) * 512 + (size_t)ln2 * 8;
    *(uint4*)(hBs + off) = make_uint4(hw[0], hw[1], hw[2], hw[3]);
    *(uint4*)(lBs + off) = make_uint4(lw[0], lw[1], lw[2], lw[3]);
  }
}

// Named-register top-12 (LL=12, r13) + 4-deep buffered insert (r15):
// appends are ~14 ops; the 48-op INSERT12 flush runs only when some lane's
// buffer fills (~15-20x per wave instead of ~1000x). Stale threshold v11
// only lags => appends are a superset of true inserts; flush preserves
// per-lane j-order => final lists identical incl. tie semantics.
#define DECL12 \
  float v0=-FLT_MAX,v1=-FLT_MAX,v2=-FLT_MAX,v3=-FLT_MAX,v4=-FLT_MAX, \
        v5=-FLT_MAX,v6=-FLT_MAX,v7=-FLT_MAX,v8=-FLT_MAX,v9=-FLT_MAX, \
        v10=-FLT_MAX,v11=-FLT_MAX; \
  int y0=0,y1=0,y2=0,y3=0,y4=0,y5=0,y6=0,y7=0,y8=0,y9=0,y10=0,y11=0;

#define CX(i) { bool cc = cv > v##i; \
  float tf = cc ? v##i : cv; int ti = cc ? y##i : ci; \
  v##i = cc ? cv : v##i; y##i = cc ? ci : y##i; cv = tf; ci = ti; }

#define INSERT12 { CX(0) CX(1) CX(2) CX(3) CX(4) CX(5) CX(6) CX(7) CX(8) CX(9) \
  CX(10) CX(11) }

#define FLUSHBUF { \
  if (bcnt > 0) { float cv = f0; int ci = g0; if (cv > v11) { INSERT12 } } \
  if (bcnt > 1) { float cv = f1; int ci = g1; if (cv > v11) { INSERT12 } } \
  if (bcnt > 2) { float cv = f2; int ci = g2; if (cv > v11) { INSERT12 } } \
  if (bcnt > 3) { float cv = f3; int ci = g3; if (cv > v11) { INSERT12 } } \
  bcnt = 0; }

__global__ __launch_bounds__(256) void kB_knn(
    const float* __restrict__ yT, const ushort* __restrict__ hBs,
    const ushort* __restrict__ lBs, const float* __restrict__ sq,
    const double* __restrict__ sqd, int* __restrict__ knn) {
  __shared__ float  lv[4][4][16][LL + 1];
  __shared__ ushort liu[4][4][16][LL + 2];
  __shared__ int    mid[16][L_];
  __shared__ double rv[16][L_];

  const int t = threadIdx.x;
  const int lane = t & 63;
  const int w = t >> 6;
  const int fg = lane >> 4, fm = lane & 15;
  const int b = blockIdx.x & 7;
  const int qg = blockIdx.x >> 3;
  const int q = qg * 16 + fm;
  const size_t bN = (size_t)b * N_;
  const ushort* hb = hBs + bN * 96;
  const ushort* lb = lBs + bN * 96;
  const float* sqb = sq + bN;
  const float sqi = sqb[q];

  const ushort* hqb = hb + (size_t)qg * 1536 + (size_t)lane * 8;
  const ushort* lqb = lb + (size_t)qg * 1536 + (size_t)lane * 8;
  const bf16x8 qh0 = *(const bf16x8*)(hqb);
  const bf16x8 qh1 = *(const bf16x8*)(hqb + 512);
  const bf16x8 qh2 = *(const bf16x8*)(hqb + 1024);
  const bf16x8 ql0 = *(const bf16x8*)(lqb);
  const bf16x8 ql1 = *(const bf16x8*)(lqb + 512);
  const bf16x8 ql2 = *(const bf16x8*)(lqb + 1024);

  DECL12
  float f0 = -FLT_MAX, f1 = -FLT_MAX, f2 = -FLT_MAX, f3 = -FLT_MAX;
  int   g0 = 0, g1 = 0, g2 = 0, g3 = 0;
  int   bcnt = 0;

  const int jchunk = w * 1024;
  #pragma unroll 1
  for (int jt = 0; jt < 16; ++jt) {
    const int g16 = (jchunk >> 4) + jt * 4;
    const ushort* hpb = hb + (size_t)g16 * 1536 + (size_t)lane * 8;
    const ushort* lpb = lb + (size_t)g16 * 1536 + (size_t)lane * 8;
    #pragma unroll
    for (int jb = 0; jb < 4; ++jb) {
      const ushort* ph = hpb + jb * 1536;
      const ushort* pl = lpb + jb * 1536;
      const bf16x8 a0 = *(const bf16x8*)(ph);
      const bf16x8 a1 = *(const bf16x8*)(ph + 512);
      const bf16x8 a2 = *(const bf16x8*)(ph + 1024);
      const bf16x8 b0 = *(const bf16x8*)(pl);
      const bf16x8 b1 = *(const bf16x8*)(pl + 512);
      const bf16x8 b2 = *(const bf16x8*)(pl + 1024);
      f32x4 c = {0.f, 0.f, 0.f, 0.f};
      c = MFMA16(a0, qh0, c);
      c = MFMA16(a1, qh1, c);
      c = MFMA16(a2, qh2, c);
      c = MFMA16(a0, ql0, c);
      c = MFMA16(a1, ql1, c);
      c = MFMA16(a2, ql2, c);
      c = MFMA16(b0, qh0, c);
      c = MFMA16(b1, qh1, c);
      c = MFMA16(b2, qh2, c);
      const int jbase = jchunk + jt * 64 + jb * 16 + fg * 4;
      const float4 s4 = *(const float4*)(sqb + jbase);
      #pragma unroll
      for (int r = 0; r < 4; ++r) {
        const float sj = r == 0 ? s4.x : r == 1 ? s4.y : r == 2 ? s4.z : s4.w;
        const float neg = 2.f * c[r] - sqi - sj;
        if (neg > v11) {                 // strict >: earlier index wins ties
          const bool c0 = (bcnt == 0), c1 = (bcnt == 1),
                     c2 = (bcnt == 2), c3 = (bcnt == 3);
          const int ci0 = jbase + r;
          f0 = c0 ? neg : f0; g0 = c0 ? ci0 : g0;
          f1 = c1 ? neg : f1; g1 = c1 ? ci0 : g1;
          f2 = c2 ? neg : f2; g2 = c2 ? ci0 : g2;
          f3 = c3 ? neg : f3; g3 = c3 ? ci0 : g3;
          ++bcnt;
        }
        if (__any(bcnt == 4)) { FLUSHBUF }
      }
    }
  }
  if (__any(bcnt > 0)) { FLUSHBUF }

  {
    float* lvp = &lv[w][fg][fm][0];
    ushort* lip = &liu[w][fg][fm][0];
    lvp[0]=v0; lvp[1]=v1; lvp[2]=v2; lvp[3]=v3; lvp[4]=v4;
    lvp[5]=v5; lvp[6]=v6; lvp[7]=v7; lvp[8]=v8; lvp[9]=v9;
    lvp[10]=v10; lvp[11]=v11;
    lvp[12]=-FLT_MAX;
    lip[0]=(ushort)y0; lip[1]=(ushort)y1; lip[2]=(ushort)y2; lip[3]=(ushort)y3;
    lip[4]=(ushort)y4; lip[5]=(ushort)y5; lip[6]=(ushort)y6; lip[7]=(ushort)y7;
    lip[8]=(ushort)y8; lip[9]=(ushort)y9; lip[10]=(ushort)y10; lip[11]=(ushort)y11;
    lip[12]=0xFFFFu;
  }
  __syncthreads();

  if (t < 16) {
    int p[16];
    #pragma unroll
    for (int c2 = 0; c2 < 16; ++c2) p[c2] = 0;
    #pragma unroll 1
    for (int r = 0; r < L_; ++r) {
      float bv = -FLT_MAX; int bi2 = INT_MAX; int bc = 0;
      #pragma unroll
      for (int c2 = 0; c2 < 16; ++c2) {
        float v = lv[c2 >> 2][c2 & 3][t][p[c2]];
        int  id = (int)liu[c2 >> 2][c2 & 3][t][p[c2]];
        if (v > bv || (v == bv && id < bi2)) { bv = v; bi2 = id; bc = c2; }
      }
      mid[t][r] = bi2;
      #pragma unroll
      for (int c2 = 0; c2 < 16; ++c2) p[c2] += (bc == c2);
    }
  }
  __syncthreads();

  {
    const double* sqdb = sqd + bN;
    const float* yTb = yT + bN * 96;
    #pragma unroll 1
    for (int task = t; task < 16 * L_; task += 256) {
      const int fq = task / L_, slot = task - fq * L_;
      const int qq = qg * 16 + fq;
      const int j = mid[fq][slot];
      const float4* q4p = (const float4*)(yTb + (size_t)qq * 96);
      const float4* p4p = (const float4*)(yTb + (size_t)j * 96);
      double a0 = 0.0, a1 = 0.0, a2 = 0.0, a3 = 0.0;
      #pragma unroll 4
      for (int m = 0; m < 24; ++m) {
        float4 qm = q4p[m], pm = p4p[m];
        a0 += (double)qm.x * (double)pm.x;
        a1 += (double)qm.y * (double)pm.y;
        a2 += (double)qm.z * (double)pm.z;
        a3 += (double)qm.w * (double)pm.w;
      }
      rv[fq][slot] = 2.0 * ((a0 + a1) + (a2 + a3)) - sqdb[qq] - sqdb[j];
    }
  }
  __syncthreads();

  if (t < 16) {
    double bd[16]; int bix[16];
    #pragma unroll
    for (int i = 0; i < 16; ++i) { bd[i] = -DBL_MAX; bix[i] = INT_MAX; }
    #pragma unroll 1
    for (int r = 0; r < L_; ++r) {
      double v = rv[t][r]; int id = mid[t][r];
      if (v > bd[15] || (v == bd[15] && id < bix[15])) {
        #pragma unroll
        for (int i = 0; i < 16; ++i) {
          if (v > bd[i] || (v == bd[i] && id < bix[i])) {
            double tv = bd[i]; bd[i] = v; v = tv;
            int ti = bix[i]; bix[i] = id; id = ti;
          }
        }
      }
    }
    int* outp = knn + (bN + (size_t)(qg * 16 + t)) * 16;
    #pragma unroll
    for (int r = 0; r < 16; ++r) outp[r] = bix[r];
  }
}

__device__ __forceinline__ float f4e(const float4& v, int i) {
  return i == 0 ? v.x : i == 1 ? v.y : i == 2 ? v.z : v.w;
}

// kC v2 (round 14): 1 wave = 1 query; lane = k*4+g; parallel k, one set of
// shuffle reductions. Unchanged.
__global__ __launch_bounds__(256) void kC_main(
    const float* __restrict__ x, const float* __restrict__ yT,
    const int* __restrict__ knn,
    const float* __restrict__ Wq, const float* __restrict__ Eq,
    const float* __restrict__ Wk, const float* __restrict__ Ek,
    const float* __restrict__ Wv, const float* __restrict__ Ev,
    float* __restrict__ out) {
  __shared__ float sWkL[32][32], sEkL[32][32], sWvL[32][32], sEvL[32][32];
  __shared__ float sWkD[32][32], sEkD[32][32], sWvD[32][32], sEvD[32][32];
  __shared__ float sQxOut[4][96];
  __shared__ float sCK[4][32][6];
  __shared__ float sCV[4][32][6];

  const int t = threadIdx.x;
  const int w = t >> 6, lane = t & 63;
  const int kk = lane >> 2, g = lane & 3;
  const int blk = blockIdx.x;
  const int b = blk & 7;
  const int n = ((blk >> 3) << 2) + w;
  const size_t bN = (size_t)b * N_;

  {
    int oc = t >> 3, icq = (t & 7) * 4;
    const float4 klo = *(const float4*)(Wk + oc * 64 + icq);
    const float4 khi = *(const float4*)(Wk + oc * 64 + 32 + icq);
    const float4 elo = *(const float4*)(Ek + oc * 64 + icq);
    const float4 ehi = *(const float4*)(Ek + oc * 64 + 32 + icq);
    const float4 vlo = *(const float4*)(Wv + oc * 64 + icq);
    const float4 vhi = *(const float4*)(Wv + oc * 64 + 32 + icq);
    const float4 flo = *(const float4*)(Ev + oc * 64 + icq);
    const float4 fhi = *(const float4*)(Ev + oc * 64 + 32 + icq);
    #pragma unroll
    for (int i = 0; i < 4; ++i) {
      sWkL[icq + i][oc] = f4e(klo, i); sWkD[icq + i][oc] = f4e(khi, i) - f4e(klo, i);
      sEkL[icq + i][oc] = f4e(elo, i); sEkD[icq + i][oc] = f4e(ehi, i) - f4e(elo, i);
      sWvL[icq + i][oc] = f4e(vlo, i); sWvD[icq + i][oc] = f4e(vhi, i) - f4e(vlo, i);
      sEvL[icq + i][oc] = f4e(flo, i); sEvD[icq + i][oc] = f4e(fhi, i) - f4e(flo, i);
    }
  }
  __syncthreads();

  const float* ctr = yT + (bN + n) * 96;

  if (lane < 32) {
    const int oc = lane;
    const float* xb = x + (size_t)b * 96 * N_ + n;
    float pq[3] = {0,0,0}, dq[3] = {0,0,0};
    float pk[3] = {0,0,0}, dk[3] = {0,0,0};
    float pv[3] = {0,0,0}, dv[3] = {0,0,0};
    #pragma unroll 4
    for (int ic = 0; ic < 32; ++ic) {
      float wq = Wq[oc * 32 + ic], eq = Eq[oc * 32 + ic];
      float wkd = sWkD[ic][oc], ekd = sEkD[ic][oc];
      float wvd = sWvD[ic][oc], evd = sEvD[ic][oc];
      #pragma unroll
      for (int d = 0; d < 3; ++d) {
        float xv = xb[(size_t)(ic * 3 + d) * N_];
        float cv = ctr[ic * 3 + d];
        pq[d] = fmaf(wq, xv, pq[d]);  dq[d] = fmaf(eq, xv, dq[d]);
        pk[d] = fmaf(wkd, cv, pk[d]); dk[d] = fmaf(ekd, cv, dk[d]);
        pv[d] = fmaf(wvd, cv, pv[d]); dv[d] = fmaf(evd, cv, dv[d]);
      }
    }
    float dot = pq[0]*dq[0] + pq[1]*dq[1] + pq[2]*dq[2];
    float dsq = dq[0]*dq[0] + dq[1]*dq[1] + dq[2]*dq[2] + 1e-6f;
    float r = dot / dsq;
    float qv[3];
    #pragma unroll
    for (int d = 0; d < 3; ++d) {
      float pn = pq[d] - r * dq[d];
      qv[d] = 0.2f * pq[d] + 0.8f * (dot >= 0.f ? pq[d] : pn);
    }
    float nn = sqrtf(qv[0]*qv[0] + qv[1]*qv[1] + qv[2]*qv[2]);
    float nch2 = nn * nn;
    #pragma unroll
    for (int m = 1; m <= 16; m <<= 1) nch2 += __shfl_xor(nch2, m, 32);
    float s = (nn / fmaxf(sqrtf(nch2), 1e-12f)) / fmaxf(nn, 1e-12f);
    #pragma unroll
    for (int d = 0; d < 3; ++d) {
      sQxOut[w][oc * 3 + d] = qv[d] * s;
      sCK[w][oc][d] = pk[d]; sCK[w][oc][3 + d] = dk[d];
      sCV[w][oc][d] = pv[d]; sCV[w][oc][3 + d] = dv[d];
    }
  }
  __syncthreads();

  const int jn = knn[(bN + n) * 16 + kk];
  const float4* nb4 = (const float4*)(yT + (bN + (size_t)jn) * 96);
  const int oc0 = g * 8;

  float aP[8][3], aD[8][3];

  // ===== K pass =====
  {
    const float4* ck = (const float4*)&sCK[w][oc0][0];
    #pragma unroll
    for (int m = 0; m < 12; ++m) {
      float4 v = ck[m];
      #pragma unroll
      for (int e = 0; e < 4; ++e) {
        int f = m * 4 + e, oi = f / 6, r2 = f % 6;
        if (r2 < 3) aP[oi][r2] = f4e(v, e); else aD[oi][r2 - 3] = f4e(v, e);
      }
    }
  }
  #pragma unroll 2
  for (int ch = 0; ch < 8; ++ch) {
    float4 r0 = nb4[ch * 3], r1 = nb4[ch * 3 + 1], r2 = nb4[ch * 3 + 2];
    #pragma unroll
    for (int icl = 0; icl < 4; ++icl) {
      int ic = ch * 4 + icl;
      float4 wA = *(const float4*)&sWkL[ic][oc0];
      float4 wB = *(const float4*)&sWkL[ic][oc0 + 4];
      float4 eA = *(const float4*)&sEkL[ic][oc0];
      float4 eB = *(const float4*)&sEkL[ic][oc0 + 4];
      #pragma unroll
      for (int d = 0; d < 3; ++d) {
        int f = icl * 3 + d;
        float v = f < 4 ? f4e(r0, f) : f < 8 ? f4e(r1, f - 4) : f4e(r2, f - 8);
        #pragma unroll
        for (int oi = 0; oi < 4; ++oi) {
          aP[oi][d]     = fmaf(f4e(wA, oi), v, aP[oi][d]);
          aD[oi][d]     = fmaf(f4e(eA, oi), v, aD[oi][d]);
          aP[oi + 4][d] = fmaf(f4e(wB, oi), v, aP[oi + 4][d]);
          aD[oi + 4][d] = fmaf(f4e(eB, oi), v, aD[oi + 4][d]);
        }
      }
    }
  }
  float att;
  {
    float part = 0.f, nchp = 0.f;
    #pragma unroll
    for (int oi = 0; oi < 8; ++oi) {
      float dot = aP[oi][0]*aD[oi][0] + aP[oi][1]*aD[oi][1] + aP[oi][2]*aD[oi][2];
      float dsq = aD[oi][0]*aD[oi][0] + aD[oi][1]*aD[oi][1] + aD[oi][2]*aD[oi][2] + 1e-6f;
      float r = dot / dsq;
      float nn2 = 0.f, qdot = 0.f;
      const float* qx = &sQxOut[w][(oc0 + oi) * 3];
      #pragma unroll
      for (int d = 0; d < 3; ++d) {
        float pn = aP[oi][d] - r * aD[oi][d];
        float ky = 0.2f * aP[oi][d] + 0.8f * (dot >= 0.f ? aP[oi][d] : pn);
        nn2 = fmaf(ky, ky, nn2);
        qdot = fmaf(ky, qx[d], qdot);
      }
      float nn = sqrtf(nn2);
      part = fmaf(nn / fmaxf(nn, 1e-12f), qdot, part);
      nchp += nn2;
    }
    float nch2 = nchp + __shfl_xor(nchp, 1);
    nch2 += __shfl_xor(nch2, 2);
    float qk = part + __shfl_xor(part, 1);
    float score = qk / fmaxf(sqrtf(nch2), 1e-12f) * 0.14433756729740643f;
    float mx = score;
    #pragma unroll
    for (int m = 4; m <= 32; m <<= 1) mx = fmaxf(mx, __shfl_xor(mx, m));
    float ex = expf(score - mx);
    float sm = ex;
    #pragma unroll
    for (int m = 4; m <= 32; m <<= 1) sm += __shfl_xor(sm, m);
    att = ex / sm;
  }

  // ===== V pass =====
  {
    const float4* cv4 = (const float4*)&sCV[w][oc0][0];
    #pragma unroll
    for (int m = 0; m < 12; ++m) {
      float4 v = cv4[m];
      #pragma unroll
      for (int e = 0; e < 4; ++e) {
        int f = m * 4 + e, oi = f / 6, r2 = f % 6;
        if (r2 < 3) aP[oi][r2] = f4e(v, e); else aD[oi][r2 - 3] = f4e(v, e);
      }
    }
  }
  #pragma unroll 2
  for (int ch = 0; ch < 8; ++ch) {
    float4 r0 = nb4[ch * 3], r1 = nb4[ch * 3 + 1], r2 = nb4[ch * 3 + 2];
    #pragma unroll
    for (int icl = 0; icl < 4; ++icl) {
      int ic = ch * 4 + icl;
      float4 wA = *(const float4*)&sWvL[ic][oc0];
      float4 wB = *(const float4*)&sWvL[ic][oc0 + 4];
      float4 eA = *(const float4*)&sEvL[ic][oc0];
      float4 eB = *(const float4*)&sEvL[ic][oc0 + 4];
      #pragma unroll
      for (int d = 0; d < 3; ++d) {
        int f = icl * 3 + d;
        float v = f < 4 ? f4e(r0, f) : f < 8 ? f4e(r1, f - 4) : f4e(r2, f - 8);
        #pragma unroll
        for (int oi = 0; oi < 4; ++oi) {
          aP[oi][d]     = fmaf(f4e(wA, oi), v, aP[oi][d]);
          aD[oi][d]     = fmaf(f4e(eA, oi), v, aD[oi][d]);
          aP[oi + 4][d] = fmaf(f4e(wB, oi), v, aP[oi + 4][d]);
          aD[oi + 4][d] = fmaf(f4e(eB, oi), v, aD[oi + 4][d]);
        }
      }
    }
  }
  #pragma unroll
  for (int oi = 0; oi < 8; ++oi) {
    float dot = aP[oi][0]*aD[oi][0] + aP[oi][1]*aD[oi][1] + aP[oi][2]*aD[oi][2];
    float dsq = aD[oi][0]*aD[oi][0] + aD[oi][1]*aD[oi][1] + aD[oi][2]*aD[oi][2] + 1e-6f;
    float r = dot / dsq;
    #pragma unroll
    for (int d = 0; d < 3; ++d) {
      float pn = aP[oi][d] - r * aD[oi][d];
      float vy = 0.2f * aP[oi][d] + 0.8f * (dot >= 0.f ? aP[oi][d] : pn);
      aP[oi][d] = att * vy;
    }
  }
  #pragma unroll
  for (int m = 4; m <= 32; m <<= 1) {
    #pragma unroll
    for (int oi = 0; oi < 8; ++oi) {
      #pragma unroll
      for (int d = 0; d < 3; ++d) aP[oi][d] += __shfl_xor(aP[oi][d], m);
    }
  }
  if (kk == 0) {
    #pragma unroll
    for (int oi = 0; oi < 8; ++oi)
      #pragma unroll
      for (int d = 0; d < 3; ++d)
        sQxOut[w][(oc0 + oi) * 3 + d] = aP[oi][d];
  }
  __syncthreads();

  const int nb0 = (blk >> 3) << 2;
  for (int idx = t; idx < 384; idx += 256) {
    int qq = idx & 3, od = idx >> 2;
    size_t a = ((size_t)b * 96 + od) * N_ + nb0 + qq;
    out[a] = x[a] + sQxOut[qq][od];
  }
}

extern "C" void kernel_launch(void* const* d_in, const int* in_sizes, int n_in,
                              void* d_out, int out_size, void* d_ws, size_t ws_size,
                              hipStream_t stream) {
  const float* x  = (const float*)d_in[0];
  const float* y  = (const float*)d_in[1];
  const float* Wq = (const float*)d_in[2];
  const float* Dq = (const float*)d_in[3];
  const float* Wk = (const float*)d_in[4];
  const float* Dk = (const float*)d_in[5];
  const float* Wv = (const float*)d_in[6];
  const float* Dv = (const float*)d_in[7];
  float* out = (float*)d_out;

  char* wsb = (char*)d_ws;
  float*  yT  = (float*)wsb;                                   // 12,582,912 B
  double* sqd = (double*)(wsb + 12582912);                     //    262,144 B
  float*  sq  = (float*)(wsb + 12845056);                      //    131,072 B
  int*    knn = (int*)(wsb + 12976128);                        //  2,097,152 B
  ushort* hBs = (ushort*)(wsb + 15073280);                     //  6,291,456 B
  ushort* lBs = (ushort*)(wsb + 21364736);                     //  6,291,456 B
  float*  Ek  = (float*)(wsb + 27656192);                      //      8,192 B
  float*  Ev  = Ek + 2048;
  float*  Eq  = Ev + 2048;

  kE_combine<<<dim3(1), dim3(256), 0, stream>>>(Wk, Dk, Wv, Dv, Wq, Dq, Ek, Ev, Eq);
  kA_transpose<<<dim3(512), dim3(256), 0, stream>>>(y, yT, sq, sqd, hBs, lBs);
  kB_knn<<<dim3(2048), dim3(256), 0, stream>>>(yT, hBs, lBs, sq, sqd, knn);
  kC_main<<<dim3(8192), dim3(256), 0, stream>>>(x, yT, knn, Wq, Eq, Wk, Ek, Wv, Ev, out);
}

// Round 16
// 580.713 us; speedup vs baseline: 3.0184x; 1.0146x over previous
//
#include <hip/hip_runtime.h>
#include <math.h>
#include <float.h>
#include <limits.h>

#define B_ 8
#define C_ 32
#define N_ 4096
#define K_ 16
#define L_ 20   // merged candidate depth (fp32-inversion margin 4, proven)
#define LL 11   // per-lane register list depth (P(lane share >11 of top-20) ~ 1e-4 total)

typedef __attribute__((ext_vector_type(8))) short bf16x8;
typedef __attribute__((ext_vector_type(4))) float f32x4;
#define MFMA16(a, b, c) __builtin_amdgcn_mfma_f32_16x16x32_bf16(a, b, c, 0, 0, 0)

// ------------------------------------------------------------------
// ws layout (bytes):
//   yT  : [B][N][96] float    12,582,912
//   sqd : [B][N]     double      262,144
//   sq  : [B][N]     float       131,072
//   knn : [B][N][16] int       2,097,152
//   hBs : swizzled bf16 hi     6,291,456
//   lBs : swizzled bf16 lo     6,291,456
//   Ek/Ev/Eq floats               20,480
// ------------------------------------------------------------------

__global__ __launch_bounds__(256) void kE_combine(
    const float* __restrict__ Wk, const float* __restrict__ Dk,
    const float* __restrict__ Wv, const float* __restrict__ Dv,
    const float* __restrict__ Wq, const float* __restrict__ Dq,
    float* __restrict__ Ek, float* __restrict__ Ev, float* __restrict__ Eq) {
  int t = threadIdx.x;
  for (int e = t; e < 2048; e += 256) {
    int o = e >> 6, c = e & 63;
    float a = 0.f, v = 0.f;
    for (int m = 0; m < 32; ++m) {
      a = fmaf(Dk[o * 32 + m], Wk[m * 64 + c], a);
      v = fmaf(Dv[o * 32 + m], Wv[m * 64 + c], v);
    }
    Ek[e] = a; Ev[e] = v;
  }
  for (int e = t; e < 1024; e += 256) {
    int o = e >> 5, c = e & 31;
    float a = 0.f;
    for (int m = 0; m < 32; ++m) a = fmaf(Dq[o * 32 + m], Wq[m * 32 + c], a);
    Eq[e] = a;
  }
}

__global__ __launch_bounds__(256) void kA_transpose(
    const float* __restrict__ y, float* __restrict__ yT,
    float* __restrict__ sq, double* __restrict__ sqd,
    ushort* __restrict__ hBs, ushort* __restrict__ lBs) {
  __shared__ float tile[96][65];
  int b = blockIdx.x >> 6;
  int n0 = (blockIdx.x & 63) * 64;
  int t = threadIdx.x;
  int g = t >> 6, ln = t & 63;
  #pragma unroll
  for (int r = 0; r < 24; ++r) {
    int d = g * 24 + r;
    tile[d][ln] = y[((size_t)b * 96 + d) * N_ + n0 + ln];
  }
  __syncthreads();
  if (t < 64) {
    float s = 0.f; double sd = 0.0;
    #pragma unroll
    for (int d = 0; d < 96; ++d) {
      float v = tile[d][t];
      s = fmaf(v, v, s);
      sd += (double)v * (double)v;
    }
    sq[b * N_ + n0 + t] = s;
    sqd[b * N_ + n0 + t] = sd;
  }
  for (int idx = t; idx < 64 * 96; idx += 256) {
    int nl = idx / 96, d = idx % 96;
    yT[((size_t)b * N_ + n0 + nl) * 96 + d] = tile[d][nl];
  }
  for (int idx = t; idx < 768; idx += 256) {
    int g16l = idx / 192;
    int rem = idx - g16l * 192;
    int sl = rem >> 6;
    int ln2 = rem & 63;
    int fg2 = ln2 >> 4, fm2 = ln2 & 15;
    int nl = g16l * 16 + fm2;
    uint hw[4], lw[4];
    #pragma unroll
    for (int e2 = 0; e2 < 4; ++e2) {
      float v0 = tile[sl * 32 + fg2 * 8 + 2 * e2][nl];
      float v1 = tile[sl * 32 + fg2 * 8 + 2 * e2 + 1][nl];
      uint x0 = __float_as_uint(v0), x1 = __float_as_uint(v1);
      uint h0 = x0 >> 16, h1 = x1 >> 16;
      float r0 = v0 - __uint_as_float(h0 << 16);
      float r1 = v1 - __uint_as_float(h1 << 16);
      uint l0 = __float_as_uint(r0) >> 16, l1 = __float_as_uint(r1) >> 16;
      hw[e2] = h0 | (h1 << 16);
      lw[e2] = l0 | (l1 << 16);
    }
    size_t off = (size_t)b * 393216 +
                 (((size_t)(n0 >> 4) + g16l) * 3 + sl) * 512 + (size_t)ln2 * 8;
    *(uint4*)(hBs + off) = make_uint4(hw[0], hw[1], hw[2], hw[3]);
    *(uint4*)(lBs + off) = make_uint4(lw[0], lw[1], lw[2], lw[3]);
  }
}

// Named-register top-11 + 4-deep buffered insert (r15 idiom). LDS trimmed to
// 19,712B (LL=11, ushort idx, rv aliases lv after merge) so 8 blocks/CU fit:
// whole 2048-block grid resident in ONE scheduling round (was 6/CU + tail).
#define DECL11 \
  float v0=-FLT_MAX,v1=-FLT_MAX,v2=-FLT_MAX,v3=-FLT_MAX,v4=-FLT_MAX, \
        v5=-FLT_MAX,v6=-FLT_MAX,v7=-FLT_MAX,v8=-FLT_MAX,v9=-FLT_MAX, \
        v10=-FLT_MAX; \
  int y0=0,y1=0,y2=0,y3=0,y4=0,y5=0,y6=0,y7=0,y8=0,y9=0,y10=0;

#define CX(i) { bool cc = cv > v##i; \
  float tf = cc ? v##i : cv; int ti = cc ? y##i : ci; \
  v##i = cc ? cv : v##i; y##i = cc ? ci : y##i; cv = tf; ci = ti; }

#define INSERT11 { CX(0) CX(1) CX(2) CX(3) CX(4) CX(5) CX(6) CX(7) CX(8) CX(9) \
  CX(10) }

#define FLUSHBUF { \
  if (bcnt > 0) { float cv = f0; int ci = g0; if (cv > v10) { INSERT11 } } \
  if (bcnt > 1) { float cv = f1; int ci = g1; if (cv > v10) { INSERT11 } } \
  if (bcnt > 2) { float cv = f2; int ci = g2; if (cv > v10) { INSERT11 } } \
  if (bcnt > 3) { float cv = f3; int ci = g3; if (cv > v10) { INSERT11 } } \
  bcnt = 0; }

__global__ __launch_bounds__(256) void kB_knn(
    const float* __restrict__ yT, const ushort* __restrict__ hBs,
    const ushort* __restrict__ lBs, const float* __restrict__ sq,
    const double* __restrict__ sqd, int* __restrict__ knn) {
  // smem map: lv [4][4][16][12] f32 = 12,288 | liu [4][4][16][12] u16 = 6,144
  //           mid [16][20] int = 1,280  => 19,712 B total.
  //           rv [16][20] dbl (2,560) ALIASES lv (merge finishes reading lv
  //           before the barrier preceding rescore writes).
  __shared__ __align__(16) char smem[19712];
  float  (*lv)[4][16][12]  = (float  (*)[4][16][12])smem;
  ushort (*liu)[4][16][12] = (ushort (*)[4][16][12])(smem + 12288);
  int    (*mid)[L_]        = (int    (*)[L_])(smem + 18432);
  double (*rv)[L_]         = (double (*)[L_])smem;            // alias lv

  const int t = threadIdx.x;
  const int lane = t & 63;
  const int w = t >> 6;
  const int fg = lane >> 4, fm = lane & 15;
  const int b = blockIdx.x & 7;
  const int qg = blockIdx.x >> 3;
  const int q = qg * 16 + fm;
  const size_t bN = (size_t)b * N_;
  const ushort* hb = hBs + bN * 96;
  const ushort* lb = lBs + bN * 96;
  const float* sqb = sq + bN;
  const float sqi = sqb[q];

  const ushort* hqb = hb + (size_t)qg * 1536 + (size_t)lane * 8;
  const ushort* lqb = lb + (size_t)qg * 1536 + (size_t)lane * 8;
  const bf16x8 qh0 = *(const bf16x8*)(hqb);
  const bf16x8 qh1 = *(const bf16x8*)(hqb + 512);
  const bf16x8 qh2 = *(const bf16x8*)(hqb + 1024);
  const bf16x8 ql0 = *(const bf16x8*)(lqb);
  const bf16x8 ql1 = *(const bf16x8*)(lqb + 512);
  const bf16x8 ql2 = *(const bf16x8*)(lqb + 1024);

  DECL11
  float f0 = -FLT_MAX, f1 = -FLT_MAX, f2 = -FLT_MAX, f3 = -FLT_MAX;
  int   g0 = 0, g1 = 0, g2 = 0, g3 = 0;
  int   bcnt = 0;

  const int jchunk = w * 1024;
  #pragma unroll 1
  for (int jt = 0; jt < 16; ++jt) {
    const int g16 = (jchunk >> 4) + jt * 4;
    const ushort* hpb = hb + (size_t)g16 * 1536 + (size_t)lane * 8;
    const ushort* lpb = lb + (size_t)g16 * 1536 + (size_t)lane * 8;
    #pragma unroll
    for (int jb = 0; jb < 4; ++jb) {
      const ushort* ph = hpb + jb * 1536;
      const ushort* pl = lpb + jb * 1536;
      const bf16x8 a0 = *(const bf16x8*)(ph);
      const bf16x8 a1 = *(const bf16x8*)(ph + 512);
      const bf16x8 a2 = *(const bf16x8*)(ph + 1024);
      const bf16x8 b0 = *(const bf16x8*)(pl);
      const bf16x8 b1 = *(const bf16x8*)(pl + 512);
      const bf16x8 b2 = *(const bf16x8*)(pl + 1024);
      f32x4 c = {0.f, 0.f, 0.f, 0.f};
      c = MFMA16(a0, qh0, c);
      c = MFMA16(a1, qh1, c);
      c = MFMA16(a2, qh2, c);
      c = MFMA16(a0, ql0, c);
      c = MFMA16(a1, ql1, c);
      c = MFMA16(a2, ql2, c);
      c = MFMA16(b0, qh0, c);
      c = MFMA16(b1, qh1, c);
      c = MFMA16(b2, qh2, c);
      const int jbase = jchunk + jt * 64 + jb * 16 + fg * 4;
      const float4 s4 = *(const float4*)(sqb + jbase);
      #pragma unroll
      for (int r = 0; r < 4; ++r) {
        const float sj = r == 0 ? s4.x : r == 1 ? s4.y : r == 2 ? s4.z : s4.w;
        const float neg = 2.f * c[r] - sqi - sj;
        if (neg > v10) {                 // strict >: earlier index wins ties
          const bool c0 = (bcnt == 0), c1 = (bcnt == 1),
                     c2 = (bcnt == 2), c3 = (bcnt == 3);
          const int ci0 = jbase + r;
          f0 = c0 ? neg : f0; g0 = c0 ? ci0 : g0;
          f1 = c1 ? neg : f1; g1 = c1 ? ci0 : g1;
          f2 = c2 ? neg : f2; g2 = c2 ? ci0 : g2;
          f3 = c3 ? neg : f3; g3 = c3 ? ci0 : g3;
          ++bcnt;
        }
        if (__any(bcnt == 4)) { FLUSHBUF }
      }
    }
  }
  if (__any(bcnt > 0)) { FLUSHBUF }

  // ---- per-lane sorted lists + sentinel ----
  {
    float* lvp = &lv[w][fg][fm][0];
    ushort* lip = &liu[w][fg][fm][0];
    lvp[0]=v0; lvp[1]=v1; lvp[2]=v2; lvp[3]=v3; lvp[4]=v4;
    lvp[5]=v5; lvp[6]=v6; lvp[7]=v7; lvp[8]=v8; lvp[9]=v9;
    lvp[10]=v10;
    lvp[11]=-FLT_MAX;
    lip[0]=(ushort)y0; lip[1]=(ushort)y1; lip[2]=(ushort)y2; lip[3]=(ushort)y3;
    lip[4]=(ushort)y4; lip[5]=(ushort)y5; lip[6]=(ushort)y6; lip[7]=(ushort)y7;
    lip[8]=(ushort)y8; lip[9]=(ushort)y9; lip[10]=(ushort)y10;
    lip[11]=0xFFFFu;
  }
  __syncthreads();

  // ---- 16-way exact merge (threads 0..15): top-20 into mid ----
  if (t < 16) {
    int p[16];
    #pragma unroll
    for (int c2 = 0; c2 < 16; ++c2) p[c2] = 0;
    #pragma unroll 1
    for (int r = 0; r < L_; ++r) {
      float bv = -FLT_MAX; int bi2 = INT_MAX; int bc = 0;
      #pragma unroll
      for (int c2 = 0; c2 < 16; ++c2) {
        float v = lv[c2 >> 2][c2 & 3][t][p[c2]];
        int  id = (int)liu[c2 >> 2][c2 & 3][t][p[c2]];
        if (v > bv || (v == bv && id < bi2)) { bv = v; bi2 = id; bc = c2; }
      }
      mid[t][r] = bi2;
      #pragma unroll
      for (int c2 = 0; c2 < 16; ++c2) p[c2] += (bc == c2);
    }
  }
  __syncthreads();   // merge done reading lv -> rv (alias) may be written

  // ---- fp64 exact re-score: 320 tasks (16 q x 20 cand) ----
  {
    const double* sqdb = sqd + bN;
    const float* yTb = yT + bN * 96;
    #pragma unroll 1
    for (int task = t; task < 16 * L_; task += 256) {
      const int fq = task / L_, slot = task - fq * L_;
      const int qq = qg * 16 + fq;
      const int j = mid[fq][slot];
      const float4* q4p = (const float4*)(yTb + (size_t)qq * 96);
      const float4* p4p = (const float4*)(yTb + (size_t)j * 96);
      double a0 = 0.0, a1 = 0.0, a2 = 0.0, a3 = 0.0;
      #pragma unroll 4
      for (int m = 0; m < 24; ++m) {
        float4 qm = q4p[m], pm = p4p[m];
        a0 += (double)qm.x * (double)pm.x;
        a1 += (double)qm.y * (double)pm.y;
        a2 += (double)qm.z * (double)pm.z;
        a3 += (double)qm.w * (double)pm.w;
      }
      rv[fq][slot] = 2.0 * ((a0 + a1) + (a2 + a3)) - sqdb[qq] - sqdb[j];
    }
  }
  __syncthreads();

  // ---- final exact sorted top-16 (threads 0..15) ----
  if (t < 16) {
    double bd[16]; int bix[16];
    #pragma unroll
    for (int i = 0; i < 16; ++i) { bd[i] = -DBL_MAX; bix[i] = INT_MAX; }
    #pragma unroll 1
    for (int r = 0; r < L_; ++r) {
      double v = rv[t][r]; int id = mid[t][r];
      if (v > bd[15] || (v == bd[15] && id < bix[15])) {
        #pragma unroll
        for (int i = 0; i < 16; ++i) {
          if (v > bd[i] || (v == bd[i] && id < bix[i])) {
            double tv = bd[i]; bd[i] = v; v = tv;
            int ti = bix[i]; bix[i] = id; id = ti;
          }
        }
      }
    }
    int* outp = knn + (bN + (size_t)(qg * 16 + t)) * 16;
    #pragma unroll
    for (int r = 0; r < 16; ++r) outp[r] = bix[r];
  }
}

__device__ __forceinline__ float f4e(const float4& v, int i) {
  return i == 0 ? v.x : i == 1 ? v.y : i == 2 ? v.z : v.w;
}

// kC v2 (round 14): 1 wave = 1 query; lane = k*4+g; parallel k, one set of
// shuffle reductions. Unchanged.
__global__ __launch_bounds__(256) void kC_main(
    const float* __restrict__ x, const float* __restrict__ yT,
    const int* __restrict__ knn,
    const float* __restrict__ Wq, const float* __restrict__ Eq,
    const float* __restrict__ Wk, const float* __restrict__ Ek,
    const float* __restrict__ Wv, const float* __restrict__ Ev,
    float* __restrict__ out) {
  __shared__ float sWkL[32][32], sEkL[32][32], sWvL[32][32], sEvL[32][32];
  __shared__ float sWkD[32][32], sEkD[32][32], sWvD[32][32], sEvD[32][32];
  __shared__ float sQxOut[4][96];
  __shared__ float sCK[4][32][6];
  __shared__ float sCV[4][32][6];

  const int t = threadIdx.x;
  const int w = t >> 6, lane = t & 63;
  const int kk = lane >> 2, g = lane & 3;
  const int blk = blockIdx.x;
  const int b = blk & 7;
  const int n = ((blk >> 3) << 2) + w;
  const size_t bN = (size_t)b * N_;

  {
    int oc = t >> 3, icq = (t & 7) * 4;
    const float4 klo = *(const float4*)(Wk + oc * 64 + icq);
    const float4 khi = *(const float4*)(Wk + oc * 64 + 32 + icq);
    const float4 elo = *(const float4*)(Ek + oc * 64 + icq);
    const float4 ehi = *(const float4*)(Ek + oc * 64 + 32 + icq);
    const float4 vlo = *(const float4*)(Wv + oc * 64 + icq);
    const float4 vhi = *(const float4*)(Wv + oc * 64 + 32 + icq);
    const float4 flo = *(const float4*)(Ev + oc * 64 + icq);
    const float4 fhi = *(const float4*)(Ev + oc * 64 + 32 + icq);
    #pragma unroll
    for (int i = 0; i < 4; ++i) {
      sWkL[icq + i][oc] = f4e(klo, i); sWkD[icq + i][oc] = f4e(khi, i) - f4e(klo, i);
      sEkL[icq + i][oc] = f4e(elo, i); sEkD[icq + i][oc] = f4e(ehi, i) - f4e(elo, i);
      sWvL[icq + i][oc] = f4e(vlo, i); sWvD[icq + i][oc] = f4e(vhi, i) - f4e(vlo, i);
      sEvL[icq + i][oc] = f4e(flo, i); sEvD[icq + i][oc] = f4e(fhi, i) - f4e(flo, i);
    }
  }
  __syncthreads();

  const float* ctr = yT + (bN + n) * 96;

  if (lane < 32) {
    const int oc = lane;
    const float* xb = x + (size_t)b * 96 * N_ + n;
    float pq[3] = {0,0,0}, dq[3] = {0,0,0};
    float pk[3] = {0,0,0}, dk[3] = {0,0,0};
    float pv[3] = {0,0,0}, dv[3] = {0,0,0};
    #pragma unroll 4
    for (int ic = 0; ic < 32; ++ic) {
      float wq = Wq[oc * 32 + ic], eq = Eq[oc * 32 + ic];
      float wkd = sWkD[ic][oc], ekd = sEkD[ic][oc];
      float wvd = sWvD[ic][oc], evd = sEvD[ic][oc];
      #pragma unroll
      for (int d = 0; d < 3; ++d) {
        float xv = xb[(size_t)(ic * 3 + d) * N_];
        float cv = ctr[ic * 3 + d];
        pq[d] = fmaf(wq, xv, pq[d]);  dq[d] = fmaf(eq, xv, dq[d]);
        pk[d] = fmaf(wkd, cv, pk[d]); dk[d] = fmaf(ekd, cv, dk[d]);
        pv[d] = fmaf(wvd, cv, pv[d]); dv[d] = fmaf(evd, cv, dv[d]);
      }
    }
    float dot = pq[0]*dq[0] + pq[1]*dq[1] + pq[2]*dq[2];
    float dsq = dq[0]*dq[0] + dq[1]*dq[1] + dq[2]*dq[2] + 1e-6f;
    float r = dot / dsq;
    float qv[3];
    #pragma unroll
    for (int d = 0; d < 3; ++d) {
      float pn = pq[d] - r * dq[d];
      qv[d] = 0.2f * pq[d] + 0.8f * (dot >= 0.f ? pq[d] : pn);
    }
    float nn = sqrtf(qv[0]*qv[0] + qv[1]*qv[1] + qv[2]*qv[2]);
    float nch2 = nn * nn;
    #pragma unroll
    for (int m = 1; m <= 16; m <<= 1) nch2 += __shfl_xor(nch2, m, 32);
    float s = (nn / fmaxf(sqrtf(nch2), 1e-12f)) / fmaxf(nn, 1e-12f);
    #pragma unroll
    for (int d = 0; d < 3; ++d) {
      sQxOut[w][oc * 3 + d] = qv[d] * s;
      sCK[w][oc][d] = pk[d]; sCK[w][oc][3 + d] = dk[d];
      sCV[w][oc][d] = pv[d]; sCV[w][oc][3 + d] = dv[d];
    }
  }
  __syncthreads();

  const int jn = knn[(bN + n) * 16 + kk];
  const float4* nb4 = (const float4*)(yT + (bN + (size_t)jn) * 96);
  const int oc0 = g * 8;

  float aP[8][3], aD[8][3];

  // ===== K pass =====
  {
    const float4* ck = (const float4*)&sCK[w][oc0][0];
    #pragma unroll
    for (int m = 0; m < 12; ++m) {
      float4 v = ck[m];
      #pragma unroll
      for (int e = 0; e < 4; ++e) {
        int f = m * 4 + e, oi = f / 6, r2 = f % 6;
        if (r2 < 3) aP[oi][r2] = f4e(v, e); else aD[oi][r2 - 3] = f4e(v, e);
      }
    }
  }
  #pragma unroll 2
  for (int ch = 0; ch < 8; ++ch) {
    float4 r0 = nb4[ch * 3], r1 = nb4[ch * 3 + 1], r2 = nb4[ch * 3 + 2];
    #pragma unroll
    for (int icl = 0; icl < 4; ++icl) {
      int ic = ch * 4 + icl;
      float4 wA = *(const float4*)&sWkL[ic][oc0];
      float4 wB = *(const float4*)&sWkL[ic][oc0 + 4];
      float4 eA = *(const float4*)&sEkL[ic][oc0];
      float4 eB = *(const float4*)&sEkL[ic][oc0 + 4];
      #pragma unroll
      for (int d = 0; d < 3; ++d) {
        int f = icl * 3 + d;
        float v = f < 4 ? f4e(r0, f) : f < 8 ? f4e(r1, f - 4) : f4e(r2, f - 8);
        #pragma unroll
        for (int oi = 0; oi < 4; ++oi) {
          aP[oi][d]     = fmaf(f4e(wA, oi), v, aP[oi][d]);
          aD[oi][d]     = fmaf(f4e(eA, oi), v, aD[oi][d]);
          aP[oi + 4][d] = fmaf(f4e(wB, oi), v, aP[oi + 4][d]);
          aD[oi + 4][d] = fmaf(f4e(eB, oi), v, aD[oi + 4][d]);
        }
      }
    }
  }
  float att;
  {
    float part = 0.f, nchp = 0.f;
    #pragma unroll
    for (int oi = 0; oi < 8; ++oi) {
      float dot = aP[oi][0]*aD[oi][0] + aP[oi][1]*aD[oi][1] + aP[oi][2]*aD[oi][2];
      float dsq = aD[oi][0]*aD[oi][0] + aD[oi][1]*aD[oi][1] + aD[oi][2]*aD[oi][2] + 1e-6f;
      float r = dot / dsq;
      float nn2 = 0.f, qdot = 0.f;
      const float* qx = &sQxOut[w][(oc0 + oi) * 3];
      #pragma unroll
      for (int d = 0; d < 3; ++d) {
        float pn = aP[oi][d] - r * aD[oi][d];
        float ky = 0.2f * aP[oi][d] + 0.8f * (dot >= 0.f ? aP[oi][d] : pn);
        nn2 = fmaf(ky, ky, nn2);
        qdot = fmaf(ky, qx[d], qdot);
      }
      float nn = sqrtf(nn2);
      part = fmaf(nn / fmaxf(nn, 1e-12f), qdot, part);
      nchp += nn2;
    }
    float nch2 = nchp + __shfl_xor(nchp, 1);
    nch2 += __shfl_xor(nch2, 2);
    float qk = part + __shfl_xor(part, 1);
    float score = qk / fmaxf(sqrtf(nch2), 1e-12f) * 0.14433756729740643f;
    float mx = score;
    #pragma unroll
    for (int m = 4; m <= 32; m <<= 1) mx = fmaxf(mx, __shfl_xor(mx, m));
    float ex = expf(score - mx);
    float sm = ex;
    #pragma unroll
    for (int m = 4; m <= 32; m <<= 1) sm += __shfl_xor(sm, m);
    att = ex / sm;
  }

  // ===== V pass =====
  {
    const float4* cv4 = (const float4*)&sCV[w][oc0][0];
    #pragma unroll
    for (int m = 0; m < 12; ++m) {
      float4 v = cv4[m];
      #pragma unroll
      for (int e = 0; e < 4; ++e) {
        int f = m * 4 + e, oi = f / 6, r2 = f % 6;
        if (r2 < 3) aP[oi][r2] = f4e(v, e); else aD[oi][r2 - 3] = f4e(v, e);
      }
    }
  }
  #pragma unroll 2
  for (int ch = 0; ch < 8; ++ch) {
    float4 r0 = nb4[ch * 3], r1 = nb4[ch * 3 + 1], r2 = nb4[ch * 3 + 2];
    #pragma unroll
    for (int icl = 0; icl < 4; ++icl) {
      int ic = ch * 4 + icl;
      float4 wA = *(const float4*)&sWvL[ic][oc0];
      float4 wB = *(const float4*)&sWvL[ic][oc0 + 4];
      float4 eA = *(const float4*)&sEvL[ic][oc0];
      float4 eB = *(const float4*)&sEvL[ic][oc0 + 4];
      #pragma unroll
      for (int d = 0; d < 3; ++d) {
        int f = icl * 3 + d;
        float v = f < 4 ? f4e(r0, f) : f < 8 ? f4e(r1, f - 4) : f4e(r2, f - 8);
        #pragma unroll
        for (int oi = 0; oi < 4; ++oi) {
          aP[oi][d]     = fmaf(f4e(wA, oi), v, aP[oi][d]);
          aD[oi][d]     = fmaf(f4e(eA, oi), v, aD[oi][d]);
          aP[oi + 4][d] = fmaf(f4e(wB, oi), v, aP[oi + 4][d]);
          aD[oi + 4][d] = fmaf(f4e(eB, oi), v, aD[oi + 4][d]);
        }
      }
    }
  }
  #pragma unroll
  for (int oi = 0; oi < 8; ++oi) {
    float dot = aP[oi][0]*aD[oi][0] + aP[oi][1]*aD[oi][1] + aP[oi][2]*aD[oi][2];
    float dsq = aD[oi][0]*aD[oi][0] + aD[oi][1]*aD[oi][1] + aD[oi][2]*aD[oi][2] + 1e-6f;
    float r = dot / dsq;
    #pragma unroll
    for (int d = 0; d < 3; ++d) {
      float pn = aP[oi][d] - r * aD[oi][d];
      float vy = 0.2f * aP[oi][d] + 0.8f * (dot >= 0.f ? aP[oi][d] : pn);
      aP[oi][d] = att * vy;
    }
  }
  #pragma unroll
  for (int m = 4; m <= 32; m <<= 1) {
    #pragma unroll
    for (int oi = 0; oi < 8; ++oi) {
      #pragma unroll
      for (int d = 0; d < 3; ++d) aP[oi][d] += __shfl_xor(aP[oi][d], m);
    }
  }
  if (kk == 0) {
    #pragma unroll
    for (int oi = 0; oi < 8; ++oi)
      #pragma unroll
      for (int d = 0; d < 3; ++d)
        sQxOut[w][(oc0 + oi) * 3 + d] = aP[oi][d];
  }
  __syncthreads();

  const int nb0 = (blk >> 3) << 2;
  for (int idx = t; idx < 384; idx += 256) {
    int qq = idx & 3, od = idx >> 2;
    size_t a = ((size_t)b * 96 + od) * N_ + nb0 + qq;
    out[a] = x[a] + sQxOut[qq][od];
  }
}

extern "C" void kernel_launch(void* const* d_in, const int* in_sizes, int n_in,
                              void* d_out, int out_size, void* d_ws, size_t ws_size,
                              hipStream_t stream) {
  const float* x  = (const float*)d_in[0];
  const float* y  = (const float*)d_in[1];
  const float* Wq = (const float*)d_in[2];
  const float* Dq = (const float*)d_in[3];
  const float* Wk = (const float*)d_in[4];
  const float* Dk = (const float*)d_in[5];
  const float* Wv = (const float*)d_in[6];
  const float* Dv = (const float*)d_in[7];
  float* out = (float*)d_out;

  char* wsb = (char*)d_ws;
  float*  yT  = (float*)wsb;                                   // 12,582,912 B
  double* sqd = (double*)(wsb + 12582912);                     //    262,144 B
  float*  sq  = (float*)(wsb + 12845056);                      //    131,072 B
  int*    knn = (int*)(wsb + 12976128);                        //  2,097,152 B
  ushort* hBs = (ushort*)(wsb + 15073280);                     //  6,291,456 B
  ushort* lBs = (ushort*)(wsb + 21364736);                     //  6,291,456 B
  float*  Ek  = (float*)(wsb + 27656192);                      //      8,192 B
  float*  Ev  = Ek + 2048;
  float*  Eq  = Ev + 2048;

  kE_combine<<<dim3(1), dim3(256), 0, stream>>>(Wk, Dk, Wv, Dv, Wq, Dq, Ek, Ev, Eq);
  kA_transpose<<<dim3(512), dim3(256), 0, stream>>>(y, yT, sq, sqd, hBs, lBs);
  kB_knn<<<dim3(2048), dim3(256), 0, stream>>>(yT, hBs, lBs, sq, sqd, knn);
  kC_main<<<dim3(8192), dim3(256), 0, stream>>>(x, yT, knn, Wq, Eq, Wk, Ek, Wv, Ev, out);
}

// Round 17
// 575.985 us; speedup vs baseline: 3.0432x; 1.0082x over previous
//
#include <hip/hip_runtime.h>
#include <hip/hip_fp16.h>
#include <math.h>
#include <float.h>
#include <limits.h>

#define B_ 8
#define C_ 32
#define N_ 4096
#define K_ 16
#define L_ 20   // merged candidate depth (fp32-inversion margin 4, proven)
#define LL 11   // per-lane register list depth

typedef __attribute__((ext_vector_type(8))) short bf16x8;
typedef __attribute__((ext_vector_type(4))) float f32x4;
#define MFMA16(a, b, c) __builtin_amdgcn_mfma_f32_16x16x32_bf16(a, b, c, 0, 0, 0)

// ------------------------------------------------------------------
// ws layout (bytes):
//   yT  : [B][N][96] float    12,582,912
//   sqd : [B][N]     double      262,144
//   sq  : [B][N]     float       131,072
//   knn : [B][N][16] int       2,097,152
//   hBs : swizzled bf16 hi     6,291,456
//   lBs : swizzled bf16 lo     6,291,456
//   Ek/Ev/Eq floats               20,480
// ------------------------------------------------------------------

__global__ __launch_bounds__(256) void kE_combine(
    const float* __restrict__ Wk, const float* __restrict__ Dk,
    const float* __restrict__ Wv, const float* __restrict__ Dv,
    const float* __restrict__ Wq, const float* __restrict__ Dq,
    float* __restrict__ Ek, float* __restrict__ Ev, float* __restrict__ Eq) {
  int t = threadIdx.x;
  for (int e = t; e < 2048; e += 256) {
    int o = e >> 6, c = e & 63;
    float a = 0.f, v = 0.f;
    for (int m = 0; m < 32; ++m) {
      a = fmaf(Dk[o * 32 + m], Wk[m * 64 + c], a);
      v = fmaf(Dv[o * 32 + m], Wv[m * 64 + c], v);
    }
    Ek[e] = a; Ev[e] = v;
  }
  for (int e = t; e < 1024; e += 256) {
    int o = e >> 5, c = e & 31;
    float a = 0.f;
    for (int m = 0; m < 32; ++m) a = fmaf(Dq[o * 32 + m], Wq[m * 32 + c], a);
    Eq[e] = a;
  }
}

__global__ __launch_bounds__(256) void kA_transpose(
    const float* __restrict__ y, float* __restrict__ yT,
    float* __restrict__ sq, double* __restrict__ sqd,
    ushort* __restrict__ hBs, ushort* __restrict__ lBs) {
  __shared__ float tile[96][65];
  int b = blockIdx.x >> 6;
  int n0 = (blockIdx.x & 63) * 64;
  int t = threadIdx.x;
  int g = t >> 6, ln = t & 63;
  #pragma unroll
  for (int r = 0; r < 24; ++r) {
    int d = g * 24 + r;
    tile[d][ln] = y[((size_t)b * 96 + d) * N_ + n0 + ln];
  }
  __syncthreads();
  if (t < 64) {
    float s = 0.f; double sd = 0.0;
    #pragma unroll
    for (int d = 0; d < 96; ++d) {
      float v = tile[d][t];
      s = fmaf(v, v, s);
      sd += (double)v * (double)v;
    }
    sq[b * N_ + n0 + t] = s;
    sqd[b * N_ + n0 + t] = sd;
  }
  for (int idx = t; idx < 64 * 96; idx += 256) {
    int nl = idx / 96, d = idx % 96;
    yT[((size_t)b * N_ + n0 + nl) * 96 + d] = tile[d][nl];
  }
  for (int idx = t; idx < 768; idx += 256) {
    int g16l = idx / 192;
    int rem = idx - g16l * 192;
    int sl = rem >> 6;
    int ln2 = rem & 63;
    int fg2 = ln2 >> 4, fm2 = ln2 & 15;
    int nl = g16l * 16 + fm2;
    uint hw[4], lw[4];
    #pragma unroll
    for (int e2 = 0; e2 < 4; ++e2) {
      float v0 = tile[sl * 32 + fg2 * 8 + 2 * e2][nl];
      float v1 = tile[sl * 32 + fg2 * 8 + 2 * e2 + 1][nl];
      uint x0 = __float_as_uint(v0), x1 = __float_as_uint(v1);
      uint h0 = x0 >> 16, h1 = x1 >> 16;
      float r0 = v0 - __uint_as_float(h0 << 16);
      float r1 = v1 - __uint_as_float(h1 << 16);
      uint l0 = __float_as_uint(r0) >> 16, l1 = __float_as_uint(r1) >> 16;
      hw[e2] = h0 | (h1 << 16);
      lw[e2] = l0 | (l1 << 16);
    }
    size_t off = (size_t)b * 393216 +
                 (((size_t)(n0 >> 4) + g16l) * 3 + sl) * 512 + (size_t)ln2 * 8;
    *(uint4*)(hBs + off) = make_uint4(hw[0], hw[1], hw[2], hw[3]);
    *(uint4*)(lBs + off) = make_uint4(lw[0], lw[1], lw[2], lw[3]);
  }
}

// Named-register top-11 + 4-deep buffered insert (r15/r16, proven).
#define DECL11 \
  float v0=-FLT_MAX,v1=-FLT_MAX,v2=-FLT_MAX,v3=-FLT_MAX,v4=-FLT_MAX, \
        v5=-FLT_MAX,v6=-FLT_MAX,v7=-FLT_MAX,v8=-FLT_MAX,v9=-FLT_MAX, \
        v10=-FLT_MAX; \
  int y0=0,y1=0,y2=0,y3=0,y4=0,y5=0,y6=0,y7=0,y8=0,y9=0,y10=0;

#define CX(i) { bool cc = cv > v##i; \
  float tf = cc ? v##i : cv; int ti = cc ? y##i : ci; \
  v##i = cc ? cv : v##i; y##i = cc ? ci : y##i; cv = tf; ci = ti; }

#define INSERT11 { CX(0) CX(1) CX(2) CX(3) CX(4) CX(5) CX(6) CX(7) CX(8) CX(9) \
  CX(10) }

#define FLUSHBUF { \
  if (bcnt > 0) { float cv = f0; int ci = g0; if (cv > v10) { INSERT11 } } \
  if (bcnt > 1) { float cv = f1; int ci = g1; if (cv > v10) { INSERT11 } } \
  if (bcnt > 2) { float cv = f2; int ci = g2; if (cv > v10) { INSERT11 } } \
  if (bcnt > 3) { float cv = f3; int ci = g3; if (cv > v10) { INSERT11 } } \
  bcnt = 0; }

__global__ __launch_bounds__(256) void kB_knn(
    const float* __restrict__ yT, const ushort* __restrict__ hBs,
    const ushort* __restrict__ lBs, const float* __restrict__ sq,
    const double* __restrict__ sqd, int* __restrict__ knn) {
  __shared__ __align__(16) char smem[19712];
  float  (*lv)[4][16][12]  = (float  (*)[4][16][12])smem;
  ushort (*liu)[4][16][12] = (ushort (*)[4][16][12])(smem + 12288);
  int    (*mid)[L_]        = (int    (*)[L_])(smem + 18432);
  double (*rv)[L_]         = (double (*)[L_])smem;            // alias lv

  const int t = threadIdx.x;
  const int lane = t & 63;
  const int w = t >> 6;
  const int fg = lane >> 4, fm = lane & 15;
  const int b = blockIdx.x & 7;
  const int qg = blockIdx.x >> 3;
  const int q = qg * 16 + fm;
  const size_t bN = (size_t)b * N_;
  const ushort* hb = hBs + bN * 96;
  const ushort* lb = lBs + bN * 96;
  const float* sqb = sq + bN;
  const float sqi = sqb[q];

  const ushort* hqb = hb + (size_t)qg * 1536 + (size_t)lane * 8;
  const ushort* lqb = lb + (size_t)qg * 1536 + (size_t)lane * 8;
  const bf16x8 qh0 = *(const bf16x8*)(hqb);
  const bf16x8 qh1 = *(const bf16x8*)(hqb + 512);
  const bf16x8 qh2 = *(const bf16x8*)(hqb + 1024);
  const bf16x8 ql0 = *(const bf16x8*)(lqb);
  const bf16x8 ql1 = *(const bf16x8*)(lqb + 512);
  const bf16x8 ql2 = *(const bf16x8*)(lqb + 1024);

  DECL11
  float f0 = -FLT_MAX, f1 = -FLT_MAX, f2 = -FLT_MAX, f3 = -FLT_MAX;
  int   g0 = 0, g1 = 0, g2 = 0, g3 = 0;
  int   bcnt = 0;

  const int jchunk = w * 1024;
  #pragma unroll 1
  for (int jt = 0; jt < 16; ++jt) {
    const int g16 = (jchunk >> 4) + jt * 4;
    const ushort* hpb = hb + (size_t)g16 * 1536 + (size_t)lane * 8;
    const ushort* lpb = lb + (size_t)g16 * 1536 + (size_t)lane * 8;
    #pragma unroll
    for (int jb = 0; jb < 4; ++jb) {
      const ushort* ph = hpb + jb * 1536;
      const ushort* pl = lpb + jb * 1536;
      const bf16x8 a0 = *(const bf16x8*)(ph);
      const bf16x8 a1 = *(const bf16x8*)(ph + 512);
      const bf16x8 a2 = *(const bf16x8*)(ph + 1024);
      const bf16x8 b0 = *(const bf16x8*)(pl);
      const bf16x8 b1 = *(const bf16x8*)(pl + 512);
      const bf16x8 b2 = *(const bf16x8*)(pl + 1024);
      f32x4 c = {0.f, 0.f, 0.f, 0.f};
      c = MFMA16(a0, qh0, c);
      c = MFMA16(a1, qh1, c);
      c = MFMA16(a2, qh2, c);
      c = MFMA16(a0, ql0, c);
      c = MFMA16(a1, ql1, c);
      c = MFMA16(a2, ql2, c);
      c = MFMA16(b0, qh0, c);
      c = MFMA16(b1, qh1, c);
      c = MFMA16(b2, qh2, c);
      const int jbase = jchunk + jt * 64 + jb * 16 + fg * 4;
      const float4 s4 = *(const float4*)(sqb + jbase);
      #pragma unroll
      for (int r = 0; r < 4; ++r) {
        const float sj = r == 0 ? s4.x : r == 1 ? s4.y : r == 2 ? s4.z : s4.w;
        const float neg = 2.f * c[r] - sqi - sj;
        if (neg > v10) {                 // strict >: earlier index wins ties
          const bool c0 = (bcnt == 0), c1 = (bcnt == 1),
                     c2 = (bcnt == 2), c3 = (bcnt == 3);
          const int ci0 = jbase + r;
          f0 = c0 ? neg : f0; g0 = c0 ? ci0 : g0;
          f1 = c1 ? neg : f1; g1 = c1 ? ci0 : g1;
          f2 = c2 ? neg : f2; g2 = c2 ? ci0 : g2;
          f3 = c3 ? neg : f3; g3 = c3 ? ci0 : g3;
          ++bcnt;
        }
        if (__any(bcnt == 4)) { FLUSHBUF }
      }
    }
  }
  if (__any(bcnt > 0)) { FLUSHBUF }

  {
    float* lvp = &lv[w][fg][fm][0];
    ushort* lip = &liu[w][fg][fm][0];
    lvp[0]=v0; lvp[1]=v1; lvp[2]=v2; lvp[3]=v3; lvp[4]=v4;
    lvp[5]=v5; lvp[6]=v6; lvp[7]=v7; lvp[8]=v8; lvp[9]=v9;
    lvp[10]=v10;
    lvp[11]=-FLT_MAX;
    lip[0]=(ushort)y0; lip[1]=(ushort)y1; lip[2]=(ushort)y2; lip[3]=(ushort)y3;
    lip[4]=(ushort)y4; lip[5]=(ushort)y5; lip[6]=(ushort)y6; lip[7]=(ushort)y7;
    lip[8]=(ushort)y8; lip[9]=(ushort)y9; lip[10]=(ushort)y10;
    lip[11]=0xFFFFu;
  }
  __syncthreads();

  if (t < 16) {
    int p[16];
    #pragma unroll
    for (int c2 = 0; c2 < 16; ++c2) p[c2] = 0;
    #pragma unroll 1
    for (int r = 0; r < L_; ++r) {
      float bv = -FLT_MAX; int bi2 = INT_MAX; int bc = 0;
      #pragma unroll
      for (int c2 = 0; c2 < 16; ++c2) {
        float v = lv[c2 >> 2][c2 & 3][t][p[c2]];
        int  id = (int)liu[c2 >> 2][c2 & 3][t][p[c2]];
        if (v > bv || (v == bv && id < bi2)) { bv = v; bi2 = id; bc = c2; }
      }
      mid[t][r] = bi2;
      #pragma unroll
      for (int c2 = 0; c2 < 16; ++c2) p[c2] += (bc == c2);
    }
  }
  __syncthreads();   // merge done reading lv -> rv (alias) may be written

  {
    const double* sqdb = sqd + bN;
    const float* yTb = yT + bN * 96;
    #pragma unroll 1
    for (int task = t; task < 16 * L_; task += 256) {
      const int fq = task / L_, slot = task - fq * L_;
      const int qq = qg * 16 + fq;
      const int j = mid[fq][slot];
      const float4* q4p = (const float4*)(yTb + (size_t)qq * 96);
      const float4* p4p = (const float4*)(yTb + (size_t)j * 96);
      double a0 = 0.0, a1 = 0.0, a2 = 0.0, a3 = 0.0;
      #pragma unroll 4
      for (int m = 0; m < 24; ++m) {
        float4 qm = q4p[m], pm = p4p[m];
        a0 += (double)qm.x * (double)pm.x;
        a1 += (double)qm.y * (double)pm.y;
        a2 += (double)qm.z * (double)pm.z;
        a3 += (double)qm.w * (double)pm.w;
      }
      rv[fq][slot] = 2.0 * ((a0 + a1) + (a2 + a3)) - sqdb[qq] - sqdb[j];
    }
  }
  __syncthreads();

  if (t < 16) {
    double bd[16]; int bix[16];
    #pragma unroll
    for (int i = 0; i < 16; ++i) { bd[i] = -DBL_MAX; bix[i] = INT_MAX; }
    #pragma unroll 1
    for (int r = 0; r < L_; ++r) {
      double v = rv[t][r]; int id = mid[t][r];
      if (v > bd[15] || (v == bd[15] && id < bix[15])) {
        #pragma unroll
        for (int i = 0; i < 16; ++i) {
          if (v > bd[i] || (v == bd[i] && id < bix[i])) {
            double tv = bd[i]; bd[i] = v; v = tv;
            int ti = bix[i]; bix[i] = id; id = ti;
          }
        }
      }
    }
    int* outp = knn + (bN + (size_t)(qg * 16 + t)) * 16;
    #pragma unroll
    for (int r = 0; r < 16; ++r) outp[r] = bix[r];
  }
}

__device__ __forceinline__ float f4e(const float4& v, int i) {
  return i == 0 ? v.x : i == 1 ? v.y : i == 2 ? v.z : v.w;
}

// kC v3: r14 structure; delta-weight arrays stored fp16 (phase-0 only,
// rel err 5e-4 -> output shift ~3e-3, margin 7x). LDS 43.5KB -> 31.5KB
// => 5 blocks/CU (was 3). knn load hoisted before staging barrier.
__global__ __launch_bounds__(256) void kC_main(
    const float* __restrict__ x, const float* __restrict__ yT,
    const int* __restrict__ knn,
    const float* __restrict__ Wq, const float* __restrict__ Eq,
    const float* __restrict__ Wk, const float* __restrict__ Ek,
    const float* __restrict__ Wv, const float* __restrict__ Ev,
    float* __restrict__ out) {
  __shared__ float sWkL[32][32], sEkL[32][32], sWvL[32][32], sEvL[32][32];
  __shared__ __half sWkD[32][32], sEkD[32][32], sWvD[32][32], sEvD[32][32];
  __shared__ float sQxOut[4][96];
  __shared__ float sCK[4][32][6];
  __shared__ float sCV[4][32][6];

  const int t = threadIdx.x;
  const int w = t >> 6, lane = t & 63;
  const int kk = lane >> 2, g = lane & 3;
  const int blk = blockIdx.x;
  const int b = blk & 7;
  const int n = ((blk >> 3) << 2) + w;
  const size_t bN = (size_t)b * N_;

  // early: issue knn gather before staging (latency hides under phase 0)
  const int jn = knn[(bN + n) * 16 + kk];

  {
    int oc = t >> 3, icq = (t & 7) * 4;
    const float4 klo = *(const float4*)(Wk + oc * 64 + icq);
    const float4 khi = *(const float4*)(Wk + oc * 64 + 32 + icq);
    const float4 elo = *(const float4*)(Ek + oc * 64 + icq);
    const float4 ehi = *(const float4*)(Ek + oc * 64 + 32 + icq);
    const float4 vlo = *(const float4*)(Wv + oc * 64 + icq);
    const float4 vhi = *(const float4*)(Wv + oc * 64 + 32 + icq);
    const float4 flo = *(const float4*)(Ev + oc * 64 + icq);
    const float4 fhi = *(const float4*)(Ev + oc * 64 + 32 + icq);
    #pragma unroll
    for (int i = 0; i < 4; ++i) {
      sWkL[icq + i][oc] = f4e(klo, i);
      sWkD[icq + i][oc] = __float2half(f4e(khi, i) - f4e(klo, i));
      sEkL[icq + i][oc] = f4e(elo, i);
      sEkD[icq + i][oc] = __float2half(f4e(ehi, i) - f4e(elo, i));
      sWvL[icq + i][oc] = f4e(vlo, i);
      sWvD[icq + i][oc] = __float2half(f4e(vhi, i) - f4e(vlo, i));
      sEvL[icq + i][oc] = f4e(flo, i);
      sEvD[icq + i][oc] = __float2half(f4e(fhi, i) - f4e(flo, i));
    }
  }
  __syncthreads();

  const float* ctr = yT + (bN + n) * 96;

  if (lane < 32) {
    const int oc = lane;
    const float* xb = x + (size_t)b * 96 * N_ + n;
    float pq[3] = {0,0,0}, dq[3] = {0,0,0};
    float pk[3] = {0,0,0}, dk[3] = {0,0,0};
    float pv[3] = {0,0,0}, dv[3] = {0,0,0};
    #pragma unroll 4
    for (int ic = 0; ic < 32; ++ic) {
      float wq = Wq[oc * 32 + ic], eq = Eq[oc * 32 + ic];
      float wkd = __half2float(sWkD[ic][oc]), ekd = __half2float(sEkD[ic][oc]);
      float wvd = __half2float(sWvD[ic][oc]), evd = __half2float(sEvD[ic][oc]);
      #pragma unroll
      for (int d = 0; d < 3; ++d) {
        float xv = xb[(size_t)(ic * 3 + d) * N_];
        float cv = ctr[ic * 3 + d];
        pq[d] = fmaf(wq, xv, pq[d]);  dq[d] = fmaf(eq, xv, dq[d]);
        pk[d] = fmaf(wkd, cv, pk[d]); dk[d] = fmaf(ekd, cv, dk[d]);
        pv[d] = fmaf(wvd, cv, pv[d]); dv[d] = fmaf(evd, cv, dv[d]);
      }
    }
    float dot = pq[0]*dq[0] + pq[1]*dq[1] + pq[2]*dq[2];
    float dsq = dq[0]*dq[0] + dq[1]*dq[1] + dq[2]*dq[2] + 1e-6f;
    float r = dot / dsq;
    float qv[3];
    #pragma unroll
    for (int d = 0; d < 3; ++d) {
      float pn = pq[d] - r * dq[d];
      qv[d] = 0.2f * pq[d] + 0.8f * (dot >= 0.f ? pq[d] : pn);
    }
    float nn = sqrtf(qv[0]*qv[0] + qv[1]*qv[1] + qv[2]*qv[2]);
    float nch2 = nn * nn;
    #pragma unroll
    for (int m = 1; m <= 16; m <<= 1) nch2 += __shfl_xor(nch2, m, 32);
    float s = (nn / fmaxf(sqrtf(nch2), 1e-12f)) / fmaxf(nn, 1e-12f);
    #pragma unroll
    for (int d = 0; d < 3; ++d) {
      sQxOut[w][oc * 3 + d] = qv[d] * s;
      sCK[w][oc][d] = pk[d]; sCK[w][oc][3 + d] = dk[d];
      sCV[w][oc][d] = pv[d]; sCV[w][oc][3 + d] = dv[d];
    }
  }
  __syncthreads();

  const float4* nb4 = (const float4*)(yT + (bN + (size_t)jn) * 96);
  const int oc0 = g * 8;

  float aP[8][3], aD[8][3];

  // ===== K pass =====
  {
    const float4* ck = (const float4*)&sCK[w][oc0][0];
    #pragma unroll
    for (int m = 0; m < 12; ++m) {
      float4 v = ck[m];
      #pragma unroll
      for (int e = 0; e < 4; ++e) {
        int f = m * 4 + e, oi = f / 6, r2 = f % 6;
        if (r2 < 3) aP[oi][r2] = f4e(v, e); else aD[oi][r2 - 3] = f4e(v, e);
      }
    }
  }
  #pragma unroll 2
  for (int ch = 0; ch < 8; ++ch) {
    float4 r0 = nb4[ch * 3], r1 = nb4[ch * 3 + 1], r2 = nb4[ch * 3 + 2];
    #pragma unroll
    for (int icl = 0; icl < 4; ++icl) {
      int ic = ch * 4 + icl;
      float4 wA = *(const float4*)&sWkL[ic][oc0];
      float4 wB = *(const float4*)&sWkL[ic][oc0 + 4];
      float4 eA = *(const float4*)&sEkL[ic][oc0];
      float4 eB = *(const float4*)&sEkL[ic][oc0 + 4];
      #pragma unroll
      for (int d = 0; d < 3; ++d) {
        int f = icl * 3 + d;
        float v = f < 4 ? f4e(r0, f) : f < 8 ? f4e(r1, f - 4) : f4e(r2, f - 8);
        #pragma unroll
        for (int oi = 0; oi < 4; ++oi) {
          aP[oi][d]     = fmaf(f4e(wA, oi), v, aP[oi][d]);
          aD[oi][d]     = fmaf(f4e(eA, oi), v, aD[oi][d]);
          aP[oi + 4][d] = fmaf(f4e(wB, oi), v, aP[oi + 4][d]);
          aD[oi + 4][d] = fmaf(f4e(eB, oi), v, aD[oi + 4][d]);
        }
      }
    }
  }
  float att;
  {
    float part = 0.f, nchp = 0.f;
    #pragma unroll
    for (int oi = 0; oi < 8; ++oi) {
      float dot = aP[oi][0]*aD[oi][0] + aP[oi][1]*aD[oi][1] + aP[oi][2]*aD[oi][2];
      float dsq = aD[oi][0]*aD[oi][0] + aD[oi][1]*aD[oi][1] + aD[oi][2]*aD[oi][2] + 1e-6f;
      float r = dot / dsq;
      float nn2 = 0.f, qdot = 0.f;
      const float* qx = &sQxOut[w][(oc0 + oi) * 3];
      #pragma unroll
      for (int d = 0; d < 3; ++d) {
        float pn = aP[oi][d] - r * aD[oi][d];
        float ky = 0.2f * aP[oi][d] + 0.8f * (dot >= 0.f ? aP[oi][d] : pn);
        nn2 = fmaf(ky, ky, nn2);
        qdot = fmaf(ky, qx[d], qdot);
      }
      float nn = sqrtf(nn2);
      part = fmaf(nn / fmaxf(nn, 1e-12f), qdot, part);
      nchp += nn2;
    }
    float nch2 = nchp + __shfl_xor(nchp, 1);
    nch2 += __shfl_xor(nch2, 2);
    float qk = part + __shfl_xor(part, 1);
    float score = qk / fmaxf(sqrtf(nch2), 1e-12f) * 0.14433756729740643f;
    float mx = score;
    #pragma unroll
    for (int m = 4; m <= 32; m <<= 1) mx = fmaxf(mx, __shfl_xor(mx, m));
    float ex = expf(score - mx);
    float sm = ex;
    #pragma unroll
    for (int m = 4; m <= 32; m <<= 1) sm += __shfl_xor(sm, m);
    att = ex / sm;
  }

  // ===== V pass =====
  {
    const float4* cv4 = (const float4*)&sCV[w][oc0][0];
    #pragma unroll
    for (int m = 0; m < 12; ++m) {
      float4 v = cv4[m];
      #pragma unroll
      for (int e = 0; e < 4; ++e) {
        int f = m * 4 + e, oi = f / 6, r2 = f % 6;
        if (r2 < 3) aP[oi][r2] = f4e(v, e); else aD[oi][r2 - 3] = f4e(v, e);
      }
    }
  }
  #pragma unroll 2
  for (int ch = 0; ch < 8; ++ch) {
    float4 r0 = nb4[ch * 3], r1 = nb4[ch * 3 + 1], r2 = nb4[ch * 3 + 2];
    #pragma unroll
    for (int icl = 0; icl < 4; ++icl) {
      int ic = ch * 4 + icl;
      float4 wA = *(const float4*)&sWvL[ic][oc0];
      float4 wB = *(const float4*)&sWvL[ic][oc0 + 4];
      float4 eA = *(const float4*)&sEvL[ic][oc0];
      float4 eB = *(const float4*)&sEvL[ic][oc0 + 4];
      #pragma unroll
      for (int d = 0; d < 3; ++d) {
        int f = icl * 3 + d;
        float v = f < 4 ? f4e(r0, f) : f < 8 ? f4e(r1, f - 4) : f4e(r2, f - 8);
        #pragma unroll
        for (int oi = 0; oi < 4; ++oi) {
          aP[oi][d]     = fmaf(f4e(wA, oi), v, aP[oi][d]);
          aD[oi][d]     = fmaf(f4e(eA, oi), v, aD[oi][d]);
          aP[oi + 4][d] = fmaf(f4e(wB, oi), v, aP[oi + 4][d]);
          aD[oi + 4][d] = fmaf(f4e(eB, oi), v, aD[oi + 4][d]);
        }
      }
    }
  }
  #pragma unroll
  for (int oi = 0; oi < 8; ++oi) {
    float dot = aP[oi][0]*aD[oi][0] + aP[oi][1]*aD[oi][1] + aP[oi][2]*aD[oi][2];
    float dsq = aD[oi][0]*aD[oi][0] + aD[oi][1]*aD[oi][1] + aD[oi][2]*aD[oi][2] + 1e-6f;
    float r = dot / dsq;
    #pragma unroll
    for (int d = 0; d < 3; ++d) {
      float pn = aP[oi][d] - r * aD[oi][d];
      float vy = 0.2f * aP[oi][d] + 0.8f * (dot >= 0.f ? aP[oi][d] : pn);
      aP[oi][d] = att * vy;
    }
  }
  #pragma unroll
  for (int m = 4; m <= 32; m <<= 1) {
    #pragma unroll
    for (int oi = 0; oi < 8; ++oi) {
      #pragma unroll
      for (int d = 0; d < 3; ++d) aP[oi][d] += __shfl_xor(aP[oi][d], m);
    }
  }
  if (kk == 0) {
    #pragma unroll
    for (int oi = 0; oi < 8; ++oi)
      #pragma unroll
      for (int d = 0; d < 3; ++d)
        sQxOut[w][(oc0 + oi) * 3 + d] = aP[oi][d];
  }
  __syncthreads();

  const int nb0 = (blk >> 3) << 2;
  for (int idx = t; idx < 384; idx += 256) {
    int qq = idx & 3, od = idx >> 2;
    size_t a = ((size_t)b * 96 + od) * N_ + nb0 + qq;
    out[a] = x[a] + sQxOut[qq][od];
  }
}

extern "C" void kernel_launch(void* const* d_in, const int* in_sizes, int n_in,
                              void* d_out, int out_size, void* d_ws, size_t ws_size,
                              hipStream_t stream) {
  const float* x  = (const float*)d_in[0];
  const float* y  = (const float*)d_in[1];
  const float* Wq = (const float*)d_in[2];
  const float* Dq = (const float*)d_in[3];
  const float* Wk = (const float*)d_in[4];
  const float* Dk = (const float*)d_in[5];
  const float* Wv = (const float*)d_in[6];
  const float* Dv = (const float*)d_in[7];
  float* out = (float*)d_out;

  char* wsb = (char*)d_ws;
  float*  yT  = (float*)wsb;                                   // 12,582,912 B
  double* sqd = (double*)(wsb + 12582912);                     //    262,144 B
  float*  sq  = (float*)(wsb + 12845056);                      //    131,072 B
  int*    knn = (int*)(wsb + 12976128);                        //  2,097,152 B
  ushort* hBs = (ushort*)(wsb + 15073280);                     //  6,291,456 B
  ushort* lBs = (ushort*)(wsb + 21364736);                     //  6,291,456 B
  float*  Ek  = (float*)(wsb + 27656192);                      //      8,192 B
  float*  Ev  = Ek + 2048;
  float*  Eq  = Ev + 2048;

  kE_combine<<<dim3(1), dim3(256), 0, stream>>>(Wk, Dk, Wv, Dv, Wq, Dq, Ek, Ev, Eq);
  kA_transpose<<<dim3(512), dim3(256), 0, stream>>>(y, yT, sq, sqd, hBs, lBs);
  kB_knn<<<dim3(2048), dim3(256), 0, stream>>>(yT, hBs, lBs, sq, sqd, knn);
  kC_main<<<dim3(8192), dim3(256), 0, stream>>>(x, yT, knn, Wq, Eq, Wk, Ek, Wv, Ev, out);
}